// Round 5
// baseline (832.210 us; speedup 1.0000x reference)
//
#include <hip/hip_runtime.h>
#include <cstdint>
#include <math.h>

#define NBATCH 32
#define NSQ 1024
#define NCQ 1024
#define DDIM 256
#define DP 257
#define KQ 128
#define KPAD 288   // 257 padded to /32

typedef __attribute__((ext_vector_type(8))) short short8;
typedef __attribute__((ext_vector_type(4))) float floatx4;

// ---------------- device helpers ----------------
__device__ __forceinline__ float bf2f(ushort u) { return __uint_as_float(((uint)u) << 16); }
__device__ __forceinline__ ushort f2bf(float f) {
    uint u = __float_as_uint(f);
    return (ushort)((u + 0x7FFFu + ((u >> 16) & 1u)) >> 16);
}
__device__ __forceinline__ float artanh_clip(float x) {
    x = fminf(fmaxf(x, -1.0f + 1e-5f), 1.0f - 1e-5f);
    return 0.5f * (log1pf(x) - log1pf(-x));
}
__device__ __forceinline__ float gelu_f(float x) {
    return 0.5f * x * (1.0f + erff(x * 0.70710678118654752440f));
}
__device__ __forceinline__ float waveRedSum(float v) {
#pragma unroll
    for (int o = 32; o > 0; o >>= 1) v += __shfl_down(v, o, 64);
    return __shfl(v, 0, 64);
}
__device__ __forceinline__ float blockRedSum(float v, float* buf) {
    int lane = threadIdx.x & 63, wid = threadIdx.x >> 6;
#pragma unroll
    for (int o = 32; o > 0; o >>= 1) v += __shfl_down(v, o, 64);
    __syncthreads();
    if (lane == 0) buf[wid] = v;
    __syncthreads();
    int nw = blockDim.x >> 6;
    float s = buf[0];
    for (int i = 1; i < nw; i++) s += buf[i];
    return s;
}
__device__ __forceinline__ float blockRedMax(float v, float* buf) {
    int lane = threadIdx.x & 63, wid = threadIdx.x >> 6;
#pragma unroll
    for (int o = 32; o > 0; o >>= 1) v = fmaxf(v, __shfl_down(v, o, 64));
    __syncthreads();
    if (lane == 0) buf[wid] = v;
    __syncthreads();
    int nw = blockDim.x >> 6;
    float s = buf[0];
    for (int i = 1; i < nw; i++) s = fmaxf(s, buf[i]);
    return s;
}

// ---------------- bf16 MFMA GEMM ----------------
// C[m,n] = sum_k A[m,k]*B'[k,n] (+bias[n])
// A_NN=false: A is (M x K) row-major.  A_NN=true: A stored (K x M).
// B_NN=false: B is (N x K) row-major (bt form). B_NN=true: B stored (K x N).
// NSPLIT: split-K factor; blockIdx.z = batch*NSPLIT + ksplit; ATOMIC epilogue.
template <bool A_NN, bool B_NN, bool OUT_BF16, bool BIAS, bool ATOMIC, int NSPLIT>
__global__ __launch_bounds__(256) void mfma_gemm(
    const short* __restrict__ A, int lda, int64_t sA,
    const short* __restrict__ B, int ldb, int64_t sB,
    void* __restrict__ Cv, int ldc, int64_t sC,
    const float* __restrict__ bias, int M, int N, int K)
{
    __shared__ short As[128][32];
    __shared__ short Bs[128][32];
    const int zz = blockIdx.z;
    const int zb = zz / NSPLIT;
    const int ks = zz - zb * NSPLIT;
    A += (int64_t)zb * sA;
    B += (int64_t)zb * sB;
    const int kper = K / NSPLIT;
    const int kbeg = ks * kper, kend = kbeg + kper;
    const int m0 = blockIdx.y * 128, n0 = blockIdx.x * 128;
    const int t = threadIdx.x;
    const int lane = t & 63, w = t >> 6;
    const int wm = (w & 1) * 64, wn = (w >> 1) * 64;
    floatx4 acc[4][4] = {};
    for (int k0 = kbeg; k0 < kend; k0 += 32) {
        // ---- stage A tile -> As[m][k] ----
        if (!A_NN) {
            int r = t >> 2, c8 = (t & 3) * 8;
            uint4 v1 = *(const uint4*)(A + (int64_t)(m0 + r) * lda + k0 + c8);
            uint4 v2 = *(const uint4*)(A + (int64_t)(m0 + r + 64) * lda + k0 + c8);
            *(uint4*)&As[r][c8] = v1;
            *(uint4*)&As[r + 64][c8] = v2;
        } else {
            int r2 = t >> 4, c8 = (t & 15) * 8;
            int kk = 2 * r2;
            const ushort* a0 = (const ushort*)A + (int64_t)(k0 + kk) * lda + m0 + c8;
            uint4 v0 = *(const uint4*)a0;
            uint4 v1 = *(const uint4*)(a0 + lda);
            const ushort* p0 = (const ushort*)&v0;
            const ushort* p1 = (const ushort*)&v1;
#pragma unroll
            for (int i = 0; i < 8; i++) {
                uint pk = (uint)p0[i] | ((uint)p1[i] << 16);
                *(uint*)&As[c8 + i][kk] = pk;
            }
        }
        // ---- stage B tile -> Bs[n][k] ----
        if (!B_NN) {
            int r = t >> 2, c8 = (t & 3) * 8;
            uint4 v1 = *(const uint4*)(B + (int64_t)(n0 + r) * ldb + k0 + c8);
            uint4 v2 = *(const uint4*)(B + (int64_t)(n0 + r + 64) * ldb + k0 + c8);
            *(uint4*)&Bs[r][c8] = v1;
            *(uint4*)&Bs[r + 64][c8] = v2;
        } else {
            int r2 = t >> 4, c8 = (t & 15) * 8;
            int kk = 2 * r2;
            const ushort* b0 = (const ushort*)B + (int64_t)(k0 + kk) * ldb + n0 + c8;
            uint4 v0 = *(const uint4*)b0;
            uint4 v1 = *(const uint4*)(b0 + ldb);
            const ushort* p0 = (const ushort*)&v0;
            const ushort* p1 = (const ushort*)&v1;
#pragma unroll
            for (int i = 0; i < 8; i++) {
                uint pk = (uint)p0[i] | ((uint)p1[i] << 16);
                *(uint*)&Bs[c8 + i][kk] = pk;
            }
        }
        __syncthreads();
        short8 af[4], bfv[4];
#pragma unroll
        for (int i = 0; i < 4; i++)
            af[i] = *(const short8*)&As[wm + 16 * i + (lane & 15)][8 * (lane >> 4)];
#pragma unroll
        for (int i = 0; i < 4; i++)
            bfv[i] = *(const short8*)&Bs[wn + 16 * i + (lane & 15)][8 * (lane >> 4)];
#pragma unroll
        for (int i = 0; i < 4; i++)
#pragma unroll
            for (int j = 0; j < 4; j++)
                acc[i][j] = __builtin_amdgcn_mfma_f32_16x16x32_bf16(af[i], bfv[j], acc[i][j], 0, 0, 0);
        __syncthreads();
    }
    // ---- epilogue: D row=(lane>>4)*4+reg, col=lane&15 ----
    const int q = lane >> 4, c = lane & 15;
#pragma unroll
    for (int j = 0; j < 4; j++) {
        int col = n0 + wn + 16 * j + c;
        float bv = BIAS ? bias[col] : 0.0f;
#pragma unroll
        for (int i = 0; i < 4; i++) {
            int rowb = m0 + wm + 16 * i + 4 * q;
#pragma unroll
            for (int r = 0; r < 4; r++) {
                float v = acc[i][j][r] + bv;
                int64_t idx = (int64_t)zb * sC + (int64_t)(rowb + r) * ldc + col;
                if (ATOMIC)       atomicAdd((float*)Cv + idx, v);
                else if (OUT_BF16) ((ushort*)Cv)[idx] = f2bf(v);
                else               ((float*)Cv)[idx] = v;
            }
        }
    }
}

// ---------------- DFT matrix generation (bf16) ----------------
__global__ void gen_cs1(ushort* CS1) {
    int idx = blockIdx.x * 256 + threadIdx.x;       // 1024*1024
    int n = idx >> 10, m = idx & 1023;
    int p = (n * m) & 1023;
    float ang = (6.28318530717958647692f / 1024.0f) * (float)p;
    CS1[n * 2048 + m] = f2bf(cosf(ang));
    CS1[n * 2048 + 1024 + m] = f2bf(-sinf(ang));
}
__global__ void gen_c2s2(ushort* C2, ushort* S2) {
    int idx = blockIdx.x * 256 + threadIdx.x;       // 256*256
    int d = idx >> 8, j = idx & 255;
    int p = (d * j) & 255;
    float ang = (6.28318530717958647692f / 256.0f) * (float)p;
    C2[idx] = f2bf(cosf(ang));
    S2[idx] = f2bf(sinf(ang));
}

// weight prep: rows 1.. of W (o x 257) -> bf16 (N x 288), zero-padded
__global__ void wprep_kernel(const float* __restrict__ WlW, const float* __restrict__ WsW,
                             const float* __restrict__ WcW, ushort* Wl, ushort* Ws, ushort* Wc) {
    int r = blockIdx.x, t = threadIdx.x;
    if (t >= KPAD) return;
    const float* src; ushort* dst; int srow;
    if (r < 256)      { src = WlW; dst = Wl + r * KPAD;        srow = r + 1; }
    else if (r < 384) { src = WsW; dst = Ws + (r - 256) * KPAD; srow = r - 256 + 1; }
    else              { src = WcW; dst = Wc + (r - 384) * KPAD; srow = r - 384 + 1; }
    dst[t] = (t < DP) ? f2bf(src[(int64_t)srow * DP + t]) : (ushort)0;
}

// float -> bf16 elementwise
__global__ void cvt_bf_kernel(const float* __restrict__ in, ushort* __restrict__ outp, int n) {
    int i = blockIdx.x * 256 + threadIdx.x;
    if (i * 4 < n) {
        float4 v = *(const float4*)(in + i * 4);
        ushort4 o; o.x = f2bf(v.x); o.y = f2bf(v.y); o.z = f2bf(v.z); o.w = f2bf(v.w);
        *(ushort4*)(outp + i * 4) = o;
    }
}

// p_logmap0 rows of 256, out bf16
__global__ __launch_bounds__(256) void plog_kernel(const float* __restrict__ in, ushort* __restrict__ outp) {
    __shared__ float red[4];
    int64_t row = blockIdx.x; int t = threadIdx.x;
    float v = in[row * 256 + t];
    float s = blockRedSum(v * v, red);
    float yn = sqrtf(fmaxf(s, 1e-15f));
    float fac = artanh_clip(yn) / yn;
    outp[row * 256 + t] = f2bf(fac * v);
}

// euclid_to_lorentz: bf16 rows 256 -> bf16 rows 288 (time at 0), split Ls/Lc
__global__ __launch_bounds__(256) void e2l_kernel(const ushort* __restrict__ in,
                                                  ushort* __restrict__ Lsb, ushort* __restrict__ Lcb) {
    __shared__ float red[4];
    int64_t row = blockIdx.x; int t = threadIdx.x;   // row in [0, 65536)
    float v = bf2f(in[row * 256 + t]);
    float s = blockRedSum(v * v, red);
    float xn = sqrtf(fmaxf(s, 1e-15f)) + 1e-5f;
    float sc = fminf(1.0f, 2.0f / xn);
    float xs = v * sc;
    float s2 = fmaxf(s * sc * sc, 1e-15f);
    float vn = sqrtf(s2);
    float fac = sinhf(vn) / vn;
    ushort* ob = (row < 32768 ? Lsb + row * KPAD : Lcb + (row - 32768) * KPAD);
    if (t == 0) ob[0] = f2bf(coshf(vn));
    ob[1 + t] = f2bf(fac * xs);
    if (t < KPAD - DP) ob[DP + t] = 0;
}

// lorentz_linear space (fp32, 256) -> bf16 row 288 with time at col 0
__global__ __launch_bounds__(256) void lfix2_kernel(const float* __restrict__ sp, ushort* __restrict__ obf) {
    __shared__ float red[4];
    int64_t row = blockIdx.x; int t = threadIdx.x;
    float v = sp[row * 256 + t];
    float s = blockRedSum(v * v, red);
    ushort* ob = obf + row * KPAD;
    if (t == 0) ob[0] = f2bf(sqrtf(s + 1.0f));
    ob[1 + t] = f2bf(v);
    if (t < KPAD - DP) ob[DP + t] = 0;
}

// lorentz_linear(K) space + bias + to_poincare; rows 0..32767 -> Ws path, rest Wc
__global__ __launch_bounds__(128) void poinc2_kernel(const float* __restrict__ sp,
                                                     const float* __restrict__ Wsb, const float* __restrict__ Wcb,
                                                     float* __restrict__ o32, ushort* __restrict__ obf) {
    __shared__ float red[2];
    int64_t row = blockIdx.x; int t = threadIdx.x;
    const float* bias = (row < 32768 ? Wsb : Wcb);
    float v = sp[row * KQ + t] + bias[1 + t];
    float s = blockRedSum(v * v, red);
    float tim = sqrtf(s + 1.0f);
    float o = v / (tim + 1.0f);
    o32[row * KQ + t] = o;
    obf[row * KQ + t] = f2bf(o);
}

// lorentz_act on bf16 Lmat rows (1024), in place, + xnrow
__global__ __launch_bounds__(256) void lact_kernel(ushort* __restrict__ Lmat, float* __restrict__ xnrow) {
    __shared__ float red[4];
    int64_t row = blockIdx.x; int t = threadIdx.x;
    ushort* r = Lmat + row * (int64_t)NCQ;
    ushort4 u = *(ushort4*)&r[4 * t];
    float v[4] = {bf2f(u.x), bf2f(u.y), bf2f(u.z), bf2f(u.w)};
    float g[4]; float s = 0.f;
#pragma unroll
    for (int i = 0; i < 4; i++) {
        int idx = 4 * t + i;
        if (idx > 0) { g[i] = gelu_f(v[i]); s += g[i] * g[i]; } else g[i] = 0.f;
    }
    s = blockRedSum(s, red);
    if (t == 0) g[0] = sqrtf(1.0f + s);
    ushort4 o; o.x = f2bf(g[0]); o.y = f2bf(g[1]); o.z = f2bf(g[2]); o.w = f2bf(g[3]);
    *(ushort4*)&r[4 * t] = o;
    if (t == 0) xnrow[row] = sqrtf(fmaxf(1.0f + 2.0f * s, 1e-15f));
}

// column-norm stage A/B
__global__ __launch_bounds__(256) void colnormA_kernel(const ushort* __restrict__ Lmat, float* __restrict__ part) {
    int b = blockIdx.x, chunk = blockIdx.y, t = threadIdx.x;
    const ushort* base = Lmat + (int64_t)b * NSQ * NCQ + (int64_t)chunk * 128 * NCQ + 4 * t;
    float s0 = 0.f, s1 = 0.f, s2 = 0.f, s3 = 0.f;
    for (int n = 0; n < 128; n++) {
        ushort4 u = *(const ushort4*)(base + (int64_t)n * NCQ);
        float a = bf2f(u.x), bb = bf2f(u.y), c = bf2f(u.z), d = bf2f(u.w);
        s0 += a * a; s1 += bb * bb; s2 += c * c; s3 += d * d;
    }
    float4 o = {s0, s1, s2, s3};
    *(float4*)(part + ((int64_t)(b * 8 + chunk)) * 4096 + 4 * t) = o;
}
__global__ __launch_bounds__(256) void colnormB_kernel(const float* __restrict__ part, float* __restrict__ xncol) {
    int b = blockIdx.x; int m = blockIdx.y * 256 + threadIdx.x;
    const float* p = part + (int64_t)b * 8 * 4096 + m;
    float s = 0.f;
#pragma unroll
    for (int c = 0; c < 8; c++) s += p[c * 4096];
    xncol[b * NCQ + m] = sqrtf(fmaxf(s, 1e-15f));
}

// Hs path rowwise chain -> logits
__global__ __launch_bounds__(64) void rowops_s_kernel(
    const float* __restrict__ Hsa, const float* __restrict__ mxs,
    const float* __restrict__ xnrow, const float* __restrict__ whs,
    float* __restrict__ logits)
{
    int64_t row = blockIdx.x; int t = threadIdx.x;
    const float* p = Hsa + row * KQ;
    const float* q = mxs + row * KQ;
    float p0 = p[t], p1 = p[t + 64], q0 = q[t], q1 = q[t + 64];
    float mxn = sqrtf(fmaxf(waveRedSum(q0 * q0 + q1 * q1), 1e-15f));
    float xn = xnrow[row];
    float fac = tanhf(mxn / xn * artanh_clip(xn)) / mxn;
    float y0 = fac * q0, y1 = fac * q1;
    float xy = waveRedSum(p0 * y0 + p1 * y1);
    float x2 = waveRedSum(p0 * p0 + p1 * p1);
    float y2 = waveRedSum(y0 * y0 + y1 * y1);
    float ca = 1.f + 2.f * xy + y2, cb = 1.f - x2;
    float den = fmaxf(1.f + 2.f * xy + x2 * y2, 1e-15f);
    float h0 = (ca * p0 + cb * y0) / den, h1 = (ca * p1 + cb * y1) / den;
    float hn = sqrtf(fmaxf(waveRedSum(h0 * h0 + h1 * h1), 1e-15f));
    float uf = artanh_clip(hn) / hn;
    float g0 = gelu_f(uf * h0), g1 = gelu_f(uf * h1);
    float gn = sqrtf(fmaxf(waveRedSum(g0 * g0 + g1 * g1), 1e-15f));
    float ef = tanhf(gn) / gn;
    float H0 = ef * g0, H1 = ef * g1;
    float dot = waveRedSum(H0 * whs[t] + H1 * whs[t + 64]);
    float Hn = sqrtf(fmaxf(waveRedSum(H0 * H0 + H1 * H1), 1e-15f));
    float mxn2 = sqrtf(fmaxf(dot * dot, 1e-15f));
    float lg = tanhf(mxn2 / Hn * artanh_clip(Hn)) * dot / mxn2;
    if (t == 0) logits[row] = lg;
}

// transpose HsA_bf (b,1024n,128j) -> HsAT (b,128j,1024n)
__global__ void thsa_kernel(const ushort* __restrict__ in, ushort* __restrict__ outp) {
    __shared__ ushort tile[32][33];
    int b = blockIdx.z;
    int n0 = blockIdx.x * 32, j0 = blockIdx.y * 32;
    const ushort* ib = in + (int64_t)b * 131072;
    ushort* ob = outp + (int64_t)b * 131072;
    int tx = threadIdx.x, ty = threadIdx.y;
    for (int i = 0; i < 32; i += 8) tile[ty + i][tx] = ib[(n0 + ty + i) * 128 + j0 + tx];
    __syncthreads();
    for (int i = 0; i < 32; i += 8) ob[(j0 + ty + i) * 1024 + n0 + tx] = tile[tx][ty + i];
}

// mobius_matvec scale on mx_cT columns
__global__ __launch_bounds__(256) void colscale_kernel(float* __restrict__ mxcT, const float* __restrict__ xncol) {
    int b = blockIdx.x; int m = blockIdx.y * 256 + threadIdx.x;
    float* base = mxcT + (int64_t)b * KQ * NCQ + m;
    float s = 0.f;
    for (int j = 0; j < KQ; j++) { float v = base[j * NCQ]; s += v * v; }
    float mxn = sqrtf(fmaxf(s, 1e-15f));
    float xn = xncol[b * NCQ + m];
    float fac = tanhf(mxn / xn * artanh_clip(xn)) / mxn;
    for (int j = 0; j < KQ; j++) base[j * NCQ] *= fac;
}

// Hc path rowwise chain (per (b,k) over NC), in place on y
__global__ __launch_bounds__(256) void rowops_c_kernel(const float* __restrict__ HcA, float* __restrict__ y) {
    __shared__ float red[4];
    int64_t row = blockIdx.x;
    int b = (int)(row >> 7), k = (int)(row & 127);
    const float* xbase = HcA + (int64_t)b * NCQ * KQ + k;
    float* yr = y + row * (int64_t)NCQ;
    int t = threadIdx.x;
    float xv[4], yv[4];
    float xy = 0.f, x2 = 0.f, y2 = 0.f;
#pragma unroll
    for (int i = 0; i < 4; i++) {
        int m = t + 256 * i;
        xv[i] = xbase[(int64_t)m * KQ]; yv[i] = yr[m];
        xy += xv[i] * yv[i]; x2 += xv[i] * xv[i]; y2 += yv[i] * yv[i];
    }
    xy = blockRedSum(xy, red);
    x2 = blockRedSum(x2, red);
    y2 = blockRedSum(y2, red);
    float ca = 1.f + 2.f * xy + y2, cb = 1.f - x2;
    float den = fmaxf(1.f + 2.f * xy + x2 * y2, 1e-15f);
    float h[4]; float hn2 = 0.f;
#pragma unroll
    for (int i = 0; i < 4; i++) { h[i] = (ca * xv[i] + cb * yv[i]) / den; hn2 += h[i] * h[i]; }
    hn2 = blockRedSum(hn2, red);
    float hn = sqrtf(fmaxf(hn2, 1e-15f));
    float uf = artanh_clip(hn) / hn;
    float g[4]; float gn2 = 0.f;
#pragma unroll
    for (int i = 0; i < 4; i++) { g[i] = gelu_f(uf * h[i]); gn2 += g[i] * g[i]; }
    gn2 = blockRedSum(gn2, red);
    float gn = sqrtf(fmaxf(gn2, 1e-15f));
    float ef = tanhf(gn) / gn;
#pragma unroll
    for (int i = 0; i < 4; i++) yr[t + 256 * i] = ef * g[i];
}

// Ac logits
__global__ __launch_bounds__(256) void logitsc_kernel(const float* __restrict__ Hc, const float* __restrict__ whc, float* __restrict__ lgc) {
    int b = blockIdx.x; int m = blockIdx.y * 256 + threadIdx.x;
    const float* base = Hc + (int64_t)b * KQ * NCQ + m;
    float s1 = 0.f, s2 = 0.f;
    for (int j = 0; j < KQ; j++) { float v = base[j * NCQ]; s1 += v * whc[j]; s2 += v * v; }
    float xn = sqrtf(fmaxf(s2, 1e-15f));
    float mxn = sqrtf(fmaxf(s1 * s1, 1e-15f));
    lgc[b * NCQ + m] = tanhf(mxn / xn * artanh_clip(xn)) * s1 / mxn;
}

__global__ __launch_bounds__(256) void softmax_kernel(const float* __restrict__ lg, float* __restrict__ outp) {
    __shared__ float red[4];
    int b = blockIdx.x; int t = threadIdx.x;
    const float* x = lg + b * 1024;
    float v[4]; float m = -1e30f;
#pragma unroll
    for (int i = 0; i < 4; i++) { v[i] = x[t + 256 * i]; m = fmaxf(m, v[i]); }
    m = blockRedMax(m, red);
    float s = 0.f;
#pragma unroll
    for (int i = 0; i < 4; i++) { v[i] = expf(v[i] - m); s += v[i]; }
    s = blockRedSum(s, red);
    float inv = 1.0f / s;
#pragma unroll
    for (int i = 0; i < 4; i++) outp[b * 1024 + t + 256 * i] = v[i] * inv;
}

// centroid stage A on bf16 L (stride 288, time at col 0)
__global__ __launch_bounds__(320) void centroidA_kernel(
    const ushort* __restrict__ Lsb, const ushort* __restrict__ Lcb,
    const float* __restrict__ As, const float* __restrict__ Ac,
    float* __restrict__ part)
{
    int b = blockIdx.x;
    int which = blockIdx.y;
    int chunk = blockIdx.z;
    const ushort* L = which ? Lcb : Lsb;
    const float* w = which ? Ac : As;
    int t = threadIdx.x;
    if (t >= DP) return;
    const ushort* Lb = L + (int64_t)b * NSQ * KPAD + (int64_t)chunk * 128 * KPAD + t;
    const float* wb = w + b * NSQ + chunk * 128;
    float s = 0.f;
    for (int n = 0; n < 128; n++) s += wb[n] * bf2f(Lb[(int64_t)n * KPAD]);
    part[((int64_t)((b * 2 + which) * 8 + chunk)) * 264 + t] = s;
}
__global__ __launch_bounds__(320) void centroidB_kernel(
    const float* __restrict__ part, float* __restrict__ co_s, float* __restrict__ co_c)
{
    int b = blockIdx.x;
    int which = blockIdx.y;
    int t = threadIdx.x;
    if (t >= DP) return;
    const float* p = part + (int64_t)(b * 2 + which) * 8 * 264 + t;
    float s = 0.f;
#pragma unroll
    for (int c = 0; c < 8; c++) s += p[c * 264];
    (which ? co_c : co_s)[b * DP + t] = s;
}

__global__ __launch_bounds__(256) void final_kernel(const float* __restrict__ co_s, const float* __restrict__ co_c, float* __restrict__ outp) {
    __shared__ float red[4];
    int b = blockIdx.x, t = threadIdx.x;
    float zmine[2];
    for (int w = 0; w < 2; w++) {
        const float* co = (w ? co_c : co_s) + b * DP;
        float at = co[0];
        float asp = co[1 + t];
        float ssp = blockRedSum(asp * asp, red);
        float li = ssp - at * at;
        float den = sqrtf(fmaxf(fabsf(li), 1e-8f));
        float xt = at / den, xsp = asp / den;
        float s2 = blockRedSum(xsp * xsp, red);
        float nrm = sqrtf(fmaxf(s2, 1e-15f));
        float ac = acoshf(fmaxf(xt, 1.0f + 1e-7f));
        zmine[w] = ac * xsp / nrm;
    }
    float vn2 = blockRedSum(zmine[0] * zmine[0] + zmine[1] * zmine[1], red);
    float vn = sqrtf(fmaxf(vn2, 1e-15f));
    float sc = sinhf(vn) / vn;
    if (t == 0) outp[b * 513] = coshf(vn);
    outp[b * 513 + 1 + t] = sc * zmine[0];
    outp[b * 513 + 1 + 256 + t] = sc * zmine[1];
}

// ---------------- host launcher ----------------
extern "C" void kernel_launch(void* const* d_in, const int* in_sizes, int n_in,
                              void* d_out, int out_size, void* d_ws, size_t ws_size,
                              hipStream_t stream)
{
    const float* sent = (const float*)d_in[0];
    const float* comm = (const float*)d_in[1];
    const float* WlW  = (const float*)d_in[2];
    const float* Wlb  = (const float*)d_in[3];
    const float* WcW  = (const float*)d_in[4];
    const float* Wcb  = (const float*)d_in[5];
    const float* WsW  = (const float*)d_in[6];
    const float* Wsb  = (const float*)d_in[7];
    const float* whs  = (const float*)d_in[8];
    const float* whc  = (const float*)d_in[9];
    float* out = (float*)d_out;
    (void)in_sizes; (void)n_in; (void)out_size; (void)ws_size;

    float* ws = (float*)d_ws;
    size_t off = 0;
    auto take = [&](size_t n) { float* p = ws + off; off += n; return p; };
    float*  xnrow = take(32768);
    float*  xncol = take(32768);
    float*  lgs   = take(32768);
    float*  lgc   = take(32768);
    float*  co_s  = take(8224);
    float*  co_c  = take(8224);
    ushort* Ls_bf = (ushort*)take(4718592);   // contiguous with Lc_bf
    ushort* Lc_bf = (ushort*)take(4718592);
    ushort* Wl_bf = (ushort*)take(36864);
    ushort* Ws_bf = (ushort*)take(18432);     // contiguous with Wc_bf
    ushort* Wc_bf = (ushort*)take(18432);
    ushort* HsA_bf = (ushort*)take(2097152);  // contiguous with HcA_bf
    ushort* HcA_bf = (ushort*)take(2097152);
    float*  part_cn   = take(1048576);
    float*  part_cent = take(135168);
    float*  F     = take(33554432);           // total 48.6M fl = 185 MiB

    // Phase overlays in F (float offsets)
    ushort* Xin_bf  = (ushort*)F;                 // [P1] 8.39M fl (64 batches x 1024 x 256)
    ushort* ZT_bf   = (ushort*)(F + 8388608);     // [P1] 16.78M fl (64 x 256 x 2048)
    ushort* CS1     = (ushort*)(F + 25165824);    // [P1] 1.05M fl
    ushort* C2_bf   = (ushort*)(F + 26214400);    // [P1] 32k fl
    ushort* S2_bf   = (ushort*)(F + 26247168);    // [P1] 32k fl
    ushort* Yst_bf  = (ushort*)F;                 // [P1] aliases Xin (dead after stage-1)
    ushort* Lmat_bf = (ushort*)F;                 // [P3-P5] 16.78M fl
    float*  Llin_sp = F + 16777216;               // [P2] 8.39M fl
    ushort* Llin_bf = (ushort*)(F + 25165824);    // [P2-P3] 4.72M fl
    float*  ycat    = F + 16777216;               // [P4] 8.39M fl (ys | yc)
    float*  HsA     = F + 25165824;               // [P4-P5] 4.19M fl
    float*  HcA     = F + 29360128;               // [P4-P5] 4.19M fl
    float*  mx      = F + 16777216;               // [P5] 4.19M fl
    ushort* HsAT    = (ushort*)(F + 20971520);    // [P5] 2.1M fl

    float* AsOut = out + 16416;
    float* AcOut = out + 16416 + 32768;

    dim3 blk(256);

    // constants
    gen_cs1<<<4096, 256, 0, stream>>>(CS1);
    gen_c2s2<<<256, 256, 0, stream>>>(C2_bf, S2_bf);
    wprep_kernel<<<512, 320, 0, stream>>>(WlW, WsW, WcW, Wl_bf, Ws_bf, Wc_bf);

    // ---- merged fft2 (sent batches 0-31, comment 32-63) ----
    cvt_bf_kernel<<<8192, 256, 0, stream>>>(sent, Xin_bf, 8388608);
    plog_kernel<<<32768, 256, 0, stream>>>(comm, Xin_bf + 8388608);
    // stage-1 (TN): ZT[j,m] = sum_d C2[j,d]*X[m,d]
    mfma_gemm<false,false,true,false,false,1><<<dim3(8,2,64), blk, 0, stream>>>(
        (const short*)C2_bf,256,0, (const short*)Xin_bf,256,262144, ZT_bf,2048,524288, nullptr, 256,1024,256);
    mfma_gemm<false,false,true,false,false,1><<<dim3(8,2,64), blk, 0, stream>>>(
        (const short*)S2_bf,256,0, (const short*)Xin_bf,256,262144, ZT_bf+1024,2048,524288, nullptr, 256,1024,256);
    // stage-2 (TN, K=2048), bf16 out into Yst (aliases Xin)
    mfma_gemm<false,false,true,false,false,1><<<dim3(2,8,64), blk, 0, stream>>>(
        (const short*)CS1,2048,0, (const short*)ZT_bf,2048,524288, Yst_bf,256,262144, nullptr, 1024,256,2048);
    e2l_kernel<<<65536, 256, 0, stream>>>(Yst_bf, Ls_bf, Lc_bf);

    // ---- L = lorentz_linear(Lc, Wl): space cols only ----
    mfma_gemm<false,false,false,true,false,1><<<dim3(2,256,1), blk, 0, stream>>>(
        (const short*)Lc_bf,KPAD,0, (const short*)Wl_bf,KPAD,0, Llin_sp,256,0, Wlb+1, 32768,256,KPAD);
    lfix2_kernel<<<32768, 256, 0, stream>>>(Llin_sp, Llin_bf);

    // ---- Lmat = lorentz_act(einsum(Ls, Llin)) in bf16 ----
    mfma_gemm<false,false,true,false,false,1><<<dim3(8,8,32), blk, 0, stream>>>(
        (const short*)Ls_bf,KPAD,294912, (const short*)Llin_bf,KPAD,294912, Lmat_bf,1024,1048576, nullptr, 1024,1024,KPAD);
    lact_kernel<<<32768, 256, 0, stream>>>(Lmat_bf, xnrow);
    colnormA_kernel<<<dim3(32,8), 256, 0, stream>>>(Lmat_bf, part_cn);
    colnormB_kernel<<<dim3(32,4), 256, 0, stream>>>(part_cn, xncol);

    // ---- Hs_a / Hc_a merged (z=0: Ls*Ws, z=1: Lc*Wc), bias in poinc2 ----
    mfma_gemm<false,false,false,false,false,1><<<dim3(1,256,2), blk, 0, stream>>>(
        (const short*)Ls_bf,KPAD,9437184, (const short*)Ws_bf,KPAD,36864, ycat,128,4194304, nullptr, 32768,128,KPAD);
    poinc2_kernel<<<65536, 128, 0, stream>>>(ycat, Wsb, Wcb, HsA, HsA_bf);

    // ---- Hs path: mx_s = Lmat . Hc_a (split-K=4, atomic) ----
    hipMemsetAsync(mx, 0, 4194304 * sizeof(float), stream);
    mfma_gemm<false,true,false,false,true,4><<<dim3(1,8,128), blk, 0, stream>>>(
        (const short*)Lmat_bf,1024,1048576, (const short*)HcA_bf,128,131072, mx,128,131072, nullptr, 1024,128,1024);
    rowops_s_kernel<<<32768, 64, 0, stream>>>(HsA, mx, xnrow, whs, lgs);

    // ---- Hc path: mx_cT = Hs_a^T . Lmat (A fast via transpose; split-K=4) ----
    thsa_kernel<<<dim3(32,4,32), dim3(32,8), 0, stream>>>(HsA_bf, HsAT);
    hipMemsetAsync(mx, 0, 4194304 * sizeof(float), stream);
    mfma_gemm<false,true,false,false,true,4><<<dim3(8,1,128), blk, 0, stream>>>(
        (const short*)HsAT,1024,131072, (const short*)Lmat_bf,1024,1048576, mx,1024,131072, nullptr, 128,1024,1024);
    colscale_kernel<<<dim3(32,4), 256, 0, stream>>>(mx, xncol);
    rowops_c_kernel<<<4096, 256, 0, stream>>>(HcA, mx);
    logitsc_kernel<<<dim3(32,4), 256, 0, stream>>>(mx, whc, lgc);

    // ---- softmaxes / centroids / concat ----
    softmax_kernel<<<32, 256, 0, stream>>>(lgs, AsOut);
    softmax_kernel<<<32, 256, 0, stream>>>(lgc, AcOut);
    centroidA_kernel<<<dim3(32,2,8), 320, 0, stream>>>(Ls_bf, Lc_bf, AsOut, AcOut, part_cent);
    centroidB_kernel<<<dim3(32,2), 320, 0, stream>>>(part_cent, co_s, co_c);
    final_kernel<<<32, 256, 0, stream>>>(co_s, co_c, out);
}

// Round 6
// 820.555 us; speedup vs baseline: 1.0142x; 1.0142x over previous
//
#include <hip/hip_runtime.h>
#include <cstdint>
#include <math.h>

#define NBATCH 32
#define NSQ 1024
#define NCQ 1024
#define DDIM 256
#define DP 257
#define KQ 128
#define KPAD 288   // 257 padded to /32

typedef __attribute__((ext_vector_type(8))) short short8;
typedef __attribute__((ext_vector_type(4))) float floatx4;

// ---------------- device helpers ----------------
__device__ __forceinline__ float bf2f(ushort u) { return __uint_as_float(((uint)u) << 16); }
__device__ __forceinline__ ushort f2bf(float f) {
    uint u = __float_as_uint(f);
    return (ushort)((u + 0x7FFFu + ((u >> 16) & 1u)) >> 16);
}
// async global->LDS, 16B per lane; LDS dest must be wave-uniform base + lane*16
__device__ __forceinline__ void gload16(const void* g, void* l) {
    __builtin_amdgcn_global_load_lds(
        (const __attribute__((address_space(1))) void*)g,
        (__attribute__((address_space(3))) void*)l,
        16, 0, 0);
}
__device__ __forceinline__ float artanh_clip(float x) {
    x = fminf(fmaxf(x, -1.0f + 1e-5f), 1.0f - 1e-5f);
    return 0.5f * (log1pf(x) - log1pf(-x));
}
__device__ __forceinline__ float gelu_f(float x) {
    return 0.5f * x * (1.0f + erff(x * 0.70710678118654752440f));
}
__device__ __forceinline__ float waveRedSum(float v) {
#pragma unroll
    for (int o = 32; o > 0; o >>= 1) v += __shfl_down(v, o, 64);
    return __shfl(v, 0, 64);
}
__device__ __forceinline__ float blockRedSum(float v, float* buf) {
    int lane = threadIdx.x & 63, wid = threadIdx.x >> 6;
#pragma unroll
    for (int o = 32; o > 0; o >>= 1) v += __shfl_down(v, o, 64);
    __syncthreads();
    if (lane == 0) buf[wid] = v;
    __syncthreads();
    int nw = blockDim.x >> 6;
    float s = buf[0];
    for (int i = 1; i < nw; i++) s += buf[i];
    return s;
}
__device__ __forceinline__ float blockRedMax(float v, float* buf) {
    int lane = threadIdx.x & 63, wid = threadIdx.x >> 6;
#pragma unroll
    for (int o = 32; o > 0; o >>= 1) v = fmaxf(v, __shfl_down(v, o, 64));
    __syncthreads();
    if (lane == 0) buf[wid] = v;
    __syncthreads();
    int nw = blockDim.x >> 6;
    float s = buf[0];
    for (int i = 1; i < nw; i++) s = fmaxf(s, buf[i]);
    return s;
}

// ---------------- bf16 MFMA GEMM ----------------
// C[m,n] = sum_k A[m,k]*B'[k,n] (+bias[n])
// A_NN=false: A is (M x K) row-major (fast path, async LDS). A_NN=true: A stored (K x M).
// B_NN=false: B is (N x K) row-major (fast path).            B_NN=true: B stored (K x N).
// NSPLIT: split-K; blockIdx.z = batch*NSPLIT + ksplit; ATOMIC epilogue for split-K.
template <bool A_NN, bool B_NN, bool OUT_BF16, bool BIAS, bool ATOMIC, int NSPLIT>
__global__ __launch_bounds__(256) void mfma_gemm(
    const short* __restrict__ A, int lda, int64_t sA,
    const short* __restrict__ B, int ldb, int64_t sB,
    void* __restrict__ Cv, int ldc, int64_t sC,
    const float* __restrict__ bias, int M, int N, int K)
{
    __shared__ short As[128][32];
    __shared__ short Bs[128][32];
    const int zz = blockIdx.z;
    const int zb = zz / NSPLIT;
    const int ks = zz - zb * NSPLIT;
    A += (int64_t)zb * sA;
    B += (int64_t)zb * sB;
    const int kper = K / NSPLIT;
    const int kbeg = ks * kper, kend = kbeg + kper;
    const int m0 = blockIdx.y * 128, n0 = blockIdx.x * 128;
    const int t = threadIdx.x;
    const int lane = t & 63, w = t >> 6;
    const int wm = (w & 1) * 64, wn = (w >> 1) * 64;
    floatx4 acc[4][4] = {};
    for (int k0 = kbeg; k0 < kend; k0 += 32) {
        // ---- stage A tile -> As[m][k] ----
        if (!A_NN) {
            int r = t >> 2, c8 = (t & 3) * 8;
            const short* ap = A + (int64_t)(m0 + r) * lda + k0 + c8;
            gload16(ap, &As[r][c8]);
            gload16(ap + (int64_t)64 * lda, &As[r + 64][c8]);
        } else {
            int r2 = t >> 4, c8 = (t & 15) * 8;
            int kk = 2 * r2;
            const ushort* a0 = (const ushort*)A + (int64_t)(k0 + kk) * lda + m0 + c8;
            uint4 v0 = *(const uint4*)a0;
            uint4 v1 = *(const uint4*)(a0 + lda);
            const ushort* p0 = (const ushort*)&v0;
            const ushort* p1 = (const ushort*)&v1;
#pragma unroll
            for (int i = 0; i < 8; i++) {
                uint pk = (uint)p0[i] | ((uint)p1[i] << 16);
                *(uint*)&As[c8 + i][kk] = pk;
            }
        }
        // ---- stage B tile -> Bs[n][k] ----
        if (!B_NN) {
            int r = t >> 2, c8 = (t & 3) * 8;
            const short* bp = B + (int64_t)(n0 + r) * ldb + k0 + c8;
            gload16(bp, &Bs[r][c8]);
            gload16(bp + (int64_t)64 * ldb, &Bs[r + 64][c8]);
        } else {
            int r2 = t >> 4, c8 = (t & 15) * 8;
            int kk = 2 * r2;
            const ushort* b0 = (const ushort*)B + (int64_t)(k0 + kk) * ldb + n0 + c8;
            uint4 v0 = *(const uint4*)b0;
            uint4 v1 = *(const uint4*)(b0 + ldb);
            const ushort* p0 = (const ushort*)&v0;
            const ushort* p1 = (const ushort*)&v1;
#pragma unroll
            for (int i = 0; i < 8; i++) {
                uint pk = (uint)p0[i] | ((uint)p1[i] << 16);
                *(uint*)&Bs[c8 + i][kk] = pk;
            }
        }
        __syncthreads();
        short8 af[4], bfv[4];
#pragma unroll
        for (int i = 0; i < 4; i++)
            af[i] = *(const short8*)&As[wm + 16 * i + (lane & 15)][8 * (lane >> 4)];
#pragma unroll
        for (int i = 0; i < 4; i++)
            bfv[i] = *(const short8*)&Bs[wn + 16 * i + (lane & 15)][8 * (lane >> 4)];
#pragma unroll
        for (int i = 0; i < 4; i++)
#pragma unroll
            for (int j = 0; j < 4; j++)
                acc[i][j] = __builtin_amdgcn_mfma_f32_16x16x32_bf16(af[i], bfv[j], acc[i][j], 0, 0, 0);
        __syncthreads();
    }
    // ---- epilogue: D row=(lane>>4)*4+reg, col=lane&15 ----
    const int q = lane >> 4, c = lane & 15;
#pragma unroll
    for (int j = 0; j < 4; j++) {
        int col = n0 + wn + 16 * j + c;
        float bv = BIAS ? bias[col] : 0.0f;
#pragma unroll
        for (int i = 0; i < 4; i++) {
            int rowb = m0 + wm + 16 * i + 4 * q;
#pragma unroll
            for (int r = 0; r < 4; r++) {
                float v = acc[i][j][r] + bv;
                int64_t idx = (int64_t)zb * sC + (int64_t)(rowb + r) * ldc + col;
                if (ATOMIC)       atomicAdd((float*)Cv + idx, v);
                else if (OUT_BF16) ((ushort*)Cv)[idx] = f2bf(v);
                else               ((float*)Cv)[idx] = v;
            }
        }
    }
}

// ---------------- fused constants: DFT matrices + weight prep ----------------
__global__ __launch_bounds__(256) void genconst_kernel(
    ushort* CS1, ushort* C2, ushort* S2,
    const float* __restrict__ WlW, const float* __restrict__ WsW, const float* __restrict__ WcW,
    ushort* Wl, ushort* Ws, ushort* Wc)
{
    int blk = blockIdx.x, t = threadIdx.x;
    if (blk < 4096) {
        int idx = blk * 256 + t;                     // 1024x1024
        int n = idx >> 10, m = idx & 1023;
        int p = (n * m) & 1023;
        float ang = (6.28318530717958647692f / 1024.0f) * (float)p;
        CS1[n * 2048 + m] = f2bf(cosf(ang));
        CS1[n * 2048 + 1024 + m] = f2bf(-sinf(ang));
    } else if (blk < 4352) {
        int idx = (blk - 4096) * 256 + t;            // 256x256
        int d = idx >> 8, j = idx & 255;
        int p = (d * j) & 255;
        float ang = (6.28318530717958647692f / 256.0f) * (float)p;
        C2[idx] = f2bf(cosf(ang));
        S2[idx] = f2bf(sinf(ang));
    } else {
        int r = blk - 4352;                          // 512 rows
        const float* src; ushort* dst; int srow;
        if (r < 256)      { src = WlW; dst = Wl + r * KPAD;        srow = r + 1; }
        else if (r < 384) { src = WsW; dst = Ws + (r - 256) * KPAD; srow = r - 256 + 1; }
        else              { src = WcW; dst = Wc + (r - 384) * KPAD; srow = r - 384 + 1; }
        dst[t] = (t < DP) ? f2bf(src[(int64_t)srow * DP + t]) : (ushort)0;
        if (t < KPAD - 256) {
            int t2 = t + 256;
            dst[t2] = (t2 < DP) ? f2bf(src[(int64_t)srow * DP + t2]) : (ushort)0;
        }
    }
}

// fused input prep: rows 0..32767 = cast(sent), rows 32768..65535 = p_logmap0(comm)
__global__ __launch_bounds__(256) void prep_in_kernel(const float* __restrict__ sent,
                                                      const float* __restrict__ comm,
                                                      ushort* __restrict__ outp) {
    __shared__ float red[4];
    int64_t row = blockIdx.x; int t = threadIdx.x;
    if (row < 32768) {
        outp[row * 256 + t] = f2bf(sent[row * 256 + t]);
        return;
    }
    const float* src = comm + (row - 32768) * 256;
    float v = src[t];
    float s = blockRedSum(v * v, red);
    float yn = sqrtf(fmaxf(s, 1e-15f));
    float fac = artanh_clip(yn) / yn;
    outp[row * 256 + t] = f2bf(fac * v);
}

// euclid_to_lorentz: bf16 rows 256 -> bf16 rows 288 (time at 0), split Ls/Lc
__global__ __launch_bounds__(256) void e2l_kernel(const ushort* __restrict__ in,
                                                  ushort* __restrict__ Lsb, ushort* __restrict__ Lcb) {
    __shared__ float red[4];
    int64_t row = blockIdx.x; int t = threadIdx.x;   // row in [0, 65536)
    float v = bf2f(in[row * 256 + t]);
    float s = blockRedSum(v * v, red);
    float xn = sqrtf(fmaxf(s, 1e-15f)) + 1e-5f;
    float sc = fminf(1.0f, 2.0f / xn);
    float xs = v * sc;
    float s2 = fmaxf(s * sc * sc, 1e-15f);
    float vn = sqrtf(s2);
    float fac = sinhf(vn) / vn;
    ushort* ob = (row < 32768 ? Lsb + row * KPAD : Lcb + (row - 32768) * KPAD);
    if (t == 0) ob[0] = f2bf(coshf(vn));
    ob[1 + t] = f2bf(fac * xs);
    if (t < KPAD - DP) ob[DP + t] = 0;
}

// lorentz_linear space (fp32, 256) -> bf16 row 288 with time at col 0
__global__ __launch_bounds__(256) void lfix2_kernel(const float* __restrict__ sp, ushort* __restrict__ obf) {
    __shared__ float red[4];
    int64_t row = blockIdx.x; int t = threadIdx.x;
    float v = sp[row * 256 + t];
    float s = blockRedSum(v * v, red);
    ushort* ob = obf + row * KPAD;
    if (t == 0) ob[0] = f2bf(sqrtf(s + 1.0f));
    ob[1 + t] = f2bf(v);
    if (t < KPAD - DP) ob[DP + t] = 0;
}

// lorentz_linear(K) space + bias + to_poincare; rows 0..32767 Ws path, rest Wc
__global__ __launch_bounds__(128) void poinc2_kernel(const float* __restrict__ sp,
                                                     const float* __restrict__ Wsb, const float* __restrict__ Wcb,
                                                     float* __restrict__ o32, ushort* __restrict__ obf) {
    __shared__ float red[2];
    int64_t row = blockIdx.x; int t = threadIdx.x;
    const float* bias = (row < 32768 ? Wsb : Wcb);
    float v = sp[row * KQ + t] + bias[1 + t];
    float s = blockRedSum(v * v, red);
    float tim = sqrtf(s + 1.0f);
    float o = v / (tim + 1.0f);
    o32[row * KQ + t] = o;
    obf[row * KQ + t] = f2bf(o);
}

// lorentz_act on bf16 Lmat rows (1024), in place, + xnrow
__global__ __launch_bounds__(256) void lact_kernel(ushort* __restrict__ Lmat, float* __restrict__ xnrow) {
    __shared__ float red[4];
    int64_t row = blockIdx.x; int t = threadIdx.x;
    ushort* r = Lmat + row * (int64_t)NCQ;
    ushort4 u = *(ushort4*)&r[4 * t];
    float v[4] = {bf2f(u.x), bf2f(u.y), bf2f(u.z), bf2f(u.w)};
    float g[4]; float s = 0.f;
#pragma unroll
    for (int i = 0; i < 4; i++) {
        int idx = 4 * t + i;
        if (idx > 0) { g[i] = gelu_f(v[i]); s += g[i] * g[i]; } else g[i] = 0.f;
    }
    s = blockRedSum(s, red);
    if (t == 0) g[0] = sqrtf(1.0f + s);
    ushort4 o; o.x = f2bf(g[0]); o.y = f2bf(g[1]); o.z = f2bf(g[2]); o.w = f2bf(g[3]);
    *(ushort4*)&r[4 * t] = o;
    if (t == 0) xnrow[row] = sqrtf(fmaxf(1.0f + 2.0f * s, 1e-15f));
}

// column-norm stage A/B
__global__ __launch_bounds__(256) void colnormA_kernel(const ushort* __restrict__ Lmat, float* __restrict__ part) {
    int b = blockIdx.x, chunk = blockIdx.y, t = threadIdx.x;
    const ushort* base = Lmat + (int64_t)b * NSQ * NCQ + (int64_t)chunk * 128 * NCQ + 4 * t;
    float s0 = 0.f, s1 = 0.f, s2 = 0.f, s3 = 0.f;
    for (int n = 0; n < 128; n++) {
        ushort4 u = *(const ushort4*)(base + (int64_t)n * NCQ);
        float a = bf2f(u.x), bb = bf2f(u.y), c = bf2f(u.z), d = bf2f(u.w);
        s0 += a * a; s1 += bb * bb; s2 += c * c; s3 += d * d;
    }
    float4 o = {s0, s1, s2, s3};
    *(float4*)(part + ((int64_t)(b * 8 + chunk)) * 4096 + 4 * t) = o;
}
__global__ __launch_bounds__(256) void colnormB_kernel(const float* __restrict__ part, float* __restrict__ xncol) {
    int b = blockIdx.x; int m = blockIdx.y * 256 + threadIdx.x;
    const float* p = part + (int64_t)b * 8 * 4096 + m;
    float s = 0.f;
#pragma unroll
    for (int c = 0; c < 8; c++) s += p[c * 4096];
    xncol[b * NCQ + m] = sqrtf(fmaxf(s, 1e-15f));
}

// Hs path rowwise chain -> logits
__global__ __launch_bounds__(64) void rowops_s_kernel(
    const float* __restrict__ Hsa, const float* __restrict__ mxs,
    const float* __restrict__ xnrow, const float* __restrict__ whs,
    float* __restrict__ logits)
{
    int64_t row = blockIdx.x; int t = threadIdx.x;
    const float* p = Hsa + row * KQ;
    const float* q = mxs + row * KQ;
    float p0 = p[t], p1 = p[t + 64], q0 = q[t], q1 = q[t + 64];
    float mxn = sqrtf(fmaxf(waveRedSum(q0 * q0 + q1 * q1), 1e-15f));
    float xn = xnrow[row];
    float fac = tanhf(mxn / xn * artanh_clip(xn)) / mxn;
    float y0 = fac * q0, y1 = fac * q1;
    float xy = waveRedSum(p0 * y0 + p1 * y1);
    float x2 = waveRedSum(p0 * p0 + p1 * p1);
    float y2 = waveRedSum(y0 * y0 + y1 * y1);
    float ca = 1.f + 2.f * xy + y2, cb = 1.f - x2;
    float den = fmaxf(1.f + 2.f * xy + x2 * y2, 1e-15f);
    float h0 = (ca * p0 + cb * y0) / den, h1 = (ca * p1 + cb * y1) / den;
    float hn = sqrtf(fmaxf(waveRedSum(h0 * h0 + h1 * h1), 1e-15f));
    float uf = artanh_clip(hn) / hn;
    float g0 = gelu_f(uf * h0), g1 = gelu_f(uf * h1);
    float gn = sqrtf(fmaxf(waveRedSum(g0 * g0 + g1 * g1), 1e-15f));
    float ef = tanhf(gn) / gn;
    float H0 = ef * g0, H1 = ef * g1;
    float dot = waveRedSum(H0 * whs[t] + H1 * whs[t + 64]);
    float Hn = sqrtf(fmaxf(waveRedSum(H0 * H0 + H1 * H1), 1e-15f));
    float mxn2 = sqrtf(fmaxf(dot * dot, 1e-15f));
    float lg = tanhf(mxn2 / Hn * artanh_clip(Hn)) * dot / mxn2;
    if (t == 0) logits[row] = lg;
}

// transpose (z batches of 1024x128) -> (z batches of 128x1024); in/out contiguous over z
__global__ void thsa_kernel(const ushort* __restrict__ in, ushort* __restrict__ outp) {
    __shared__ ushort tile[32][33];
    int z = blockIdx.z;
    int n0 = blockIdx.x * 32, j0 = blockIdx.y * 32;
    const ushort* ib = in + (int64_t)z * 131072;
    ushort* ob = outp + (int64_t)z * 131072;
    int tx = threadIdx.x, ty = threadIdx.y;
    for (int i = 0; i < 32; i += 8) tile[ty + i][tx] = ib[(n0 + ty + i) * 128 + j0 + tx];
    __syncthreads();
    for (int i = 0; i < 32; i += 8) ob[(j0 + ty + i) * 1024 + n0 + tx] = tile[tx][ty + i];
}

// mobius_matvec scale on mx_cT columns
__global__ __launch_bounds__(256) void colscale_kernel(float* __restrict__ mxcT, const float* __restrict__ xncol) {
    int b = blockIdx.x; int m = blockIdx.y * 256 + threadIdx.x;
    float* base = mxcT + (int64_t)b * KQ * NCQ + m;
    float s = 0.f;
    for (int j = 0; j < KQ; j++) { float v = base[j * NCQ]; s += v * v; }
    float mxn = sqrtf(fmaxf(s, 1e-15f));
    float xn = xncol[b * NCQ + m];
    float fac = tanhf(mxn / xn * artanh_clip(xn)) / mxn;
    for (int j = 0; j < KQ; j++) base[j * NCQ] *= fac;
}

// Hc path rowwise chain (per (b,k) over NC), in place on y
__global__ __launch_bounds__(256) void rowops_c_kernel(const float* __restrict__ HcA, float* __restrict__ y) {
    __shared__ float red[4];
    int64_t row = blockIdx.x;
    int b = (int)(row >> 7), k = (int)(row & 127);
    const float* xbase = HcA + (int64_t)b * NCQ * KQ + k;
    float* yr = y + row * (int64_t)NCQ;
    int t = threadIdx.x;
    float xv[4], yv[4];
    float xy = 0.f, x2 = 0.f, y2 = 0.f;
#pragma unroll
    for (int i = 0; i < 4; i++) {
        int m = t + 256 * i;
        xv[i] = xbase[(int64_t)m * KQ]; yv[i] = yr[m];
        xy += xv[i] * yv[i]; x2 += xv[i] * xv[i]; y2 += yv[i] * yv[i];
    }
    xy = blockRedSum(xy, red);
    x2 = blockRedSum(x2, red);
    y2 = blockRedSum(y2, red);
    float ca = 1.f + 2.f * xy + y2, cb = 1.f - x2;
    float den = fmaxf(1.f + 2.f * xy + x2 * y2, 1e-15f);
    float h[4]; float hn2 = 0.f;
#pragma unroll
    for (int i = 0; i < 4; i++) { h[i] = (ca * xv[i] + cb * yv[i]) / den; hn2 += h[i] * h[i]; }
    hn2 = blockRedSum(hn2, red);
    float hn = sqrtf(fmaxf(hn2, 1e-15f));
    float uf = artanh_clip(hn) / hn;
    float g[4]; float gn2 = 0.f;
#pragma unroll
    for (int i = 0; i < 4; i++) { g[i] = gelu_f(uf * h[i]); gn2 += g[i] * g[i]; }
    gn2 = blockRedSum(gn2, red);
    float gn = sqrtf(fmaxf(gn2, 1e-15f));
    float ef = tanhf(gn) / gn;
#pragma unroll
    for (int i = 0; i < 4; i++) yr[t + 256 * i] = ef * g[i];
}

// Ac logits
__global__ __launch_bounds__(256) void logitsc_kernel(const float* __restrict__ Hc, const float* __restrict__ whc, float* __restrict__ lgc) {
    int b = blockIdx.x; int m = blockIdx.y * 256 + threadIdx.x;
    const float* base = Hc + (int64_t)b * KQ * NCQ + m;
    float s1 = 0.f, s2 = 0.f;
    for (int j = 0; j < KQ; j++) { float v = base[j * NCQ]; s1 += v * whc[j]; s2 += v * v; }
    float xn = sqrtf(fmaxf(s2, 1e-15f));
    float mxn = sqrtf(fmaxf(s1 * s1, 1e-15f));
    lgc[b * NCQ + m] = tanhf(mxn / xn * artanh_clip(xn)) * s1 / mxn;
}

// fused softmax for lgs|lgc (contiguous) -> AsOut|AcOut (contiguous), grid 64
__global__ __launch_bounds__(256) void softmax_kernel(const float* __restrict__ lg, float* __restrict__ outp) {
    __shared__ float red[4];
    int b = blockIdx.x; int t = threadIdx.x;
    const float* x = lg + b * 1024;
    float v[4]; float m = -1e30f;
#pragma unroll
    for (int i = 0; i < 4; i++) { v[i] = x[t + 256 * i]; m = fmaxf(m, v[i]); }
    m = blockRedMax(m, red);
    float s = 0.f;
#pragma unroll
    for (int i = 0; i < 4; i++) { v[i] = expf(v[i] - m); s += v[i]; }
    s = blockRedSum(s, red);
    float inv = 1.0f / s;
#pragma unroll
    for (int i = 0; i < 4; i++) outp[b * 1024 + t + 256 * i] = v[i] * inv;
}

// centroid stage A on bf16 L (stride 288, time at col 0)
__global__ __launch_bounds__(320) void centroidA_kernel(
    const ushort* __restrict__ Lsb, const ushort* __restrict__ Lcb,
    const float* __restrict__ As, const float* __restrict__ Ac,
    float* __restrict__ part)
{
    int b = blockIdx.x;
    int which = blockIdx.y;
    int chunk = blockIdx.z;
    const ushort* L = which ? Lcb : Lsb;
    const float* w = which ? Ac : As;
    int t = threadIdx.x;
    if (t >= DP) return;
    const ushort* Lb = L + (int64_t)b * NSQ * KPAD + (int64_t)chunk * 128 * KPAD + t;
    const float* wb = w + b * NSQ + chunk * 128;
    float s = 0.f;
    for (int n = 0; n < 128; n++) s += wb[n] * bf2f(Lb[(int64_t)n * KPAD]);
    part[((int64_t)((b * 2 + which) * 8 + chunk)) * 264 + t] = s;
}
__global__ __launch_bounds__(320) void centroidB_kernel(
    const float* __restrict__ part, float* __restrict__ co_s, float* __restrict__ co_c)
{
    int b = blockIdx.x;
    int which = blockIdx.y;
    int t = threadIdx.x;
    if (t >= DP) return;
    const float* p = part + (int64_t)(b * 2 + which) * 8 * 264 + t;
    float s = 0.f;
#pragma unroll
    for (int c = 0; c < 8; c++) s += p[c * 264];
    (which ? co_c : co_s)[b * DP + t] = s;
}

__global__ __launch_bounds__(256) void final_kernel(const float* __restrict__ co_s, const float* __restrict__ co_c, float* __restrict__ outp) {
    __shared__ float red[4];
    int b = blockIdx.x, t = threadIdx.x;
    float zmine[2];
    for (int w = 0; w < 2; w++) {
        const float* co = (w ? co_c : co_s) + b * DP;
        float at = co[0];
        float asp = co[1 + t];
        float ssp = blockRedSum(asp * asp, red);
        float li = ssp - at * at;
        float den = sqrtf(fmaxf(fabsf(li), 1e-8f));
        float xt = at / den, xsp = asp / den;
        float s2 = blockRedSum(xsp * xsp, red);
        float nrm = sqrtf(fmaxf(s2, 1e-15f));
        float ac = acoshf(fmaxf(xt, 1.0f + 1e-7f));
        zmine[w] = ac * xsp / nrm;
    }
    float vn2 = blockRedSum(zmine[0] * zmine[0] + zmine[1] * zmine[1], red);
    float vn = sqrtf(fmaxf(vn2, 1e-15f));
    float sc = sinhf(vn) / vn;
    if (t == 0) outp[b * 513] = coshf(vn);
    outp[b * 513 + 1 + t] = sc * zmine[0];
    outp[b * 513 + 1 + 256 + t] = sc * zmine[1];
}

// ---------------- host launcher ----------------
extern "C" void kernel_launch(void* const* d_in, const int* in_sizes, int n_in,
                              void* d_out, int out_size, void* d_ws, size_t ws_size,
                              hipStream_t stream)
{
    const float* sent = (const float*)d_in[0];
    const float* comm = (const float*)d_in[1];
    const float* WlW  = (const float*)d_in[2];
    const float* Wlb  = (const float*)d_in[3];
    const float* WcW  = (const float*)d_in[4];
    const float* Wcb  = (const float*)d_in[5];
    const float* WsW  = (const float*)d_in[6];
    const float* Wsb  = (const float*)d_in[7];
    const float* whs  = (const float*)d_in[8];
    const float* whc  = (const float*)d_in[9];
    float* out = (float*)d_out;
    (void)in_sizes; (void)n_in; (void)out_size; (void)ws_size;

    float* ws = (float*)d_ws;
    size_t off = 0;
    auto take = [&](size_t n) { float* p = ws + off; off += n; return p; };
    float*  xnrow = take(32768);
    float*  xncol = take(32768);
    float*  lgs   = take(32768);   // contiguous with lgc
    float*  lgc   = take(32768);
    float*  co_s  = take(8224);
    float*  co_c  = take(8224);
    ushort* Ls_bf = (ushort*)take(4718592);   // contiguous with Lc_bf
    ushort* Lc_bf = (ushort*)take(4718592);
    ushort* Wl_bf = (ushort*)take(36864);
    ushort* Ws_bf = (ushort*)take(18432);
    ushort* Wc_bf = (ushort*)take(18432);
    ushort* HsA_bf = (ushort*)take(2097152);  // contiguous with HcA_bf
    ushort* HcA_bf = (ushort*)take(2097152);
    float*  part_cn   = take(1048576);
    float*  part_cent = take(135168);
    float*  F     = take(33554432);           // total 48.6M fl = 185 MiB

    // Phase overlays in F (float offsets)
    ushort* Xin_bf  = (ushort*)F;                 // [P1] 8.39M fl (64 x 1024 x 256)
    ushort* ZT_bf   = (ushort*)(F + 8388608);     // [P1] 16.78M fl (64 x 256 x 2048)
    ushort* CS1     = (ushort*)(F + 25165824);    // [P1] 1.05M fl
    ushort* C2_bf   = (ushort*)(F + 26214400);    // [P1] 32k fl
    ushort* S2_bf   = (ushort*)(F + 26247168);    // [P1] 32k fl
    ushort* Yst_bf  = (ushort*)F;                 // [P1] aliases Xin (dead after stage-1)
    ushort* Lmat_bf = (ushort*)F;                 // [P3-P5] 16.78M fl
    float*  Llin_sp = F + 16777216;               // [P2] 8.39M fl
    ushort* Llin_bf = (ushort*)(F + 25165824);    // [P2-P3] 4.72M fl
    float*  ycat    = F + 16777216;               // [P4] 8.39M fl (ys | yc)
    float*  HsA     = F + 25165824;               // [P4-P5] 4.19M fl
    float*  HcA     = F + 29360128;               // [P4-P5] 4.19M fl
    float*  mx      = F + 16777216;               // [P5] 4.19M fl
    ushort* HsAT    = (ushort*)(F + 20971520);    // [P5] 2.1M fl, contiguous with HcAT
    ushort* HcAT    = (ushort*)(F + 23068672);    // [P5] 2.1M fl

    float* AsOut = out + 16416;
    float* AcOut = out + 16416 + 32768;

    dim3 blk(256);

    // constants (CS1, C2/S2, weight prep) in one launch
    genconst_kernel<<<4864, 256, 0, stream>>>(CS1, C2_bf, S2_bf, WlW, WsW, WcW, Wl_bf, Ws_bf, Wc_bf);

    // ---- merged input prep + fft2 (sent batches 0-31, comment 32-63) ----
    prep_in_kernel<<<65536, 256, 0, stream>>>(sent, comm, Xin_bf);
    // stage-1 (TN): ZT[j,m] = sum_d C2[j,d]*X[m,d]
    mfma_gemm<false,false,true,false,false,1><<<dim3(8,2,64), blk, 0, stream>>>(
        (const short*)C2_bf,256,0, (const short*)Xin_bf,256,262144, ZT_bf,2048,524288, nullptr, 256,1024,256);
    mfma_gemm<false,false,true,false,false,1><<<dim3(8,2,64), blk, 0, stream>>>(
        (const short*)S2_bf,256,0, (const short*)Xin_bf,256,262144, ZT_bf+1024,2048,524288, nullptr, 256,1024,256);
    // stage-2 (TN, K=2048), bf16 out into Yst (aliases Xin)
    mfma_gemm<false,false,true,false,false,1><<<dim3(2,8,64), blk, 0, stream>>>(
        (const short*)CS1,2048,0, (const short*)ZT_bf,2048,524288, Yst_bf,256,262144, nullptr, 1024,256,2048);
    e2l_kernel<<<65536, 256, 0, stream>>>(Yst_bf, Ls_bf, Lc_bf);

    // ---- L = lorentz_linear(Lc, Wl): space cols only ----
    mfma_gemm<false,false,false,true,false,1><<<dim3(2,256,1), blk, 0, stream>>>(
        (const short*)Lc_bf,KPAD,0, (const short*)Wl_bf,KPAD,0, Llin_sp,256,0, Wlb+1, 32768,256,KPAD);
    lfix2_kernel<<<32768, 256, 0, stream>>>(Llin_sp, Llin_bf);

    // ---- Lmat = lorentz_act(einsum(Ls, Llin)) in bf16 ----
    mfma_gemm<false,false,true,false,false,1><<<dim3(8,8,32), blk, 0, stream>>>(
        (const short*)Ls_bf,KPAD,294912, (const short*)Llin_bf,KPAD,294912, Lmat_bf,1024,1048576, nullptr, 1024,1024,KPAD);
    lact_kernel<<<32768, 256, 0, stream>>>(Lmat_bf, xnrow);
    colnormA_kernel<<<dim3(32,8), 256, 0, stream>>>(Lmat_bf, part_cn);
    colnormB_kernel<<<dim3(32,4), 256, 0, stream>>>(part_cn, xncol);

    // ---- Hs_a / Hc_a merged (z=0: Ls*Ws, z=1: Lc*Wc), bias in poinc2 ----
    mfma_gemm<false,false,false,false,false,1><<<dim3(1,256,2), blk, 0, stream>>>(
        (const short*)Ls_bf,KPAD,9437184, (const short*)Ws_bf,KPAD,36864, ycat,128,4194304, nullptr, 32768,128,KPAD);
    poinc2_kernel<<<65536, 128, 0, stream>>>(ycat, Wsb, Wcb, HsA, HsA_bf);

    // ---- transpose HsA_bf and HcA_bf (contiguous) in one launch ----
    thsa_kernel<<<dim3(32,4,64), dim3(32,8), 0, stream>>>(HsA_bf, HsAT);

    // ---- Hs path: mx_s = Lmat . Hc_a (fast TT via HcAT; split-K=4, atomic) ----
    hipMemsetAsync(mx, 0, 4194304 * sizeof(float), stream);
    mfma_gemm<false,false,false,false,true,4><<<dim3(1,8,128), blk, 0, stream>>>(
        (const short*)Lmat_bf,1024,1048576, (const short*)HcAT,1024,131072, mx,128,131072, nullptr, 1024,128,1024);
    rowops_s_kernel<<<32768, 64, 0, stream>>>(HsA, mx, xnrow, whs, lgs);

    // ---- Hc path: mx_cT = Hs_a^T . Lmat (A fast via HsAT; split-K=4) ----
    hipMemsetAsync(mx, 0, 4194304 * sizeof(float), stream);
    mfma_gemm<false,true,false,false,true,4><<<dim3(8,1,128), blk, 0, stream>>>(
        (const short*)HsAT,1024,131072, (const short*)Lmat_bf,1024,1048576, mx,1024,131072, nullptr, 128,1024,1024);
    colscale_kernel<<<dim3(32,4), 256, 0, stream>>>(mx, xncol);
    rowops_c_kernel<<<4096, 256, 0, stream>>>(HcA, mx);
    logitsc_kernel<<<dim3(32,4), 256, 0, stream>>>(mx, whc, lgc);

    // ---- fused softmaxes / centroids / concat ----
    softmax_kernel<<<64, 256, 0, stream>>>(lgs, AsOut);
    centroidA_kernel<<<dim3(32,2,8), 320, 0, stream>>>(Ls_bf, Lc_bf, AsOut, AcOut, part_cent);
    centroidB_kernel<<<dim3(32,2), 320, 0, stream>>>(part_cent, co_s, co_c);
    final_kernel<<<32, 256, 0, stream>>>(co_s, co_c, out);
}

// Round 7
// 755.173 us; speedup vs baseline: 1.1020x; 1.0866x over previous
//
#include <hip/hip_runtime.h>
#include <cstdint>
#include <math.h>

#define NBATCH 32
#define NSQ 1024
#define NCQ 1024
#define DDIM 256
#define DP 257
#define KQ 128
#define KPAD 288   // 257 padded to /32
#define KF 1280    // folded stage-2 K (513 cos + 127 pad + 512 sin + 128 pad)
#define NFOLD 640  // folded m rows per batch (513 padded to /128)

typedef __attribute__((ext_vector_type(8))) short short8;
typedef __attribute__((ext_vector_type(4))) float floatx4;

// ---------------- device helpers ----------------
__device__ __forceinline__ float bf2f(ushort u) { return __uint_as_float(((uint)u) << 16); }
__device__ __forceinline__ ushort f2bf(float f) {
    uint u = __float_as_uint(f);
    return (ushort)((u + 0x7FFFu + ((u >> 16) & 1u)) >> 16);
}
// async global->LDS, 16B per lane; LDS dest = wave-uniform base + lane*16
__device__ __forceinline__ void gload16(const void* g, void* l) {
    __builtin_amdgcn_global_load_lds(
        (const __attribute__((address_space(1))) void*)g,
        (__attribute__((address_space(3))) void*)l,
        16, 0, 0);
}
__device__ __forceinline__ float artanh_clip(float x) {
    x = fminf(fmaxf(x, -1.0f + 1e-5f), 1.0f - 1e-5f);
    return 0.5f * (log1pf(x) - log1pf(-x));
}
__device__ __forceinline__ float gelu_f(float x) {
    return 0.5f * x * (1.0f + erff(x * 0.70710678118654752440f));
}
__device__ __forceinline__ float waveRedSum(float v) {
#pragma unroll
    for (int o = 32; o > 0; o >>= 1) v += __shfl_down(v, o, 64);
    return __shfl(v, 0, 64);
}
__device__ __forceinline__ float blockRedSum(float v, float* buf) {
    int lane = threadIdx.x & 63, wid = threadIdx.x >> 6;
#pragma unroll
    for (int o = 32; o > 0; o >>= 1) v += __shfl_down(v, o, 64);
    __syncthreads();
    if (lane == 0) buf[wid] = v;
    __syncthreads();
    int nw = blockDim.x >> 6;
    float s = buf[0];
    for (int i = 1; i < nw; i++) s += buf[i];
    return s;
}
__device__ __forceinline__ float blockRedMax(float v, float* buf) {
    int lane = threadIdx.x & 63, wid = threadIdx.x >> 6;
#pragma unroll
    for (int o = 32; o > 0; o >>= 1) v = fmaxf(v, __shfl_down(v, o, 64));
    __syncthreads();
    if (lane == 0) buf[wid] = v;
    __syncthreads();
    int nw = blockDim.x >> 6;
    float s = buf[0];
    for (int i = 1; i < nw; i++) s = fmaxf(s, buf[i]);
    return s;
}

// ---------------- bf16 MFMA GEMM ----------------
// C[m,n] = sum_k A[m,k]*B'[k,n] (+bias[n])
// A_NN=false: A is (M x K) row-major (fast path, async LDS). A_NN=true: A stored (K x M).
// B_NN=false: B is (N x K) row-major (fast path).            B_NN=true: B stored (K x N).
// NSPLIT: split-K; blockIdx.z = batch*NSPLIT + ksplit; ATOMIC epilogue for split-K.
template <bool A_NN, bool B_NN, bool OUT_BF16, bool BIAS, bool ATOMIC, int NSPLIT>
__global__ __launch_bounds__(256) void mfma_gemm(
    const short* __restrict__ A, int lda, int64_t sA,
    const short* __restrict__ B, int ldb, int64_t sB,
    void* __restrict__ Cv, int ldc, int64_t sC,
    const float* __restrict__ bias, int M, int N, int K)
{
    __shared__ short As[128][32];
    __shared__ short Bs[128][32];
    const int zz = blockIdx.z;
    const int zb = zz / NSPLIT;
    const int ks = zz - zb * NSPLIT;
    A += (int64_t)zb * sA;
    B += (int64_t)zb * sB;
    const int kper = K / NSPLIT;
    const int kbeg = ks * kper, kend = kbeg + kper;
    const int m0 = blockIdx.y * 128, n0 = blockIdx.x * 128;
    const int t = threadIdx.x;
    const int lane = t & 63, w = t >> 6;
    const int wm = (w & 1) * 64, wn = (w >> 1) * 64;
    floatx4 acc[4][4] = {};
    for (int k0 = kbeg; k0 < kend; k0 += 32) {
        if (!A_NN) {
            int r = t >> 2, c8 = (t & 3) * 8;
            const short* ap = A + (int64_t)(m0 + r) * lda + k0 + c8;
            gload16(ap, &As[r][c8]);
            gload16(ap + (int64_t)64 * lda, &As[r + 64][c8]);
        } else {
            int r2 = t >> 4, c8 = (t & 15) * 8;
            int kk = 2 * r2;
            const ushort* a0 = (const ushort*)A + (int64_t)(k0 + kk) * lda + m0 + c8;
            uint4 v0 = *(const uint4*)a0;
            uint4 v1 = *(const uint4*)(a0 + lda);
            const ushort* p0 = (const ushort*)&v0;
            const ushort* p1 = (const ushort*)&v1;
#pragma unroll
            for (int i = 0; i < 8; i++) {
                uint pk = (uint)p0[i] | ((uint)p1[i] << 16);
                *(uint*)&As[c8 + i][kk] = pk;
            }
        }
        if (!B_NN) {
            int r = t >> 2, c8 = (t & 3) * 8;
            const short* bp = B + (int64_t)(n0 + r) * ldb + k0 + c8;
            gload16(bp, &Bs[r][c8]);
            gload16(bp + (int64_t)64 * ldb, &Bs[r + 64][c8]);
        } else {
            int r2 = t >> 4, c8 = (t & 15) * 8;
            int kk = 2 * r2;
            const ushort* b0 = (const ushort*)B + (int64_t)(k0 + kk) * ldb + n0 + c8;
            uint4 v0 = *(const uint4*)b0;
            uint4 v1 = *(const uint4*)(b0 + ldb);
            const ushort* p0 = (const ushort*)&v0;
            const ushort* p1 = (const ushort*)&v1;
#pragma unroll
            for (int i = 0; i < 8; i++) {
                uint pk = (uint)p0[i] | ((uint)p1[i] << 16);
                *(uint*)&Bs[c8 + i][kk] = pk;
            }
        }
        __syncthreads();
        short8 af[4], bfv[4];
#pragma unroll
        for (int i = 0; i < 4; i++)
            af[i] = *(const short8*)&As[wm + 16 * i + (lane & 15)][8 * (lane >> 4)];
#pragma unroll
        for (int i = 0; i < 4; i++)
            bfv[i] = *(const short8*)&Bs[wn + 16 * i + (lane & 15)][8 * (lane >> 4)];
#pragma unroll
        for (int i = 0; i < 4; i++)
#pragma unroll
            for (int j = 0; j < 4; j++)
                acc[i][j] = __builtin_amdgcn_mfma_f32_16x16x32_bf16(af[i], bfv[j], acc[i][j], 0, 0, 0);
        __syncthreads();
    }
    const int q = lane >> 4, c = lane & 15;
#pragma unroll
    for (int j = 0; j < 4; j++) {
        int col = n0 + wn + 16 * j + c;
        float bv = BIAS ? bias[col] : 0.0f;
#pragma unroll
        for (int i = 0; i < 4; i++) {
            int rowb = m0 + wm + 16 * i + 4 * q;
#pragma unroll
            for (int r = 0; r < 4; r++) {
                float v = acc[i][j][r] + bv;
                int64_t idx = (int64_t)zb * sC + (int64_t)(rowb + r) * ldc + col;
                if (ATOMIC)       atomicAdd((float*)Cv + idx, v);
                else if (OUT_BF16) ((ushort*)Cv)[idx] = f2bf(v);
                else               ((float*)Cv)[idx] = v;
            }
        }
    }
}

// ---------------- fused constants: folded DFT matrices + weight prep ----------------
// CS1f (1024 x 1280): k<=512 -> cos(2pi nk/1024); 513..639 -> 0;
//                     k=640+r, r<=512 -> -sin(2pi nr/1024); r>512 -> 0.
__global__ __launch_bounds__(256) void genconst_kernel(
    ushort* CS1f, ushort* C2, ushort* S2,
    const float* __restrict__ WlW, const float* __restrict__ WsW, const float* __restrict__ WcW,
    ushort* Wl, ushort* Ws, ushort* Wc)
{
    int blk = blockIdx.x, t = threadIdx.x;
    if (blk < 5120) {
        int idx = blk * 256 + t;                 // 1024*1280
        int n = idx / KF, k = idx - n * KF;
        float v;
        if (k <= 512) {
            int p = (n * k) & 1023;
            v = cosf((6.28318530717958647692f / 1024.0f) * (float)p);
        } else if (k < 640) v = 0.0f;
        else {
            int r = k - 640;
            if (r <= 512) {
                int p = (n * r) & 1023;
                v = -sinf((6.28318530717958647692f / 1024.0f) * (float)p);
            } else v = 0.0f;
        }
        CS1f[idx] = f2bf(v);
    } else if (blk < 5376) {
        int idx = (blk - 5120) * 256 + t;        // 256x256
        int d = idx >> 8, j = idx & 255;
        int p = (d * j) & 255;
        float ang = (6.28318530717958647692f / 256.0f) * (float)p;
        C2[idx] = f2bf(cosf(ang));
        S2[idx] = f2bf(sinf(ang));
    } else {
        int r = blk - 5376;                      // 512 rows
        const float* src; ushort* dst; int srow;
        if (r < 256)      { src = WlW; dst = Wl + r * KPAD;        srow = r + 1; }
        else if (r < 384) { src = WsW; dst = Ws + (r - 256) * KPAD; srow = r - 256 + 1; }
        else              { src = WcW; dst = Wc + (r - 384) * KPAD; srow = r - 384 + 1; }
        dst[t] = (t < DP) ? f2bf(src[(int64_t)srow * DP + t]) : (ushort)0;
        if (t < KPAD - 256) {
            int t2 = t + 256;
            dst[t2] = (t2 < DP) ? f2bf(src[(int64_t)srow * DP + t2]) : (ushort)0;
        }
    }
}

// fused input prep + m-fold: z<32 sent (cast), z>=32 comm (p_logmap0), then
// XC[z][bp] = X[bp] + X[1024-bp]  (bp=0,512: single),  XS[z][bp] = X[bp] - X[1024-bp]
__global__ __launch_bounds__(256) void prep_fold_kernel(const float* __restrict__ sent,
                                                        const float* __restrict__ comm,
                                                        ushort* __restrict__ XC, ushort* __restrict__ XS) {
    __shared__ float red[4];
    int bp = blockIdx.x;           // 0..512
    int z = blockIdx.y;            // 0..63
    int t = threadIdx.x;
    int m2 = (1024 - bp) & 1023;
    const float* base = (z < 32) ? sent + (int64_t)z * 262144 : comm + (int64_t)(z - 32) * 262144;
    float r1 = base[bp * 256 + t];
    float r2 = base[m2 * 256 + t];
    if (z >= 32) {
        float s1 = blockRedSum(r1 * r1, red);
        float yn1 = sqrtf(fmaxf(s1, 1e-15f));
        r1 *= artanh_clip(yn1) / yn1;
        float s2 = blockRedSum(r2 * r2, red);
        float yn2 = sqrtf(fmaxf(s2, 1e-15f));
        r2 *= artanh_clip(yn2) / yn2;
    }
    int64_t o = ((int64_t)z * NFOLD + bp) * 256 + t;
    bool single = (bp == 0) || (bp == 512);
    XC[o] = f2bf(single ? r1 : r1 + r2);
    if (!single) XS[o] = f2bf(r1 - r2);
}

// euclid_to_lorentz: bf16 rows 256 -> bf16 rows 288 (time at 0), split Ls/Lc
__global__ __launch_bounds__(256) void e2l_kernel(const ushort* __restrict__ in,
                                                  ushort* __restrict__ Lsb, ushort* __restrict__ Lcb) {
    __shared__ float red[4];
    int64_t row = blockIdx.x; int t = threadIdx.x;
    float v = bf2f(in[row * 256 + t]);
    float s = blockRedSum(v * v, red);
    float xn = sqrtf(fmaxf(s, 1e-15f)) + 1e-5f;
    float sc = fminf(1.0f, 2.0f / xn);
    float xs = v * sc;
    float s2 = fmaxf(s * sc * sc, 1e-15f);
    float vn = sqrtf(s2);
    float fac = sinhf(vn) / vn;
    ushort* ob = (row < 32768 ? Lsb + row * KPAD : Lcb + (row - 32768) * KPAD);
    if (t == 0) ob[0] = f2bf(coshf(vn));
    ob[1 + t] = f2bf(fac * xs);
    if (t < KPAD - DP) ob[DP + t] = 0;
}

// lorentz_linear space (fp32, 256) -> bf16 row 288 with time at col 0
__global__ __launch_bounds__(256) void lfix2_kernel(const float* __restrict__ sp, ushort* __restrict__ obf) {
    __shared__ float red[4];
    int64_t row = blockIdx.x; int t = threadIdx.x;
    float v = sp[row * 256 + t];
    float s = blockRedSum(v * v, red);
    ushort* ob = obf + row * KPAD;
    if (t == 0) ob[0] = f2bf(sqrtf(s + 1.0f));
    ob[1 + t] = f2bf(v);
    if (t < KPAD - DP) ob[DP + t] = 0;
}

// lorentz_linear(K) space + bias + to_poincare; fp32 out only for Hs half
__global__ __launch_bounds__(128) void poinc2_kernel(const float* __restrict__ sp,
                                                     const float* __restrict__ Wsb, const float* __restrict__ Wcb,
                                                     float* __restrict__ o32, ushort* __restrict__ obf) {
    __shared__ float red[2];
    int64_t row = blockIdx.x; int t = threadIdx.x;
    const float* bias = (row < 32768 ? Wsb : Wcb);
    float v = sp[row * KQ + t] + bias[1 + t];
    float s = blockRedSum(v * v, red);
    float tim = sqrtf(s + 1.0f);
    float o = v / (tim + 1.0f);
    if (row < 32768) o32[row * KQ + t] = o;
    obf[row * KQ + t] = f2bf(o);
}

// lorentz_act on bf16 Lmat rows (1024), in place, + xnrow
__global__ __launch_bounds__(256) void lact_kernel(ushort* __restrict__ Lmat, float* __restrict__ xnrow) {
    __shared__ float red[4];
    int64_t row = blockIdx.x; int t = threadIdx.x;
    ushort* r = Lmat + row * (int64_t)NCQ;
    ushort4 u = *(ushort4*)&r[4 * t];
    float v[4] = {bf2f(u.x), bf2f(u.y), bf2f(u.z), bf2f(u.w)};
    float g[4]; float s = 0.f;
#pragma unroll
    for (int i = 0; i < 4; i++) {
        int idx = 4 * t + i;
        if (idx > 0) { g[i] = gelu_f(v[i]); s += g[i] * g[i]; } else g[i] = 0.f;
    }
    s = blockRedSum(s, red);
    if (t == 0) g[0] = sqrtf(1.0f + s);
    ushort4 o; o.x = f2bf(g[0]); o.y = f2bf(g[1]); o.z = f2bf(g[2]); o.w = f2bf(g[3]);
    *(ushort4*)&r[4 * t] = o;
    if (t == 0) xnrow[row] = sqrtf(fmaxf(1.0f + 2.0f * s, 1e-15f));
}

// column-norm stage A/B
__global__ __launch_bounds__(256) void colnormA_kernel(const ushort* __restrict__ Lmat, float* __restrict__ part) {
    int b = blockIdx.x, chunk = blockIdx.y, t = threadIdx.x;
    const ushort* base = Lmat + (int64_t)b * NSQ * NCQ + (int64_t)chunk * 128 * NCQ + 4 * t;
    float s0 = 0.f, s1 = 0.f, s2 = 0.f, s3 = 0.f;
    for (int n = 0; n < 128; n++) {
        ushort4 u = *(const ushort4*)(base + (int64_t)n * NCQ);
        float a = bf2f(u.x), bb = bf2f(u.y), c = bf2f(u.z), d = bf2f(u.w);
        s0 += a * a; s1 += bb * bb; s2 += c * c; s3 += d * d;
    }
    float4 o = {s0, s1, s2, s3};
    *(float4*)(part + ((int64_t)(b * 8 + chunk)) * 4096 + 4 * t) = o;
}
__global__ __launch_bounds__(256) void colnormB_kernel(const float* __restrict__ part, float* __restrict__ xncol) {
    int b = blockIdx.x; int m = blockIdx.y * 256 + threadIdx.x;
    const float* p = part + (int64_t)b * 8 * 4096 + m;
    float s = 0.f;
#pragma unroll
    for (int c = 0; c < 8; c++) s += p[c * 4096];
    xncol[b * NCQ + m] = sqrtf(fmaxf(s, 1e-15f));
}

// Hs path rowwise chain -> logits
__global__ __launch_bounds__(64) void rowops_s_kernel(
    const float* __restrict__ Hsa, const float* __restrict__ mxs,
    const float* __restrict__ xnrow, const float* __restrict__ whs,
    float* __restrict__ logits)
{
    int64_t row = blockIdx.x; int t = threadIdx.x;
    const float* p = Hsa + row * KQ;
    const float* q = mxs + row * KQ;
    float p0 = p[t], p1 = p[t + 64], q0 = q[t], q1 = q[t + 64];
    float mxn = sqrtf(fmaxf(waveRedSum(q0 * q0 + q1 * q1), 1e-15f));
    float xn = xnrow[row];
    float fac = tanhf(mxn / xn * artanh_clip(xn)) / mxn;
    float y0 = fac * q0, y1 = fac * q1;
    float xy = waveRedSum(p0 * y0 + p1 * y1);
    float x2 = waveRedSum(p0 * p0 + p1 * p1);
    float y2 = waveRedSum(y0 * y0 + y1 * y1);
    float ca = 1.f + 2.f * xy + y2, cb = 1.f - x2;
    float den = fmaxf(1.f + 2.f * xy + x2 * y2, 1e-15f);
    float h0 = (ca * p0 + cb * y0) / den, h1 = (ca * p1 + cb * y1) / den;
    float hn = sqrtf(fmaxf(waveRedSum(h0 * h0 + h1 * h1), 1e-15f));
    float uf = artanh_clip(hn) / hn;
    float g0 = gelu_f(uf * h0), g1 = gelu_f(uf * h1);
    float gn = sqrtf(fmaxf(waveRedSum(g0 * g0 + g1 * g1), 1e-15f));
    float ef = tanhf(gn) / gn;
    float H0 = ef * g0, H1 = ef * g1;
    float dot = waveRedSum(H0 * whs[t] + H1 * whs[t + 64]);
    float Hn = sqrtf(fmaxf(waveRedSum(H0 * H0 + H1 * H1), 1e-15f));
    float mxn2 = sqrtf(fmaxf(dot * dot, 1e-15f));
    float lg = tanhf(mxn2 / Hn * artanh_clip(Hn)) * dot / mxn2;
    if (t == 0) logits[row] = lg;
}

// transpose (z batches of 1024x128) -> (z batches of 128x1024); contiguous over z
__global__ void thsa_kernel(const ushort* __restrict__ in, ushort* __restrict__ outp) {
    __shared__ ushort tile[32][33];
    int z = blockIdx.z;
    int n0 = blockIdx.x * 32, j0 = blockIdx.y * 32;
    const ushort* ib = in + (int64_t)z * 131072;
    ushort* ob = outp + (int64_t)z * 131072;
    int tx = threadIdx.x, ty = threadIdx.y;
    for (int i = 0; i < 32; i += 8) tile[ty + i][tx] = ib[(n0 + ty + i) * 128 + j0 + tx];
    __syncthreads();
    for (int i = 0; i < 32; i += 8) ob[(j0 + ty + i) * 1024 + n0 + tx] = tile[tx][ty + i];
}

// mobius_matvec scale on mx_cT columns
__global__ __launch_bounds__(256) void colscale_kernel(float* __restrict__ mxcT, const float* __restrict__ xncol) {
    int b = blockIdx.x; int m = blockIdx.y * 256 + threadIdx.x;
    float* base = mxcT + (int64_t)b * KQ * NCQ + m;
    float s = 0.f;
    for (int j = 0; j < KQ; j++) { float v = base[j * NCQ]; s += v * v; }
    float mxn = sqrtf(fmaxf(s, 1e-15f));
    float xn = xncol[b * NCQ + m];
    float fac = tanhf(mxn / xn * artanh_clip(xn)) / mxn;
    for (int j = 0; j < KQ; j++) base[j * NCQ] *= fac;
}

// Hc path rowwise chain (per (b,k) over NC), x from coalesced bf16 HcAT, y in place
__global__ __launch_bounds__(256) void rowops_c_kernel(const ushort* __restrict__ HcAT, float* __restrict__ y) {
    __shared__ float red[4];
    int64_t row = blockIdx.x;
    const ushort* xbase = HcAT + row * (int64_t)NCQ;
    float* yr = y + row * (int64_t)NCQ;
    int t = threadIdx.x;
    float xv[4], yv[4];
    float xy = 0.f, x2 = 0.f, y2 = 0.f;
#pragma unroll
    for (int i = 0; i < 4; i++) {
        int m = t + 256 * i;
        xv[i] = bf2f(xbase[m]); yv[i] = yr[m];
        xy += xv[i] * yv[i]; x2 += xv[i] * xv[i]; y2 += yv[i] * yv[i];
    }
    xy = blockRedSum(xy, red);
    x2 = blockRedSum(x2, red);
    y2 = blockRedSum(y2, red);
    float ca = 1.f + 2.f * xy + y2, cb = 1.f - x2;
    float den = fmaxf(1.f + 2.f * xy + x2 * y2, 1e-15f);
    float h[4]; float hn2 = 0.f;
#pragma unroll
    for (int i = 0; i < 4; i++) { h[i] = (ca * xv[i] + cb * yv[i]) / den; hn2 += h[i] * h[i]; }
    hn2 = blockRedSum(hn2, red);
    float hn = sqrtf(fmaxf(hn2, 1e-15f));
    float uf = artanh_clip(hn) / hn;
    float g[4]; float gn2 = 0.f;
#pragma unroll
    for (int i = 0; i < 4; i++) { g[i] = gelu_f(uf * h[i]); gn2 += g[i] * g[i]; }
    gn2 = blockRedSum(gn2, red);
    float gn = sqrtf(fmaxf(gn2, 1e-15f));
    float ef = tanhf(gn) / gn;
#pragma unroll
    for (int i = 0; i < 4; i++) yr[t + 256 * i] = ef * g[i];
}

// Ac logits
__global__ __launch_bounds__(256) void logitsc_kernel(const float* __restrict__ Hc, const float* __restrict__ whc, float* __restrict__ lgc) {
    int b = blockIdx.x; int m = blockIdx.y * 256 + threadIdx.x;
    const float* base = Hc + (int64_t)b * KQ * NCQ + m;
    float s1 = 0.f, s2 = 0.f;
    for (int j = 0; j < KQ; j++) { float v = base[j * NCQ]; s1 += v * whc[j]; s2 += v * v; }
    float xn = sqrtf(fmaxf(s2, 1e-15f));
    float mxn = sqrtf(fmaxf(s1 * s1, 1e-15f));
    lgc[b * NCQ + m] = tanhf(mxn / xn * artanh_clip(xn)) * s1 / mxn;
}

// fused softmax for lgs|lgc (contiguous) -> AsOut|AcOut (contiguous), grid 64
__global__ __launch_bounds__(256) void softmax_kernel(const float* __restrict__ lg, float* __restrict__ outp) {
    __shared__ float red[4];
    int b = blockIdx.x; int t = threadIdx.x;
    const float* x = lg + b * 1024;
    float v[4]; float m = -1e30f;
#pragma unroll
    for (int i = 0; i < 4; i++) { v[i] = x[t + 256 * i]; m = fmaxf(m, v[i]); }
    m = blockRedMax(m, red);
    float s = 0.f;
#pragma unroll
    for (int i = 0; i < 4; i++) { v[i] = expf(v[i] - m); s += v[i]; }
    s = blockRedSum(s, red);
    float inv = 1.0f / s;
#pragma unroll
    for (int i = 0; i < 4; i++) outp[b * 1024 + t + 256 * i] = v[i] * inv;
}

// centroid stage A on bf16 L (stride 288, time at col 0)
__global__ __launch_bounds__(320) void centroidA_kernel(
    const ushort* __restrict__ Lsb, const ushort* __restrict__ Lcb,
    const float* __restrict__ As, const float* __restrict__ Ac,
    float* __restrict__ part)
{
    int b = blockIdx.x;
    int which = blockIdx.y;
    int chunk = blockIdx.z;
    const ushort* L = which ? Lcb : Lsb;
    const float* w = which ? Ac : As;
    int t = threadIdx.x;
    if (t >= DP) return;
    const ushort* Lb = L + (int64_t)b * NSQ * KPAD + (int64_t)chunk * 128 * KPAD + t;
    const float* wb = w + b * NSQ + chunk * 128;
    float s = 0.f;
    for (int n = 0; n < 128; n++) s += wb[n] * bf2f(Lb[(int64_t)n * KPAD]);
    part[((int64_t)((b * 2 + which) * 8 + chunk)) * 264 + t] = s;
}
__global__ __launch_bounds__(320) void centroidB_kernel(
    const float* __restrict__ part, float* __restrict__ co_s, float* __restrict__ co_c)
{
    int b = blockIdx.x;
    int which = blockIdx.y;
    int t = threadIdx.x;
    if (t >= DP) return;
    const float* p = part + (int64_t)(b * 2 + which) * 8 * 264 + t;
    float s = 0.f;
#pragma unroll
    for (int c = 0; c < 8; c++) s += p[c * 264];
    (which ? co_c : co_s)[b * DP + t] = s;
}

__global__ __launch_bounds__(256) void final_kernel(const float* __restrict__ co_s, const float* __restrict__ co_c, float* __restrict__ outp) {
    __shared__ float red[4];
    int b = blockIdx.x, t = threadIdx.x;
    float zmine[2];
    for (int w = 0; w < 2; w++) {
        const float* co = (w ? co_c : co_s) + b * DP;
        float at = co[0];
        float asp = co[1 + t];
        float ssp = blockRedSum(asp * asp, red);
        float li = ssp - at * at;
        float den = sqrtf(fmaxf(fabsf(li), 1e-8f));
        float xt = at / den, xsp = asp / den;
        float s2 = blockRedSum(xsp * xsp, red);
        float nrm = sqrtf(fmaxf(s2, 1e-15f));
        float ac = acoshf(fmaxf(xt, 1.0f + 1e-7f));
        zmine[w] = ac * xsp / nrm;
    }
    float vn2 = blockRedSum(zmine[0] * zmine[0] + zmine[1] * zmine[1], red);
    float vn = sqrtf(fmaxf(vn2, 1e-15f));
    float sc = sinhf(vn) / vn;
    if (t == 0) outp[b * 513] = coshf(vn);
    outp[b * 513 + 1 + t] = sc * zmine[0];
    outp[b * 513 + 1 + 256 + t] = sc * zmine[1];
}

// ---------------- host launcher ----------------
extern "C" void kernel_launch(void* const* d_in, const int* in_sizes, int n_in,
                              void* d_out, int out_size, void* d_ws, size_t ws_size,
                              hipStream_t stream)
{
    const float* sent = (const float*)d_in[0];
    const float* comm = (const float*)d_in[1];
    const float* WlW  = (const float*)d_in[2];
    const float* Wlb  = (const float*)d_in[3];
    const float* WcW  = (const float*)d_in[4];
    const float* Wcb  = (const float*)d_in[5];
    const float* WsW  = (const float*)d_in[6];
    const float* Wsb  = (const float*)d_in[7];
    const float* whs  = (const float*)d_in[8];
    const float* whc  = (const float*)d_in[9];
    float* out = (float*)d_out;
    (void)in_sizes; (void)n_in; (void)out_size; (void)ws_size;

    float* ws = (float*)d_ws;
    size_t off = 0;
    auto take = [&](size_t n) { float* p = ws + off; off += n; return p; };
    float*  xnrow = take(32768);
    float*  xncol = take(32768);
    float*  lgs   = take(32768);   // contiguous with lgc
    float*  lgc   = take(32768);
    float*  co_s  = take(8224);
    float*  co_c  = take(8224);
    ushort* Ls_bf = (ushort*)take(4718592);   // contiguous with Lc_bf
    ushort* Lc_bf = (ushort*)take(4718592);
    ushort* Wl_bf = (ushort*)take(36864);
    ushort* Ws_bf = (ushort*)take(18432);
    ushort* Wc_bf = (ushort*)take(18432);
    ushort* HsA_bf = (ushort*)take(2097152);  // contiguous with HcA_bf
    ushort* HcA_bf = (ushort*)take(2097152);
    float*  part_cn   = take(1048576);
    float*  part_cent = take(135168);
    float*  F     = take(33554432);           // total 48.6M fl = 185 MiB

    // Phase overlays in F (float offsets)
    ushort* XC_bf   = (ushort*)F;                 // [P1] 64x640x256 us = 5.24M fl
    ushort* XS_bf   = (ushort*)(F + 5242880);     // [P1] 5.24M fl
    ushort* Ff_bf   = (ushort*)(F + 10485760);    // [P1] 64x256x1280 us = 10.49M fl
    ushort* CS1f    = (ushort*)(F + 20971520);    // [P1] 1024x1280 us = 0.66M fl
    ushort* C2_bf   = (ushort*)(F + 21626880);    // [P1] 32k fl
    ushort* S2_bf   = (ushort*)(F + 21659648);    // [P1] 32k fl
    ushort* Yst_bf  = (ushort*)F;                 // [P1] aliases XC/XS (dead after stage-1)
    ushort* Lmat_bf = (ushort*)F;                 // [P3-P5] 16.78M fl
    float*  Llin_sp = F + 16777216;               // [P2] 8.39M fl
    ushort* Llin_bf = (ushort*)(F + 25165824);    // [P2-P3] 4.72M fl
    float*  ycat    = F + 16777216;               // [P4] 8.39M fl (ys | yc)
    float*  HsA     = F + 25165824;               // [P4-P5] 4.19M fl
    float*  mx      = F + 16777216;               // [P5] 4.19M fl
    ushort* HsAT    = (ushort*)(F + 20971520);    // [P5] 2.1M fl, contiguous with HcAT
    ushort* HcAT    = (ushort*)(F + 23068672);    // [P5] 2.1M fl

    float* AsOut = out + 16416;
    float* AcOut = out + 16416 + 32768;

    dim3 blk(256);

    // constants (CS1f, C2/S2, weight prep) in one launch
    genconst_kernel<<<5888, 256, 0, stream>>>(CS1f, C2_bf, S2_bf, WlW, WsW, WcW, Wl_bf, Ws_bf, Wc_bf);

    // ---- input prep + m-fold (sent z 0-31, comment z 32-63) ----
    prep_fold_kernel<<<dim3(513, 64), 256, 0, stream>>>(sent, comm, XC_bf, XS_bf);
    // stage-1 folded (TN): Fc[j,m] = sum_d C2[j,d]*XC[m,d]  -> Ff cols 0..639
    mfma_gemm<false,false,true,false,false,1><<<dim3(5,2,64), blk, 0, stream>>>(
        (const short*)C2_bf,256,0, (const short*)XC_bf,256,(int64_t)NFOLD*256, Ff_bf,KF,(int64_t)256*KF, nullptr, 256,NFOLD,256);
    //                 Fs[j,m] = sum_d S2[j,d]*XS[m,d]  -> Ff cols 640..1279
    mfma_gemm<false,false,true,false,false,1><<<dim3(5,2,64), blk, 0, stream>>>(
        (const short*)S2_bf,256,0, (const short*)XS_bf,256,(int64_t)NFOLD*256, Ff_bf+NFOLD,KF,(int64_t)256*KF, nullptr, 256,NFOLD,256);
    // stage-2 folded (TN, K=1280): Y[n,j] = sum_k CS1f[n,k]*Ff[j,k]
    mfma_gemm<false,false,true,false,false,1><<<dim3(2,8,64), blk, 0, stream>>>(
        (const short*)CS1f,KF,0, (const short*)Ff_bf,KF,(int64_t)256*KF, Yst_bf,256,262144, nullptr, 1024,256,KF);
    e2l_kernel<<<65536, 256, 0, stream>>>(Yst_bf, Ls_bf, Lc_bf);

    // ---- L = lorentz_linear(Lc, Wl): space cols only ----
    mfma_gemm<false,false,false,true,false,1><<<dim3(2,256,1), blk, 0, stream>>>(
        (const short*)Lc_bf,KPAD,0, (const short*)Wl_bf,KPAD,0, Llin_sp,256,0, Wlb+1, 32768,256,KPAD);
    lfix2_kernel<<<32768, 256, 0, stream>>>(Llin_sp, Llin_bf);

    // ---- Lmat = lorentz_act(einsum(Ls, Llin)) in bf16 ----
    mfma_gemm<false,false,true,false,false,1><<<dim3(8,8,32), blk, 0, stream>>>(
        (const short*)Ls_bf,KPAD,294912, (const short*)Llin_bf,KPAD,294912, Lmat_bf,1024,1048576, nullptr, 1024,1024,KPAD);
    lact_kernel<<<32768, 256, 0, stream>>>(Lmat_bf, xnrow);
    colnormA_kernel<<<dim3(32,8), 256, 0, stream>>>(Lmat_bf, part_cn);
    colnormB_kernel<<<dim3(32,4), 256, 0, stream>>>(part_cn, xncol);

    // ---- Hs_a / Hc_a merged (z=0: Ls*Ws, z=1: Lc*Wc), bias in poinc2 ----
    mfma_gemm<false,false,false,false,false,1><<<dim3(1,256,2), blk, 0, stream>>>(
        (const short*)Ls_bf,KPAD,9437184, (const short*)Ws_bf,KPAD,36864, ycat,128,4194304, nullptr, 32768,128,KPAD);
    poinc2_kernel<<<65536, 128, 0, stream>>>(ycat, Wsb, Wcb, HsA, HsA_bf);

    // ---- transpose HsA_bf and HcA_bf (contiguous) in one launch ----
    thsa_kernel<<<dim3(32,4,64), dim3(32,8), 0, stream>>>(HsA_bf, HsAT);

    // ---- Hs path: mx_s = Lmat . Hc_a (fast TT via HcAT; split-K=4, atomic) ----
    hipMemsetAsync(mx, 0, 4194304 * sizeof(float), stream);
    mfma_gemm<false,false,false,false,true,4><<<dim3(1,8,128), blk, 0, stream>>>(
        (const short*)Lmat_bf,1024,1048576, (const short*)HcAT,1024,131072, mx,128,131072, nullptr, 1024,128,1024);
    rowops_s_kernel<<<32768, 64, 0, stream>>>(HsA, mx, xnrow, whs, lgs);

    // ---- Hc path: mx_cT = Hs_a^T . Lmat (A fast via HsAT; split-K=4) ----
    hipMemsetAsync(mx, 0, 4194304 * sizeof(float), stream);
    mfma_gemm<false,true,false,false,true,4><<<dim3(8,1,128), blk, 0, stream>>>(
        (const short*)HsAT,1024,131072, (const short*)Lmat_bf,1024,1048576, mx,1024,131072, nullptr, 128,1024,1024);
    colscale_kernel<<<dim3(32,4), 256, 0, stream>>>(mx, xncol);
    rowops_c_kernel<<<4096, 256, 0, stream>>>(HcAT, mx);
    logitsc_kernel<<<dim3(32,4), 256, 0, stream>>>(mx, whc, lgc);

    // ---- fused softmaxes / centroids / concat ----
    softmax_kernel<<<64, 256, 0, stream>>>(lgs, AsOut);
    centroidA_kernel<<<dim3(32,2,8), 320, 0, stream>>>(Ls_bf, Lc_bf, AsOut, AcOut, part_cent);
    centroidB_kernel<<<dim3(32,2), 320, 0, stream>>>(part_cent, co_s, co_c);
    final_kernel<<<32, 256, 0, stream>>>(co_s, co_c, out);
}

// Round 8
// 726.400 us; speedup vs baseline: 1.1457x; 1.0396x over previous
//
#include <hip/hip_runtime.h>
#include <cstdint>
#include <math.h>

#define NBATCH 32
#define NSQ 1024
#define NCQ 1024
#define DDIM 256
#define DP 257
#define KQ 128
#define KPAD 288   // 257 padded to /32
#define NFOLD 640  // folded m rows per batch (513 padded to /128)
#define KF2 640    // folded stage-2 K (513 used)

typedef __attribute__((ext_vector_type(8))) short short8;
typedef __attribute__((ext_vector_type(4))) float floatx4;

// ---------------- device helpers ----------------
__device__ __forceinline__ float bf2f(ushort u) { return __uint_as_float(((uint)u) << 16); }
__device__ __forceinline__ ushort f2bf(float f) {
    uint u = __float_as_uint(f);
    return (ushort)((u + 0x7FFFu + ((u >> 16) & 1u)) >> 16);
}
// async global->LDS, 16B per lane; LDS dest = wave-uniform base + lane*16
__device__ __forceinline__ void gload16(const void* g, void* l) {
    __builtin_amdgcn_global_load_lds(
        (const __attribute__((address_space(1))) void*)g,
        (__attribute__((address_space(3))) void*)l,
        16, 0, 0);
}
__device__ __forceinline__ float artanh_clip(float x) {
    x = fminf(fmaxf(x, -1.0f + 1e-5f), 1.0f - 1e-5f);
    return 0.5f * (log1pf(x) - log1pf(-x));
}
__device__ __forceinline__ float gelu_f(float x) {
    return 0.5f * x * (1.0f + erff(x * 0.70710678118654752440f));
}
__device__ __forceinline__ float waveRedSum(float v) {
#pragma unroll
    for (int o = 32; o > 0; o >>= 1) v += __shfl_down(v, o, 64);
    return __shfl(v, 0, 64);
}
__device__ __forceinline__ float blockRedSum(float v, float* buf) {
    int lane = threadIdx.x & 63, wid = threadIdx.x >> 6;
#pragma unroll
    for (int o = 32; o > 0; o >>= 1) v += __shfl_down(v, o, 64);
    __syncthreads();
    if (lane == 0) buf[wid] = v;
    __syncthreads();
    int nw = blockDim.x >> 6;
    float s = buf[0];
    for (int i = 1; i < nw; i++) s += buf[i];
    return s;
}
__device__ __forceinline__ float blockRedMax(float v, float* buf) {
    int lane = threadIdx.x & 63, wid = threadIdx.x >> 6;
#pragma unroll
    for (int o = 32; o > 0; o >>= 1) v = fmaxf(v, __shfl_down(v, o, 64));
    __syncthreads();
    if (lane == 0) buf[wid] = v;
    __syncthreads();
    int nw = blockDim.x >> 6;
    float s = buf[0];
    for (int i = 1; i < nw; i++) s = fmaxf(s, buf[i]);
    return s;
}

// ---------------- bf16 MFMA GEMM ----------------
// C[m,n] = sum_k A[m,k]*B'[k,n] (+bias[n])
// A_NN=false: A is (M x K) row-major (fast path, async LDS). A_NN=true: A stored (K x M).
// B_NN=false: B is (N x K) row-major (fast path).            B_NN=true: B stored (K x N).
// NSPLIT: split-K; blockIdx.z = batch*NSPLIT + ksplit; ATOMIC epilogue.
// DUAL: blockIdx.z = batch*2 + half; half selects A1/B1 and +cOff1 on C.
template <bool A_NN, bool B_NN, bool OUT_BF16, bool BIAS, bool ATOMIC, int NSPLIT, bool DUAL>
__global__ __launch_bounds__(256) void mfma_gemm(
    const short* __restrict__ A, int lda, int64_t sA,
    const short* __restrict__ B, int ldb, int64_t sB,
    void* __restrict__ Cv, int ldc, int64_t sC,
    const float* __restrict__ bias, int M, int N, int K,
    const short* __restrict__ A1, const short* __restrict__ B1, int64_t cOff1)
{
    __shared__ short As[128][32];
    __shared__ short Bs[128][32];
    const int zz = blockIdx.z;
    int zb, ks, half;
    if (DUAL) { half = zz & 1; zb = zz >> 1; ks = 0; }
    else      { zb = zz / NSPLIT; ks = zz - zb * NSPLIT; half = 0; }
    const short* Ap = (DUAL && half) ? A1 : A;
    const short* Bp = (DUAL && half) ? B1 : B;
    Ap += (int64_t)zb * sA;
    Bp += (int64_t)zb * sB;
    const int kper = K / NSPLIT;
    const int kbeg = ks * kper, kend = kbeg + kper;
    const int m0 = blockIdx.y * 128, n0 = blockIdx.x * 128;
    const int t = threadIdx.x;
    const int lane = t & 63, w = t >> 6;
    const int wm = (w & 1) * 64, wn = (w >> 1) * 64;
    floatx4 acc[4][4] = {};
    for (int k0 = kbeg; k0 < kend; k0 += 32) {
        if (!A_NN) {
            int r = t >> 2, c8 = (t & 3) * 8;
            const short* ap = Ap + (int64_t)(m0 + r) * lda + k0 + c8;
            gload16(ap, &As[r][c8]);
            gload16(ap + (int64_t)64 * lda, &As[r + 64][c8]);
        } else {
            int r2 = t >> 4, c8 = (t & 15) * 8;
            int kk = 2 * r2;
            const ushort* a0 = (const ushort*)Ap + (int64_t)(k0 + kk) * lda + m0 + c8;
            uint4 v0 = *(const uint4*)a0;
            uint4 v1 = *(const uint4*)(a0 + lda);
            const ushort* p0 = (const ushort*)&v0;
            const ushort* p1 = (const ushort*)&v1;
#pragma unroll
            for (int i = 0; i < 8; i++) {
                uint pk = (uint)p0[i] | ((uint)p1[i] << 16);
                *(uint*)&As[c8 + i][kk] = pk;
            }
        }
        if (!B_NN) {
            int r = t >> 2, c8 = (t & 3) * 8;
            const short* bp = Bp + (int64_t)(n0 + r) * ldb + k0 + c8;
            gload16(bp, &Bs[r][c8]);
            gload16(bp + (int64_t)64 * ldb, &Bs[r + 64][c8]);
        } else {
            int r2 = t >> 4, c8 = (t & 15) * 8;
            int kk = 2 * r2;
            const ushort* b0 = (const ushort*)Bp + (int64_t)(k0 + kk) * ldb + n0 + c8;
            uint4 v0 = *(const uint4*)b0;
            uint4 v1 = *(const uint4*)(b0 + ldb);
            const ushort* p0 = (const ushort*)&v0;
            const ushort* p1 = (const ushort*)&v1;
#pragma unroll
            for (int i = 0; i < 8; i++) {
                uint pk = (uint)p0[i] | ((uint)p1[i] << 16);
                *(uint*)&Bs[c8 + i][kk] = pk;
            }
        }
        __syncthreads();
        short8 af[4], bfv[4];
#pragma unroll
        for (int i = 0; i < 4; i++)
            af[i] = *(const short8*)&As[wm + 16 * i + (lane & 15)][8 * (lane >> 4)];
#pragma unroll
        for (int i = 0; i < 4; i++)
            bfv[i] = *(const short8*)&Bs[wn + 16 * i + (lane & 15)][8 * (lane >> 4)];
#pragma unroll
        for (int i = 0; i < 4; i++)
#pragma unroll
            for (int j = 0; j < 4; j++)
                acc[i][j] = __builtin_amdgcn_mfma_f32_16x16x32_bf16(af[i], bfv[j], acc[i][j], 0, 0, 0);
        __syncthreads();
    }
    const int q = lane >> 4, c = lane & 15;
    const int64_t cbase = (int64_t)zb * sC + ((DUAL && half) ? cOff1 : 0);
#pragma unroll
    for (int j = 0; j < 4; j++) {
        int col = n0 + wn + 16 * j + c;
        float bv = BIAS ? bias[col] : 0.0f;
#pragma unroll
        for (int i = 0; i < 4; i++) {
            int rowb = m0 + wm + 16 * i + 4 * q;
#pragma unroll
            for (int r = 0; r < 4; r++) {
                float v = acc[i][j][r] + bv;
                int64_t idx = cbase + (int64_t)(rowb + r) * ldc + col;
                if (ATOMIC)       atomicAdd((float*)Cv + idx, v);
                else if (OUT_BF16) ((ushort*)Cv)[idx] = f2bf(v);
                else               ((float*)Cv)[idx] = v;
            }
        }
    }
}

// ---------------- fused constants: folded DFT matrices + weight prep ----------------
// CS1c (640x640): k<=512 -> cos(2pi nk/1024), else 0
// CS1s (640x640): k<=512 -> -sin(2pi nk/1024) (exact 0 at k=0), else 0
__global__ __launch_bounds__(256) void genconst_kernel(
    ushort* CS1c, ushort* CS1s, ushort* C2, ushort* S2,
    const float* __restrict__ WlW, const float* __restrict__ WsW, const float* __restrict__ WcW,
    ushort* Wl, ushort* Ws, ushort* Wc)
{
    int blk = blockIdx.x, t = threadIdx.x;
    if (blk < 3200) {
        int idx = blk * 256 + t;                 // 2 x 640*640
        int hs = idx >= 409600;
        int e = idx - hs * 409600;
        int n = e / KF2, k = e - n * KF2;
        float v = 0.0f;
        if (k <= 512) {
            int p = (n * k) & 1023;
            float ang = (6.28318530717958647692f / 1024.0f) * (float)p;
            v = hs ? ((k == 0) ? 0.0f : -sinf(ang)) : cosf(ang);
        }
        (hs ? CS1s : CS1c)[e] = f2bf(v);
    } else if (blk < 3456) {
        int idx = (blk - 3200) * 256 + t;        // 256x256
        int d = idx >> 8, j = idx & 255;
        int p = (d * j) & 255;
        float ang = (6.28318530717958647692f / 256.0f) * (float)p;
        C2[idx] = f2bf(cosf(ang));
        S2[idx] = f2bf(sinf(ang));
    } else {
        int r = blk - 3456;                      // 512 rows
        const float* src; ushort* dst; int srow;
        if (r < 256)      { src = WlW; dst = Wl + r * KPAD;        srow = r + 1; }
        else if (r < 384) { src = WsW; dst = Ws + (r - 256) * KPAD; srow = r - 256 + 1; }
        else              { src = WcW; dst = Wc + (r - 384) * KPAD; srow = r - 384 + 1; }
        dst[t] = (t < DP) ? f2bf(src[(int64_t)srow * DP + t]) : (ushort)0;
        if (t < KPAD - 256) {
            int t2 = t + 256;
            dst[t2] = (t2 < DP) ? f2bf(src[(int64_t)srow * DP + t2]) : (ushort)0;
        }
    }
}

// fused input prep + m-fold: z<32 sent (cast), z>=32 comm (p_logmap0)
__global__ __launch_bounds__(256) void prep_fold_kernel(const float* __restrict__ sent,
                                                        const float* __restrict__ comm,
                                                        ushort* __restrict__ XC, ushort* __restrict__ XS) {
    __shared__ float red[4];
    int bp = blockIdx.x;           // 0..512
    int z = blockIdx.y;            // 0..63
    int t = threadIdx.x;
    int m2 = (1024 - bp) & 1023;
    const float* base = (z < 32) ? sent + (int64_t)z * 262144 : comm + (int64_t)(z - 32) * 262144;
    float r1 = base[bp * 256 + t];
    float r2 = base[m2 * 256 + t];
    if (z >= 32) {
        float s1 = blockRedSum(r1 * r1, red);
        float yn1 = sqrtf(fmaxf(s1, 1e-15f));
        r1 *= artanh_clip(yn1) / yn1;
        float s2 = blockRedSum(r2 * r2, red);
        float yn2 = sqrtf(fmaxf(s2, 1e-15f));
        r2 *= artanh_clip(yn2) / yn2;
    }
    int64_t o = ((int64_t)z * NFOLD + bp) * 256 + t;
    bool single = (bp == 0) || (bp == 512);
    XC[o] = f2bf(single ? r1 : r1 + r2);
    if (!single) XS[o] = f2bf(r1 - r2);
}

// euclid_to_lorentz with n-fold combine: Y[n] = Yc[n'] +/- Ys[n']
__global__ __launch_bounds__(256) void e2l_kernel(const ushort* __restrict__ YcYs,
                                                  ushort* __restrict__ Lsb, ushort* __restrict__ Lcb) {
    __shared__ float red[4];
    int64_t row = blockIdx.x; int t = threadIdx.x;   // row in [0, 65536)
    int z = (int)(row >> 10), n = (int)(row & 1023);
    int np = (n <= 512) ? n : 1024 - n;
    float sgn = (n <= 512) ? 1.0f : -1.0f;
    const ushort* base = YcYs + (int64_t)z * 327680 + np * 256 + t;
    float v = bf2f(base[0]) + sgn * bf2f(base[163840]);
    float s = blockRedSum(v * v, red);
    float xn = sqrtf(fmaxf(s, 1e-15f)) + 1e-5f;
    float sc = fminf(1.0f, 2.0f / xn);
    float xs = v * sc;
    float s2 = fmaxf(s * sc * sc, 1e-15f);
    float vn = sqrtf(s2);
    float fac = sinhf(vn) / vn;
    ushort* ob = (row < 32768 ? Lsb + row * KPAD : Lcb + (row - 32768) * KPAD);
    if (t == 0) ob[0] = f2bf(coshf(vn));
    ob[1 + t] = f2bf(fac * xs);
    if (t < KPAD - DP) ob[DP + t] = 0;
}

// lorentz_linear space (fp32, 256) -> bf16 row 288 with time at col 0
__global__ __launch_bounds__(256) void lfix2_kernel(const float* __restrict__ sp, ushort* __restrict__ obf) {
    __shared__ float red[4];
    int64_t row = blockIdx.x; int t = threadIdx.x;
    float v = sp[row * 256 + t];
    float s = blockRedSum(v * v, red);
    ushort* ob = obf + row * KPAD;
    if (t == 0) ob[0] = f2bf(sqrtf(s + 1.0f));
    ob[1 + t] = f2bf(v);
    if (t < KPAD - DP) ob[DP + t] = 0;
}

// lorentz_linear(K) space + bias + to_poincare -> bf16 only
__global__ __launch_bounds__(128) void poinc2_kernel(const float* __restrict__ sp,
                                                     const float* __restrict__ Wsb, const float* __restrict__ Wcb,
                                                     ushort* __restrict__ obf) {
    __shared__ float red[2];
    int64_t row = blockIdx.x; int t = threadIdx.x;
    const float* bias = (row < 32768 ? Wsb : Wcb);
    float v = sp[row * KQ + t] + bias[1 + t];
    float s = blockRedSum(v * v, red);
    float tim = sqrtf(s + 1.0f);
    obf[row * KQ + t] = f2bf(v / (tim + 1.0f));
}

// lorentz_act on bf16 Lmat rows (1024), in place, + xnrow
__global__ __launch_bounds__(256) void lact_kernel(ushort* __restrict__ Lmat, float* __restrict__ xnrow) {
    __shared__ float red[4];
    int64_t row = blockIdx.x; int t = threadIdx.x;
    ushort* r = Lmat + row * (int64_t)NCQ;
    ushort4 u = *(ushort4*)&r[4 * t];
    float v[4] = {bf2f(u.x), bf2f(u.y), bf2f(u.z), bf2f(u.w)};
    float g[4]; float s = 0.f;
#pragma unroll
    for (int i = 0; i < 4; i++) {
        int idx = 4 * t + i;
        if (idx > 0) { g[i] = gelu_f(v[i]); s += g[i] * g[i]; } else g[i] = 0.f;
    }
    s = blockRedSum(s, red);
    if (t == 0) g[0] = sqrtf(1.0f + s);
    ushort4 o; o.x = f2bf(g[0]); o.y = f2bf(g[1]); o.z = f2bf(g[2]); o.w = f2bf(g[3]);
    *(ushort4*)&r[4 * t] = o;
    if (t == 0) xnrow[row] = sqrtf(fmaxf(1.0f + 2.0f * s, 1e-15f));
}

// column-norm stage A (partials)
__global__ __launch_bounds__(256) void colnormA_kernel(const ushort* __restrict__ Lmat, float* __restrict__ part) {
    int b = blockIdx.x, chunk = blockIdx.y, t = threadIdx.x;
    const ushort* base = Lmat + (int64_t)b * NSQ * NCQ + (int64_t)chunk * 128 * NCQ + 4 * t;
    float s0 = 0.f, s1 = 0.f, s2 = 0.f, s3 = 0.f;
    for (int n = 0; n < 128; n++) {
        ushort4 u = *(const ushort4*)(base + (int64_t)n * NCQ);
        float a = bf2f(u.x), bb = bf2f(u.y), c = bf2f(u.z), d = bf2f(u.w);
        s0 += a * a; s1 += bb * bb; s2 += c * c; s3 += d * d;
    }
    float4 o = {s0, s1, s2, s3};
    *(float4*)(part + ((int64_t)(b * 8 + chunk)) * 4096 + 4 * t) = o;
}
// fused colnormB + mobius column scale on mx_cT (xncol stays in registers)
__global__ __launch_bounds__(256) void cnscale_kernel(const float* __restrict__ part,
                                                      float* __restrict__ mxcT) {
    int b = blockIdx.x; int m = blockIdx.y * 256 + threadIdx.x;
    const float* p = part + (int64_t)b * 8 * 4096 + m;
    float s = 0.f;
#pragma unroll
    for (int c = 0; c < 8; c++) s += p[c * 4096];
    float xn = sqrtf(fmaxf(s, 1e-15f));
    float* base = mxcT + (int64_t)b * KQ * NCQ + m;
    float sm = 0.f;
    for (int j = 0; j < KQ; j++) { float v = base[j * NCQ]; sm += v * v; }
    float mxn = sqrtf(fmaxf(sm, 1e-15f));
    float fac = tanhf(mxn / xn * artanh_clip(xn)) / mxn;
    for (int j = 0; j < KQ; j++) base[j * NCQ] *= fac;
}

// Hs path rowwise chain -> logits (p from bf16 HsA)
__global__ __launch_bounds__(64) void rowops_s_kernel(
    const ushort* __restrict__ Hsa, const float* __restrict__ mxs,
    const float* __restrict__ xnrow, const float* __restrict__ whs,
    float* __restrict__ logits)
{
    int64_t row = blockIdx.x; int t = threadIdx.x;
    const ushort* p = Hsa + row * KQ;
    const float* q = mxs + row * KQ;
    float p0 = bf2f(p[t]), p1 = bf2f(p[t + 64]), q0 = q[t], q1 = q[t + 64];
    float mxn = sqrtf(fmaxf(waveRedSum(q0 * q0 + q1 * q1), 1e-15f));
    float xn = xnrow[row];
    float fac = tanhf(mxn / xn * artanh_clip(xn)) / mxn;
    float y0 = fac * q0, y1 = fac * q1;
    float xy = waveRedSum(p0 * y0 + p1 * y1);
    float x2 = waveRedSum(p0 * p0 + p1 * p1);
    float y2 = waveRedSum(y0 * y0 + y1 * y1);
    float ca = 1.f + 2.f * xy + y2, cb = 1.f - x2;
    float den = fmaxf(1.f + 2.f * xy + x2 * y2, 1e-15f);
    float h0 = (ca * p0 + cb * y0) / den, h1 = (ca * p1 + cb * y1) / den;
    float hn = sqrtf(fmaxf(waveRedSum(h0 * h0 + h1 * h1), 1e-15f));
    float uf = artanh_clip(hn) / hn;
    float g0 = gelu_f(uf * h0), g1 = gelu_f(uf * h1);
    float gn = sqrtf(fmaxf(waveRedSum(g0 * g0 + g1 * g1), 1e-15f));
    float ef = tanhf(gn) / gn;
    float H0 = ef * g0, H1 = ef * g1;
    float dot = waveRedSum(H0 * whs[t] + H1 * whs[t + 64]);
    float Hn = sqrtf(fmaxf(waveRedSum(H0 * H0 + H1 * H1), 1e-15f));
    float mxn2 = sqrtf(fmaxf(dot * dot, 1e-15f));
    float lg = tanhf(mxn2 / Hn * artanh_clip(Hn)) * dot / mxn2;
    if (t == 0) logits[row] = lg;
}

// transpose (z batches of 1024x128) -> (z batches of 128x1024)
__global__ void thsa_kernel(const ushort* __restrict__ in, ushort* __restrict__ outp) {
    __shared__ ushort tile[32][33];
    int z = blockIdx.z;
    int n0 = blockIdx.x * 32, j0 = blockIdx.y * 32;
    const ushort* ib = in + (int64_t)z * 131072;
    ushort* ob = outp + (int64_t)z * 131072;
    int tx = threadIdx.x, ty = threadIdx.y;
    for (int i = 0; i < 32; i += 8) tile[ty + i][tx] = ib[(n0 + ty + i) * 128 + j0 + tx];
    __syncthreads();
    for (int i = 0; i < 32; i += 8) ob[(j0 + ty + i) * 1024 + n0 + tx] = tile[tx][ty + i];
}

// Hc path rowwise chain (per (b,k) over NC), x from bf16 HcAT, y in place
__global__ __launch_bounds__(256) void rowops_c_kernel(const ushort* __restrict__ HcAT, float* __restrict__ y) {
    __shared__ float red[4];
    int64_t row = blockIdx.x;
    const ushort* xbase = HcAT + row * (int64_t)NCQ;
    float* yr = y + row * (int64_t)NCQ;
    int t = threadIdx.x;
    float xv[4], yv[4];
    float xy = 0.f, x2 = 0.f, y2 = 0.f;
#pragma unroll
    for (int i = 0; i < 4; i++) {
        int m = t + 256 * i;
        xv[i] = bf2f(xbase[m]); yv[i] = yr[m];
        xy += xv[i] * yv[i]; x2 += xv[i] * xv[i]; y2 += yv[i] * yv[i];
    }
    xy = blockRedSum(xy, red);
    x2 = blockRedSum(x2, red);
    y2 = blockRedSum(y2, red);
    float ca = 1.f + 2.f * xy + y2, cb = 1.f - x2;
    float den = fmaxf(1.f + 2.f * xy + x2 * y2, 1e-15f);
    float h[4]; float hn2 = 0.f;
#pragma unroll
    for (int i = 0; i < 4; i++) { h[i] = (ca * xv[i] + cb * yv[i]) / den; hn2 += h[i] * h[i]; }
    hn2 = blockRedSum(hn2, red);
    float hn = sqrtf(fmaxf(hn2, 1e-15f));
    float uf = artanh_clip(hn) / hn;
    float g[4]; float gn2 = 0.f;
#pragma unroll
    for (int i = 0; i < 4; i++) { g[i] = gelu_f(uf * h[i]); gn2 += g[i] * g[i]; }
    gn2 = blockRedSum(gn2, red);
    float gn = sqrtf(fmaxf(gn2, 1e-15f));
    float ef = tanhf(gn) / gn;
#pragma unroll
    for (int i = 0; i < 4; i++) yr[t + 256 * i] = ef * g[i];
}

// Ac logits
__global__ __launch_bounds__(256) void logitsc_kernel(const float* __restrict__ Hc, const float* __restrict__ whc, float* __restrict__ lgc) {
    int b = blockIdx.x; int m = blockIdx.y * 256 + threadIdx.x;
    const float* base = Hc + (int64_t)b * KQ * NCQ + m;
    float s1 = 0.f, s2 = 0.f;
    for (int j = 0; j < KQ; j++) { float v = base[j * NCQ]; s1 += v * whc[j]; s2 += v * v; }
    float xn = sqrtf(fmaxf(s2, 1e-15f));
    float mxn = sqrtf(fmaxf(s1 * s1, 1e-15f));
    lgc[b * NCQ + m] = tanhf(mxn / xn * artanh_clip(xn)) * s1 / mxn;
}

// fused softmax for lgs|lgc (contiguous) -> AsOut|AcOut (contiguous), grid 64
__global__ __launch_bounds__(256) void softmax_kernel(const float* __restrict__ lg, float* __restrict__ outp) {
    __shared__ float red[4];
    int b = blockIdx.x; int t = threadIdx.x;
    const float* x = lg + b * 1024;
    float v[4]; float m = -1e30f;
#pragma unroll
    for (int i = 0; i < 4; i++) { v[i] = x[t + 256 * i]; m = fmaxf(m, v[i]); }
    m = blockRedMax(m, red);
    float s = 0.f;
#pragma unroll
    for (int i = 0; i < 4; i++) { v[i] = expf(v[i] - m); s += v[i]; }
    s = blockRedSum(s, red);
    float inv = 1.0f / s;
#pragma unroll
    for (int i = 0; i < 4; i++) outp[b * 1024 + t + 256 * i] = v[i] * inv;
}

// centroid stage A on bf16 L (stride 288, time at col 0)
__global__ __launch_bounds__(320) void centroidA_kernel(
    const ushort* __restrict__ Lsb, const ushort* __restrict__ Lcb,
    const float* __restrict__ As, const float* __restrict__ Ac,
    float* __restrict__ part)
{
    int b = blockIdx.x;
    int which = blockIdx.y;
    int chunk = blockIdx.z;
    const ushort* L = which ? Lcb : Lsb;
    const float* w = which ? Ac : As;
    int t = threadIdx.x;
    if (t >= DP) return;
    const ushort* Lb = L + (int64_t)b * NSQ * KPAD + (int64_t)chunk * 128 * KPAD + t;
    const float* wb = w + b * NSQ + chunk * 128;
    float s = 0.f;
    for (int n = 0; n < 128; n++) s += wb[n] * bf2f(Lb[(int64_t)n * KPAD]);
    part[((int64_t)((b * 2 + which) * 8 + chunk)) * 264 + t] = s;
}
__global__ __launch_bounds__(320) void centroidB_kernel(
    const float* __restrict__ part, float* __restrict__ co_s, float* __restrict__ co_c)
{
    int b = blockIdx.x;
    int which = blockIdx.y;
    int t = threadIdx.x;
    if (t >= DP) return;
    const float* p = part + (int64_t)(b * 2 + which) * 8 * 264 + t;
    float s = 0.f;
#pragma unroll
    for (int c = 0; c < 8; c++) s += p[c * 264];
    (which ? co_c : co_s)[b * DP + t] = s;
}

__global__ __launch_bounds__(256) void final_kernel(const float* __restrict__ co_s, const float* __restrict__ co_c, float* __restrict__ outp) {
    __shared__ float red[4];
    int b = blockIdx.x, t = threadIdx.x;
    float zmine[2];
    for (int w = 0; w < 2; w++) {
        const float* co = (w ? co_c : co_s) + b * DP;
        float at = co[0];
        float asp = co[1 + t];
        float ssp = blockRedSum(asp * asp, red);
        float li = ssp - at * at;
        float den = sqrtf(fmaxf(fabsf(li), 1e-8f));
        float xt = at / den, xsp = asp / den;
        float s2 = blockRedSum(xsp * xsp, red);
        float nrm = sqrtf(fmaxf(s2, 1e-15f));
        float ac = acoshf(fmaxf(xt, 1.0f + 1e-7f));
        zmine[w] = ac * xsp / nrm;
    }
    float vn2 = blockRedSum(zmine[0] * zmine[0] + zmine[1] * zmine[1], red);
    float vn = sqrtf(fmaxf(vn2, 1e-15f));
    float sc = sinhf(vn) / vn;
    if (t == 0) outp[b * 513] = coshf(vn);
    outp[b * 513 + 1 + t] = sc * zmine[0];
    outp[b * 513 + 1 + 256 + t] = sc * zmine[1];
}

// ---------------- host launcher ----------------
extern "C" void kernel_launch(void* const* d_in, const int* in_sizes, int n_in,
                              void* d_out, int out_size, void* d_ws, size_t ws_size,
                              hipStream_t stream)
{
    const float* sent = (const float*)d_in[0];
    const float* comm = (const float*)d_in[1];
    const float* WlW  = (const float*)d_in[2];
    const float* Wlb  = (const float*)d_in[3];
    const float* WcW  = (const float*)d_in[4];
    const float* Wcb  = (const float*)d_in[5];
    const float* WsW  = (const float*)d_in[6];
    const float* Wsb  = (const float*)d_in[7];
    const float* whs  = (const float*)d_in[8];
    const float* whc  = (const float*)d_in[9];
    float* out = (float*)d_out;
    (void)in_sizes; (void)n_in; (void)out_size; (void)ws_size;

    float* ws = (float*)d_ws;
    size_t off = 0;
    auto take = [&](size_t n) { float* p = ws + off; off += n; return p; };
    float*  xnrow = take(32768);
    float*  lgs   = take(32768);   // contiguous with lgc
    float*  lgc   = take(32768);
    float*  co_s  = take(8224);
    float*  co_c  = take(8224);
    ushort* Ls_bf = (ushort*)take(4718592);   // contiguous with Lc_bf
    ushort* Lc_bf = (ushort*)take(4718592);
    ushort* Wl_bf = (ushort*)take(36864);
    ushort* Ws_bf = (ushort*)take(18432);
    ushort* Wc_bf = (ushort*)take(18432);
    ushort* HsA_bf = (ushort*)take(2097152);  // contiguous with HcA_bf
    ushort* HcA_bf = (ushort*)take(2097152);
    float*  part_cn   = take(1048576);
    float*  part_cent = take(135168);
    float*  F     = take(33554432);           // ~185 MiB total

    // Phase overlays in F (float offsets)
    ushort* XC_bf   = (ushort*)F;                 // [P1] 64x640x256 us = 5.24M fl
    ushort* XS_bf   = (ushort*)(F + 5242880);     // [P1] 5.24M fl
    ushort* Ff_bf   = (ushort*)(F + 10485760);    // [P1] 64x256x1280 us = 10.49M fl
    ushort* CS1c    = (ushort*)(F + 20971520);    // [P1] 640x640 us = 204800 fl
    ushort* CS1s    = (ushort*)(F + 21176320);    // [P1] 204800 fl
    ushort* C2_bf   = (ushort*)(F + 21381120);    // [P1] 32k fl
    ushort* S2_bf   = (ushort*)(F + 21413888);    // [P1] 32k fl
    ushort* YcYs    = (ushort*)F;                 // [P1] aliases XC/XS (dead after stage-1); 10.49M fl
    ushort* Lmat_bf = (ushort*)F;                 // [P3-P5] 16.78M fl
    float*  Llin_sp = F + 16777216;               // [P2] 8.39M fl
    ushort* Llin_bf = (ushort*)(F + 25165824);    // [P2-P3] 4.72M fl
    float*  ycat    = F + 16777216;               // [P4] 8.39M fl (ys | yc)
    float*  mx      = F + 16777216;               // [P5] 4.19M fl
    ushort* HsAT    = (ushort*)(F + 20971520);    // [P5] 2.1M fl, contiguous with HcAT
    ushort* HcAT    = (ushort*)(F + 23068672);    // [P5] 2.1M fl

    float* AsOut = out + 16416;
    float* AcOut = out + 16416 + 32768;

    dim3 blk(256);
    const short* NUL = nullptr;

    // constants in one launch
    genconst_kernel<<<3968, 256, 0, stream>>>(CS1c, CS1s, C2_bf, S2_bf, WlW, WsW, WcW, Wl_bf, Ws_bf, Wc_bf);

    // ---- input prep + m-fold (sent z 0-31, comment z 32-63) ----
    prep_fold_kernel<<<dim3(513, 64), 256, 0, stream>>>(sent, comm, XC_bf, XS_bf);
    // stage-1 DUAL: half 0: Ff[:, :640] = C2 . XC^T ; half 1: Ff[:, 640:] = S2 . XS^T
    mfma_gemm<false,false,true,false,false,1,true><<<dim3(5,2,128), blk, 0, stream>>>(
        (const short*)C2_bf,256,0, (const short*)XC_bf,256,(int64_t)NFOLD*256, Ff_bf,1280,(int64_t)256*1280,
        nullptr, 256,NFOLD,256, (const short*)S2_bf, (const short*)XS_bf, 640);
    // stage-2 DUAL (n-folded): half 0: Yc = CS1c . Fc^T ; half 1: Ys = CS1s . Fs^T
    mfma_gemm<false,false,true,false,false,1,true><<<dim3(2,5,128), blk, 0, stream>>>(
        (const short*)CS1c,KF2,0, (const short*)Ff_bf,1280,(int64_t)256*1280, YcYs,256,327680,
        nullptr, NFOLD,256,KF2, (const short*)CS1s, (const short*)(Ff_bf+640), 163840);
    e2l_kernel<<<65536, 256, 0, stream>>>(YcYs, Ls_bf, Lc_bf);

    // ---- L = lorentz_linear(Lc, Wl): space cols only ----
    mfma_gemm<false,false,false,true,false,1,false><<<dim3(2,256,1), blk, 0, stream>>>(
        (const short*)Lc_bf,KPAD,0, (const short*)Wl_bf,KPAD,0, Llin_sp,256,0,
        Wlb+1, 32768,256,KPAD, NUL, NUL, 0);
    lfix2_kernel<<<32768, 256, 0, stream>>>(Llin_sp, Llin_bf);

    // ---- Lmat = lorentz_act(einsum(Ls, Llin)) in bf16 ----
    mfma_gemm<false,false,true,false,false,1,false><<<dim3(8,8,32), blk, 0, stream>>>(
        (const short*)Ls_bf,KPAD,294912, (const short*)Llin_bf,KPAD,294912, Lmat_bf,1024,1048576,
        nullptr, 1024,1024,KPAD, NUL, NUL, 0);
    lact_kernel<<<32768, 256, 0, stream>>>(Lmat_bf, xnrow);
    colnormA_kernel<<<dim3(32,8), 256, 0, stream>>>(Lmat_bf, part_cn);

    // ---- Hs_a / Hc_a merged (z=0: Ls*Ws, z=1: Lc*Wc), bias in poinc2 ----
    mfma_gemm<false,false,false,false,false,1,false><<<dim3(1,256,2), blk, 0, stream>>>(
        (const short*)Ls_bf,KPAD,9437184, (const short*)Ws_bf,KPAD,36864, ycat,128,4194304,
        nullptr, 32768,128,KPAD, NUL, NUL, 0);
    poinc2_kernel<<<65536, 128, 0, stream>>>(ycat, Wsb, Wcb, HsA_bf);

    // ---- transpose HsA_bf and HcA_bf (contiguous) in one launch ----
    thsa_kernel<<<dim3(32,4,64), dim3(32,8), 0, stream>>>(HsA_bf, HsAT);

    // ---- Hs path: mx_s = Lmat . Hc_a (fast TT via HcAT; split-K=4, atomic) ----
    hipMemsetAsync(mx, 0, 4194304 * sizeof(float), stream);
    mfma_gemm<false,false,false,false,true,4,false><<<dim3(1,8,128), blk, 0, stream>>>(
        (const short*)Lmat_bf,1024,1048576, (const short*)HcAT,1024,131072, mx,128,131072,
        nullptr, 1024,128,1024, NUL, NUL, 0);
    rowops_s_kernel<<<32768, 64, 0, stream>>>(HsA_bf, mx, xnrow, whs, lgs);

    // ---- Hc path: mx_cT = Hs_a^T . Lmat (A fast via HsAT; split-K=4) ----
    hipMemsetAsync(mx, 0, 4194304 * sizeof(float), stream);
    mfma_gemm<false,true,false,false,true,4,false><<<dim3(8,1,128), blk, 0, stream>>>(
        (const short*)HsAT,1024,131072, (const short*)Lmat_bf,1024,1048576, mx,1024,131072,
        nullptr, 128,1024,1024, NUL, NUL, 0);
    cnscale_kernel<<<dim3(32,4), 256, 0, stream>>>(part_cn, mx);
    rowops_c_kernel<<<4096, 256, 0, stream>>>(HcAT, mx);
    logitsc_kernel<<<dim3(32,4), 256, 0, stream>>>(mx, whc, lgc);

    // ---- fused softmaxes / centroids / concat ----
    softmax_kernel<<<64, 256, 0, stream>>>(lgs, AsOut);
    centroidA_kernel<<<dim3(32,2,8), 320, 0, stream>>>(Ls_bf, Lc_bf, AsOut, AcOut, part_cent);
    centroidB_kernel<<<dim3(32,2), 320, 0, stream>>>(part_cent, co_s, co_c);
    final_kernel<<<32, 256, 0, stream>>>(co_s, co_c, out);
}

// Round 9
// 629.810 us; speedup vs baseline: 1.3214x; 1.1534x over previous
//
#include <hip/hip_runtime.h>
#include <cstdint>
#include <math.h>

#define NBATCH 32
#define NSQ 1024
#define NCQ 1024
#define DDIM 256
#define DP 257
#define KQ 128
#define KPAD 288   // 257 padded to /32
#define NFOLD 640  // folded m rows per batch (513 padded to /128)
#define KF2 640    // folded stage-2 K (513 used)

typedef __attribute__((ext_vector_type(8))) short short8;
typedef __attribute__((ext_vector_type(4))) float floatx4;

// ---------------- device helpers ----------------
__device__ __forceinline__ float bf2f(ushort u) { return __uint_as_float(((uint)u) << 16); }
__device__ __forceinline__ ushort f2bf(float f) {
    uint u = __float_as_uint(f);
    return (ushort)((u + 0x7FFFu + ((u >> 16) & 1u)) >> 16);
}
__device__ __forceinline__ void gload16(const void* g, void* l) {
    __builtin_amdgcn_global_load_lds(
        (const __attribute__((address_space(1))) void*)g,
        (__attribute__((address_space(3))) void*)l,
        16, 0, 0);
}
__device__ __forceinline__ float artanh_clip(float x) {
    x = fminf(fmaxf(x, -1.0f + 1e-5f), 1.0f - 1e-5f);
    return 0.5f * (log1pf(x) - log1pf(-x));
}
__device__ __forceinline__ float gelu_f(float x) {
    return 0.5f * x * (1.0f + erff(x * 0.70710678118654752440f));
}
__device__ __forceinline__ float waveRedSum(float v) {
#pragma unroll
    for (int o = 32; o > 0; o >>= 1) v += __shfl_down(v, o, 64);
    return __shfl(v, 0, 64);
}
__device__ __forceinline__ float blockRedSum(float v, float* buf) {
    int lane = threadIdx.x & 63, wid = threadIdx.x >> 6;
#pragma unroll
    for (int o = 32; o > 0; o >>= 1) v += __shfl_down(v, o, 64);
    __syncthreads();
    if (lane == 0) buf[wid] = v;
    __syncthreads();
    int nw = blockDim.x >> 6;
    float s = buf[0];
    for (int i = 1; i < nw; i++) s += buf[i];
    return s;
}
__device__ __forceinline__ float blockRedMax(float v, float* buf) {
    int lane = threadIdx.x & 63, wid = threadIdx.x >> 6;
#pragma unroll
    for (int o = 32; o > 0; o >>= 1) v = fmaxf(v, __shfl_down(v, o, 64));
    __syncthreads();
    if (lane == 0) buf[wid] = v;
    __syncthreads();
    int nw = blockDim.x >> 6;
    float s = buf[0];
    for (int i = 1; i < nw; i++) s = fmaxf(s, buf[i]);
    return s;
}

// ---------------- bf16 MFMA GEMM ----------------
// C[m,n] = sum_k A[m,k]*B'[k,n] (+bias[n]; biasB used when zb!=0)
template <bool A_NN, bool B_NN, bool OUT_BF16, bool BIAS, bool ATOMIC, int NSPLIT, bool DUAL>
__global__ __launch_bounds__(256) void mfma_gemm(
    const short* __restrict__ A, int lda, int64_t sA,
    const short* __restrict__ B, int ldb, int64_t sB,
    void* __restrict__ Cv, int ldc, int64_t sC,
    const float* __restrict__ bias, int M, int N, int K,
    const short* __restrict__ A1, const short* __restrict__ B1, int64_t cOff1,
    const float* __restrict__ biasB)
{
    __shared__ short As[128][32];
    __shared__ short Bs[128][32];
    const int zz = blockIdx.z;
    int zb, ks, half;
    if (DUAL) { half = zz & 1; zb = zz >> 1; ks = 0; }
    else      { zb = zz / NSPLIT; ks = zz - zb * NSPLIT; half = 0; }
    const short* Ap = (DUAL && half) ? A1 : A;
    const short* Bp = (DUAL && half) ? B1 : B;
    Ap += (int64_t)zb * sA;
    Bp += (int64_t)zb * sB;
    const int kper = K / NSPLIT;
    const int kbeg = ks * kper, kend = kbeg + kper;
    const int m0 = blockIdx.y * 128, n0 = blockIdx.x * 128;
    const int t = threadIdx.x;
    const int lane = t & 63, w = t >> 6;
    const int wm = (w & 1) * 64, wn = (w >> 1) * 64;
    floatx4 acc[4][4] = {};
    for (int k0 = kbeg; k0 < kend; k0 += 32) {
        if (!A_NN) {
            int r = t >> 2, c8 = (t & 3) * 8;
            const short* ap = Ap + (int64_t)(m0 + r) * lda + k0 + c8;
            gload16(ap, &As[r][c8]);
            gload16(ap + (int64_t)64 * lda, &As[r + 64][c8]);
        } else {
            int r2 = t >> 4, c8 = (t & 15) * 8;
            int kk = 2 * r2;
            const ushort* a0 = (const ushort*)Ap + (int64_t)(k0 + kk) * lda + m0 + c8;
            uint4 v0 = *(const uint4*)a0;
            uint4 v1 = *(const uint4*)(a0 + lda);
            const ushort* p0 = (const ushort*)&v0;
            const ushort* p1 = (const ushort*)&v1;
#pragma unroll
            for (int i = 0; i < 8; i++) {
                uint pk = (uint)p0[i] | ((uint)p1[i] << 16);
                *(uint*)&As[c8 + i][kk] = pk;
            }
        }
        if (!B_NN) {
            int r = t >> 2, c8 = (t & 3) * 8;
            const short* bp = Bp + (int64_t)(n0 + r) * ldb + k0 + c8;
            gload16(bp, &Bs[r][c8]);
            gload16(bp + (int64_t)64 * ldb, &Bs[r + 64][c8]);
        } else {
            int r2 = t >> 4, c8 = (t & 15) * 8;
            int kk = 2 * r2;
            const ushort* b0 = (const ushort*)Bp + (int64_t)(k0 + kk) * ldb + n0 + c8;
            uint4 v0 = *(const uint4*)b0;
            uint4 v1 = *(const uint4*)(b0 + ldb);
            const ushort* p0 = (const ushort*)&v0;
            const ushort* p1 = (const ushort*)&v1;
#pragma unroll
            for (int i = 0; i < 8; i++) {
                uint pk = (uint)p0[i] | ((uint)p1[i] << 16);
                *(uint*)&Bs[c8 + i][kk] = pk;
            }
        }
        __syncthreads();
        short8 af[4], bfv[4];
#pragma unroll
        for (int i = 0; i < 4; i++)
            af[i] = *(const short8*)&As[wm + 16 * i + (lane & 15)][8 * (lane >> 4)];
#pragma unroll
        for (int i = 0; i < 4; i++)
            bfv[i] = *(const short8*)&Bs[wn + 16 * i + (lane & 15)][8 * (lane >> 4)];
#pragma unroll
        for (int i = 0; i < 4; i++)
#pragma unroll
            for (int j = 0; j < 4; j++)
                acc[i][j] = __builtin_amdgcn_mfma_f32_16x16x32_bf16(af[i], bfv[j], acc[i][j], 0, 0, 0);
        __syncthreads();
    }
    const int q = lane >> 4, c = lane & 15;
    const int64_t cbase = (int64_t)zb * sC + ((DUAL && half) ? cOff1 : 0);
    const float* bsel = (BIAS && biasB && zb) ? biasB : bias;
#pragma unroll
    for (int j = 0; j < 4; j++) {
        int col = n0 + wn + 16 * j + c;
        float bv = BIAS ? bsel[col] : 0.0f;
#pragma unroll
        for (int i = 0; i < 4; i++) {
            int rowb = m0 + wm + 16 * i + 4 * q;
#pragma unroll
            for (int r = 0; r < 4; r++) {
                float v = acc[i][j][r] + bv;
                int64_t idx = cbase + (int64_t)(rowb + r) * ldc + col;
                if (ATOMIC)       atomicAdd((float*)Cv + idx, v);
                else if (OUT_BF16) ((ushort*)Cv)[idx] = f2bf(v);
                else               ((float*)Cv)[idx] = v;
            }
        }
    }
}

// ---------------- fused constants ----------------
__global__ __launch_bounds__(256) void genconst_kernel(
    ushort* CS1c, ushort* CS1s, ushort* C2, ushort* S2,
    const float* __restrict__ WlW, const float* __restrict__ WsW, const float* __restrict__ WcW,
    ushort* Wl, ushort* Ws, ushort* Wc)
{
    int blk = blockIdx.x, t = threadIdx.x;
    if (blk < 3200) {
        int idx = blk * 256 + t;                 // 2 x 640*640
        int hs = idx >= 409600;
        int e = idx - hs * 409600;
        int n = e / KF2, k = e - n * KF2;
        float v = 0.0f;
        if (k <= 512) {
            int p = (n * k) & 1023;
            float ang = (6.28318530717958647692f / 1024.0f) * (float)p;
            v = hs ? ((k == 0) ? 0.0f : -sinf(ang)) : cosf(ang);
        }
        (hs ? CS1s : CS1c)[e] = f2bf(v);
    } else if (blk < 3456) {
        int idx = (blk - 3200) * 256 + t;        // 256x256
        int d = idx >> 8, j = idx & 255;
        int p = (d * j) & 255;
        float ang = (6.28318530717958647692f / 256.0f) * (float)p;
        C2[idx] = f2bf(cosf(ang));
        S2[idx] = f2bf(sinf(ang));
    } else {
        int r = blk - 3456;                      // 512 rows
        const float* src; ushort* dst; int srow;
        if (r < 256)      { src = WlW; dst = Wl + r * KPAD;        srow = r + 1; }
        else if (r < 384) { src = WsW; dst = Ws + (r - 256) * KPAD; srow = r - 256 + 1; }
        else              { src = WcW; dst = Wc + (r - 384) * KPAD; srow = r - 384 + 1; }
        dst[t] = (t < DP) ? f2bf(src[(int64_t)srow * DP + t]) : (ushort)0;
        if (t < KPAD - 256) {
            int t2 = t + 256;
            dst[t2] = (t2 < DP) ? f2bf(src[(int64_t)srow * DP + t2]) : (ushort)0;
        }
    }
}

// input prep + m-fold, wave-per-(bp,z): z<32 sent (cast), z>=32 comm (p_logmap0)
__global__ __launch_bounds__(256) void prep_fold_kernel(const float* __restrict__ sent,
                                                        const float* __restrict__ comm,
                                                        ushort* __restrict__ XC, ushort* __restrict__ XS) {
    int bp = blockIdx.x;                       // 0..512
    int z = blockIdx.y * 4 + (threadIdx.x >> 6);
    int lane = threadIdx.x & 63;
    int m2 = (1024 - bp) & 1023;
    const float* base = (z < 32) ? sent + (int64_t)z * 262144 : comm + (int64_t)(z - 32) * 262144;
    float4 a = *(const float4*)(base + bp * 256 + 4 * lane);
    float4 b = *(const float4*)(base + m2 * 256 + 4 * lane);
    if (z >= 32) {
        float s1 = waveRedSum(a.x * a.x + a.y * a.y + a.z * a.z + a.w * a.w);
        float yn1 = sqrtf(fmaxf(s1, 1e-15f));
        float f1 = artanh_clip(yn1) / yn1;
        a.x *= f1; a.y *= f1; a.z *= f1; a.w *= f1;
        float s2 = waveRedSum(b.x * b.x + b.y * b.y + b.z * b.z + b.w * b.w);
        float yn2 = sqrtf(fmaxf(s2, 1e-15f));
        float f2v = artanh_clip(yn2) / yn2;
        b.x *= f2v; b.y *= f2v; b.z *= f2v; b.w *= f2v;
    }
    int64_t o = ((int64_t)z * NFOLD + bp) * 256 + 4 * lane;
    bool single = (bp == 0) || (bp == 512);
    ushort4 oc;
    oc.x = f2bf(single ? a.x : a.x + b.x);
    oc.y = f2bf(single ? a.y : a.y + b.y);
    oc.z = f2bf(single ? a.z : a.z + b.z);
    oc.w = f2bf(single ? a.w : a.w + b.w);
    *(ushort4*)(XC + o) = oc;
    if (!single) {
        ushort4 os;
        os.x = f2bf(a.x - b.x); os.y = f2bf(a.y - b.y);
        os.z = f2bf(a.z - b.z); os.w = f2bf(a.w - b.w);
        *(ushort4*)(XS + o) = os;
    }
}

// euclid_to_lorentz, wave-per-row, n-fold combine, exp-based sinh/cosh
__global__ __launch_bounds__(256) void e2l_kernel(const ushort* __restrict__ YcYs,
                                                  ushort* __restrict__ Lsb, ushort* __restrict__ Lcb) {
    int64_t row = (int64_t)blockIdx.x * 4 + (threadIdx.x >> 6);   // 0..65535
    int lane = threadIdx.x & 63;
    int z = (int)(row >> 10), n = (int)(row & 1023);
    int np = (n <= 512) ? n : 1024 - n;
    float sgn = (n <= 512) ? 1.0f : -1.0f;
    const ushort* base = YcYs + (int64_t)z * 327680 + np * 256 + 4 * lane;
    ushort4 uc = *(const ushort4*)base;
    ushort4 us = *(const ushort4*)(base + 163840);
    float v0 = bf2f(uc.x) + sgn * bf2f(us.x);
    float v1 = bf2f(uc.y) + sgn * bf2f(us.y);
    float v2 = bf2f(uc.z) + sgn * bf2f(us.z);
    float v3 = bf2f(uc.w) + sgn * bf2f(us.w);
    float s = waveRedSum(v0 * v0 + v1 * v1 + v2 * v2 + v3 * v3);
    float xn = sqrtf(fmaxf(s, 1e-15f)) + 1e-5f;
    float sc = fminf(1.0f, 2.0f / xn);
    float s2 = fmaxf(s * sc * sc, 1e-15f);
    float vn = sqrtf(s2);
    float e = expf(vn);
    float ei = 1.0f / e;
    float shv = (vn < 1e-4f) ? 1.0f : (e - ei) * 0.5f / vn;   // sinh(vn)/vn
    float fac = shv * sc;
    ushort* ob = (row < 32768 ? Lsb + row * KPAD : Lcb + (row - 32768) * KPAD);
    ob[1 + 4 * lane + 0] = f2bf(fac * v0);
    ob[1 + 4 * lane + 1] = f2bf(fac * v1);
    ob[1 + 4 * lane + 2] = f2bf(fac * v2);
    ob[1 + 4 * lane + 3] = f2bf(fac * v3);
    if (lane == 0) ob[0] = f2bf((e + ei) * 0.5f);
    if (lane < KPAD - DP) ob[DP + lane] = 0;
}

// lorentz_linear time fill (in place on bf16 rows of 288, space already at [1..257))
__global__ __launch_bounds__(256) void lnorm_kernel(ushort* __restrict__ Llin_bf) {
    int64_t row = (int64_t)blockIdx.x * 4 + (threadIdx.x >> 6);
    int lane = threadIdx.x & 63;
    ushort* ob = Llin_bf + row * KPAD;
    float s = 0.f;
#pragma unroll
    for (int i = 0; i < 4; i++) { float v = bf2f(ob[1 + 4 * lane + i]); s += v * v; }
    s = waveRedSum(s);
    if (lane == 0) ob[0] = f2bf(sqrtf(s + 1.0f));
    if (lane < KPAD - DP) ob[DP + lane] = 0;
}

// to_poincare in place on bf16 rows of 128 (bias already added in GEMM)
__global__ __launch_bounds__(256) void poinc2_kernel(ushort* __restrict__ Hcat) {
    int64_t row = (int64_t)blockIdx.x * 4 + (threadIdx.x >> 6);
    int lane = threadIdx.x & 63;
    ushort* r = Hcat + row * KQ;
    ushort2 u = *(ushort2*)&r[2 * lane];
    float v0 = bf2f(u.x), v1 = bf2f(u.y);
    float s = waveRedSum(v0 * v0 + v1 * v1);
    float inv = 1.0f / (sqrtf(s + 1.0f) + 1.0f);
    ushort2 o; o.x = f2bf(v0 * inv); o.y = f2bf(v1 * inv);
    *(ushort2*)&r[2 * lane] = o;
}

// lorentz_act on bf16 Lmat rows (1024), in place, + xnrow
__global__ __launch_bounds__(256) void lact_kernel(ushort* __restrict__ Lmat, float* __restrict__ xnrow) {
    __shared__ float red[4];
    int64_t row = blockIdx.x; int t = threadIdx.x;
    ushort* r = Lmat + row * (int64_t)NCQ;
    ushort4 u = *(ushort4*)&r[4 * t];
    float v[4] = {bf2f(u.x), bf2f(u.y), bf2f(u.z), bf2f(u.w)};
    float g[4]; float s = 0.f;
#pragma unroll
    for (int i = 0; i < 4; i++) {
        int idx = 4 * t + i;
        if (idx > 0) { g[i] = gelu_f(v[i]); s += g[i] * g[i]; } else g[i] = 0.f;
    }
    s = blockRedSum(s, red);
    if (t == 0) g[0] = sqrtf(1.0f + s);
    ushort4 o; o.x = f2bf(g[0]); o.y = f2bf(g[1]); o.z = f2bf(g[2]); o.w = f2bf(g[3]);
    *(ushort4*)&r[4 * t] = o;
    if (t == 0) xnrow[row] = sqrtf(fmaxf(1.0f + 2.0f * s, 1e-15f));
}

// column-norm stage A (partials)
__global__ __launch_bounds__(256) void colnormA_kernel(const ushort* __restrict__ Lmat, float* __restrict__ part) {
    int b = blockIdx.x, chunk = blockIdx.y, t = threadIdx.x;
    const ushort* base = Lmat + (int64_t)b * NSQ * NCQ + (int64_t)chunk * 128 * NCQ + 4 * t;
    float s0 = 0.f, s1 = 0.f, s2 = 0.f, s3 = 0.f;
    for (int n = 0; n < 128; n++) {
        ushort4 u = *(const ushort4*)(base + (int64_t)n * NCQ);
        float a = bf2f(u.x), bb = bf2f(u.y), c = bf2f(u.z), d = bf2f(u.w);
        s0 += a * a; s1 += bb * bb; s2 += c * c; s3 += d * d;
    }
    float4 o = {s0, s1, s2, s3};
    *(float4*)(part + ((int64_t)(b * 8 + chunk)) * 4096 + 4 * t) = o;
}
// fused colnormB + mobius column scale on mx_cT
__global__ __launch_bounds__(256) void cnscale_kernel(const float* __restrict__ part,
                                                      float* __restrict__ mxcT) {
    int b = blockIdx.x; int m = blockIdx.y * 256 + threadIdx.x;
    const float* p = part + (int64_t)b * 8 * 4096 + m;
    float s = 0.f;
#pragma unroll
    for (int c = 0; c < 8; c++) s += p[c * 4096];
    float xn = sqrtf(fmaxf(s, 1e-15f));
    float* base = mxcT + (int64_t)b * KQ * NCQ + m;
    float sm = 0.f;
    for (int j = 0; j < KQ; j++) { float v = base[j * NCQ]; sm += v * v; }
    float mxn = sqrtf(fmaxf(sm, 1e-15f));
    float fac = tanhf(mxn / xn * artanh_clip(xn)) / mxn;
    for (int j = 0; j < KQ; j++) base[j * NCQ] *= fac;
}

// Hs path rowwise chain -> logits (p from bf16 HsA)
__global__ __launch_bounds__(64) void rowops_s_kernel(
    const ushort* __restrict__ Hsa, const float* __restrict__ mxs,
    const float* __restrict__ xnrow, const float* __restrict__ whs,
    float* __restrict__ logits)
{
    int64_t row = blockIdx.x; int t = threadIdx.x;
    const ushort* p = Hsa + row * KQ;
    const float* q = mxs + row * KQ;
    float p0 = bf2f(p[t]), p1 = bf2f(p[t + 64]), q0 = q[t], q1 = q[t + 64];
    float mxn = sqrtf(fmaxf(waveRedSum(q0 * q0 + q1 * q1), 1e-15f));
    float xn = xnrow[row];
    float fac = tanhf(mxn / xn * artanh_clip(xn)) / mxn;
    float y0 = fac * q0, y1 = fac * q1;
    float xy = waveRedSum(p0 * y0 + p1 * y1);
    float x2 = waveRedSum(p0 * p0 + p1 * p1);
    float y2 = waveRedSum(y0 * y0 + y1 * y1);
    float ca = 1.f + 2.f * xy + y2, cb = 1.f - x2;
    float den = fmaxf(1.f + 2.f * xy + x2 * y2, 1e-15f);
    float h0 = (ca * p0 + cb * y0) / den, h1 = (ca * p1 + cb * y1) / den;
    float hn = sqrtf(fmaxf(waveRedSum(h0 * h0 + h1 * h1), 1e-15f));
    float uf = artanh_clip(hn) / hn;
    float g0 = gelu_f(uf * h0), g1 = gelu_f(uf * h1);
    float gn = sqrtf(fmaxf(waveRedSum(g0 * g0 + g1 * g1), 1e-15f));
    float ef = tanhf(gn) / gn;
    float H0 = ef * g0, H1 = ef * g1;
    float dot = waveRedSum(H0 * whs[t] + H1 * whs[t + 64]);
    float Hn = sqrtf(fmaxf(waveRedSum(H0 * H0 + H1 * H1), 1e-15f));
    float mxn2 = sqrtf(fmaxf(dot * dot, 1e-15f));
    float lg = tanhf(mxn2 / Hn * artanh_clip(Hn)) * dot / mxn2;
    if (t == 0) logits[row] = lg;
}

// transpose (z batches of 1024x128) -> (z batches of 128x1024)
__global__ void thsa_kernel(const ushort* __restrict__ in, ushort* __restrict__ outp) {
    __shared__ ushort tile[32][33];
    int z = blockIdx.z;
    int n0 = blockIdx.x * 32, j0 = blockIdx.y * 32;
    const ushort* ib = in + (int64_t)z * 131072;
    ushort* ob = outp + (int64_t)z * 131072;
    int tx = threadIdx.x, ty = threadIdx.y;
    for (int i = 0; i < 32; i += 8) tile[ty + i][tx] = ib[(n0 + ty + i) * 128 + j0 + tx];
    __syncthreads();
    for (int i = 0; i < 32; i += 8) ob[(j0 + ty + i) * 1024 + n0 + tx] = tile[tx][ty + i];
}

// Hc path rowwise chain (per (b,k) over NC), x from bf16 HcAT, y in place
__global__ __launch_bounds__(256) void rowops_c_kernel(const ushort* __restrict__ HcAT, float* __restrict__ y) {
    __shared__ float red[4];
    int64_t row = blockIdx.x;
    const ushort* xbase = HcAT + row * (int64_t)NCQ;
    float* yr = y + row * (int64_t)NCQ;
    int t = threadIdx.x;
    float xv[4], yv[4];
    float xy = 0.f, x2 = 0.f, y2 = 0.f;
#pragma unroll
    for (int i = 0; i < 4; i++) {
        int m = t + 256 * i;
        xv[i] = bf2f(xbase[m]); yv[i] = yr[m];
        xy += xv[i] * yv[i]; x2 += xv[i] * xv[i]; y2 += yv[i] * yv[i];
    }
    xy = blockRedSum(xy, red);
    x2 = blockRedSum(x2, red);
    y2 = blockRedSum(y2, red);
    float ca = 1.f + 2.f * xy + y2, cb = 1.f - x2;
    float den = fmaxf(1.f + 2.f * xy + x2 * y2, 1e-15f);
    float h[4]; float hn2 = 0.f;
#pragma unroll
    for (int i = 0; i < 4; i++) { h[i] = (ca * xv[i] + cb * yv[i]) / den; hn2 += h[i] * h[i]; }
    hn2 = blockRedSum(hn2, red);
    float hn = sqrtf(fmaxf(hn2, 1e-15f));
    float uf = artanh_clip(hn) / hn;
    float g[4]; float gn2 = 0.f;
#pragma unroll
    for (int i = 0; i < 4; i++) { g[i] = gelu_f(uf * h[i]); gn2 += g[i] * g[i]; }
    gn2 = blockRedSum(gn2, red);
    float gn = sqrtf(fmaxf(gn2, 1e-15f));
    float ef = tanhf(gn) / gn;
#pragma unroll
    for (int i = 0; i < 4; i++) yr[t + 256 * i] = ef * g[i];
}

// Ac logits
__global__ __launch_bounds__(256) void logitsc_kernel(const float* __restrict__ Hc, const float* __restrict__ whc, float* __restrict__ lgc) {
    int b = blockIdx.x; int m = blockIdx.y * 256 + threadIdx.x;
    const float* base = Hc + (int64_t)b * KQ * NCQ + m;
    float s1 = 0.f, s2 = 0.f;
    for (int j = 0; j < KQ; j++) { float v = base[j * NCQ]; s1 += v * whc[j]; s2 += v * v; }
    float xn = sqrtf(fmaxf(s2, 1e-15f));
    float mxn = sqrtf(fmaxf(s1 * s1, 1e-15f));
    lgc[b * NCQ + m] = tanhf(mxn / xn * artanh_clip(xn)) * s1 / mxn;
}

// fused softmax for lgs|lgc -> AsOut|AcOut, grid 64
__global__ __launch_bounds__(256) void softmax_kernel(const float* __restrict__ lg, float* __restrict__ outp) {
    __shared__ float red[4];
    int b = blockIdx.x; int t = threadIdx.x;
    const float* x = lg + b * 1024;
    float v[4]; float m = -1e30f;
#pragma unroll
    for (int i = 0; i < 4; i++) { v[i] = x[t + 256 * i]; m = fmaxf(m, v[i]); }
    m = blockRedMax(m, red);
    float s = 0.f;
#pragma unroll
    for (int i = 0; i < 4; i++) { v[i] = expf(v[i] - m); s += v[i]; }
    s = blockRedSum(s, red);
    float inv = 1.0f / s;
#pragma unroll
    for (int i = 0; i < 4; i++) outp[b * 1024 + t + 256 * i] = v[i] * inv;
}

// centroid stage A on bf16 L (stride 288, time at col 0)
__global__ __launch_bounds__(320) void centroidA_kernel(
    const ushort* __restrict__ Lsb, const ushort* __restrict__ Lcb,
    const float* __restrict__ As, const float* __restrict__ Ac,
    float* __restrict__ part)
{
    int b = blockIdx.x;
    int which = blockIdx.y;
    int chunk = blockIdx.z;
    const ushort* L = which ? Lcb : Lsb;
    const float* w = which ? Ac : As;
    int t = threadIdx.x;
    if (t >= DP) return;
    const ushort* Lb = L + (int64_t)b * NSQ * KPAD + (int64_t)chunk * 128 * KPAD + t;
    const float* wb = w + b * NSQ + chunk * 128;
    float s = 0.f;
    for (int n = 0; n < 128; n++) s += wb[n] * bf2f(Lb[(int64_t)n * KPAD]);
    part[((int64_t)((b * 2 + which) * 8 + chunk)) * 264 + t] = s;
}
__global__ __launch_bounds__(320) void centroidB_kernel(
    const float* __restrict__ part, float* __restrict__ co_s, float* __restrict__ co_c)
{
    int b = blockIdx.x;
    int which = blockIdx.y;
    int t = threadIdx.x;
    if (t >= DP) return;
    const float* p = part + (int64_t)(b * 2 + which) * 8 * 264 + t;
    float s = 0.f;
#pragma unroll
    for (int c = 0; c < 8; c++) s += p[c * 264];
    (which ? co_c : co_s)[b * DP + t] = s;
}

__global__ __launch_bounds__(256) void final_kernel(const float* __restrict__ co_s, const float* __restrict__ co_c, float* __restrict__ outp) {
    __shared__ float red[4];
    int b = blockIdx.x, t = threadIdx.x;
    float zmine[2];
    for (int w = 0; w < 2; w++) {
        const float* co = (w ? co_c : co_s) + b * DP;
        float at = co[0];
        float asp = co[1 + t];
        float ssp = blockRedSum(asp * asp, red);
        float li = ssp - at * at;
        float den = sqrtf(fmaxf(fabsf(li), 1e-8f));
        float xt = at / den, xsp = asp / den;
        float s2 = blockRedSum(xsp * xsp, red);
        float nrm = sqrtf(fmaxf(s2, 1e-15f));
        float ac = acoshf(fmaxf(xt, 1.0f + 1e-7f));
        zmine[w] = ac * xsp / nrm;
    }
    float vn2 = blockRedSum(zmine[0] * zmine[0] + zmine[1] * zmine[1], red);
    float vn = sqrtf(fmaxf(vn2, 1e-15f));
    float sc = sinhf(vn) / vn;
    if (t == 0) outp[b * 513] = coshf(vn);
    outp[b * 513 + 1 + t] = sc * zmine[0];
    outp[b * 513 + 1 + 256 + t] = sc * zmine[1];
}

// ---------------- host launcher ----------------
extern "C" void kernel_launch(void* const* d_in, const int* in_sizes, int n_in,
                              void* d_out, int out_size, void* d_ws, size_t ws_size,
                              hipStream_t stream)
{
    const float* sent = (const float*)d_in[0];
    const float* comm = (const float*)d_in[1];
    const float* WlW  = (const float*)d_in[2];
    const float* Wlb  = (const float*)d_in[3];
    const float* WcW  = (const float*)d_in[4];
    const float* Wcb  = (const float*)d_in[5];
    const float* WsW  = (const float*)d_in[6];
    const float* Wsb  = (const float*)d_in[7];
    const float* whs  = (const float*)d_in[8];
    const float* whc  = (const float*)d_in[9];
    float* out = (float*)d_out;
    (void)in_sizes; (void)n_in; (void)out_size; (void)ws_size;

    float* ws = (float*)d_ws;
    size_t off = 0;
    auto take = [&](size_t n) { float* p = ws + off; off += n; return p; };
    float*  xnrow = take(32768);
    float*  lgs   = take(32768);   // contiguous with lgc
    float*  lgc   = take(32768);
    float*  co_s  = take(8224);
    float*  co_c  = take(8224);
    ushort* Ls_bf = (ushort*)take(4718592);   // contiguous with Lc_bf
    ushort* Lc_bf = (ushort*)take(4718592);
    ushort* Wl_bf = (ushort*)take(36864);
    ushort* Ws_bf = (ushort*)take(18432);
    ushort* Wc_bf = (ushort*)take(18432);
    ushort* HsA_bf = (ushort*)take(2097152);  // contiguous with HcA_bf
    ushort* HcA_bf = (ushort*)take(2097152);
    float*  part_cn   = take(1048576);
    float*  part_cent = take(135168);
    float*  F     = take(33554432);

    // Phase overlays in F (float offsets)
    ushort* XC_bf   = (ushort*)F;                 // [P1] 5.24M fl
    ushort* XS_bf   = (ushort*)(F + 5242880);     // [P1] 5.24M fl
    ushort* Ff_bf   = (ushort*)(F + 10485760);    // [P1] 10.49M fl
    ushort* CS1c    = (ushort*)(F + 20971520);    // [P1] 204800 fl
    ushort* CS1s    = (ushort*)(F + 21176320);    // [P1] 204800 fl
    ushort* C2_bf   = (ushort*)(F + 21381120);    // [P1] 32k fl
    ushort* S2_bf   = (ushort*)(F + 21413888);    // [P1] 32k fl
    ushort* YcYs    = (ushort*)F;                 // [P1] aliases XC/XS; 10.49M fl
    ushort* Lmat_bf = (ushort*)F;                 // [P3-P5] 16.78M fl
    ushort* Llin_bf = (ushort*)(F + 25165824);    // [P2-P3] 4.72M fl
    float*  mx      = F + 16777216;               // [P5] 4.19M fl
    ushort* HsAT    = (ushort*)(F + 20971520);    // [P5] 2.1M fl, contiguous with HcAT
    ushort* HcAT    = (ushort*)(F + 23068672);    // [P5] 2.1M fl

    float* AsOut = out + 16416;
    float* AcOut = out + 16416 + 32768;

    dim3 blk(256);
    const short* NUL = nullptr;

    genconst_kernel<<<3968, 256, 0, stream>>>(CS1c, CS1s, C2_bf, S2_bf, WlW, WsW, WcW, Wl_bf, Ws_bf, Wc_bf);

    // ---- input prep + m-fold ----
    prep_fold_kernel<<<dim3(513, 16), blk, 0, stream>>>(sent, comm, XC_bf, XS_bf);
    // stage-1 DUAL: Ff[:, :640] = C2 . XC^T ; Ff[:, 640:] = S2 . XS^T
    mfma_gemm<false,false,true,false,false,1,true><<<dim3(5,2,128), blk, 0, stream>>>(
        (const short*)C2_bf,256,0, (const short*)XC_bf,256,(int64_t)NFOLD*256, Ff_bf,1280,(int64_t)256*1280,
        nullptr, 256,NFOLD,256, (const short*)S2_bf, (const short*)XS_bf, 640, nullptr);
    // stage-2 DUAL (n-folded): Yc = CS1c . Fc^T ; Ys = CS1s . Fs^T
    mfma_gemm<false,false,true,false,false,1,true><<<dim3(2,5,128), blk, 0, stream>>>(
        (const short*)CS1c,KF2,0, (const short*)Ff_bf,1280,(int64_t)256*1280, YcYs,256,327680,
        nullptr, NFOLD,256,KF2, (const short*)CS1s, (const short*)(Ff_bf+640), 163840, nullptr);
    e2l_kernel<<<16384, blk, 0, stream>>>(YcYs, Ls_bf, Lc_bf);

    // ---- L = lorentz_linear(Lc, Wl): space cols bf16 straight into Llin_bf[.,1:] ----
    mfma_gemm<false,false,true,true,false,1,false><<<dim3(2,256,1), blk, 0, stream>>>(
        (const short*)Lc_bf,KPAD,0, (const short*)Wl_bf,KPAD,0, (void*)(Llin_bf+1),KPAD,0,
        Wlb+1, 32768,256,KPAD, NUL, NUL, 0, nullptr);
    lnorm_kernel<<<8192, blk, 0, stream>>>(Llin_bf);

    // ---- Lmat = lorentz_act(einsum(Ls, Llin)) in bf16 ----
    mfma_gemm<false,false,true,false,false,1,false><<<dim3(8,8,32), blk, 0, stream>>>(
        (const short*)Ls_bf,KPAD,294912, (const short*)Llin_bf,KPAD,294912, Lmat_bf,1024,1048576,
        nullptr, 1024,1024,KPAD, NUL, NUL, 0, nullptr);
    lact_kernel<<<32768, blk, 0, stream>>>(Lmat_bf, xnrow);
    colnormA_kernel<<<dim3(32,8), blk, 0, stream>>>(Lmat_bf, part_cn);

    // ---- Hs_a / Hc_a: bf16 + per-z bias straight into HsA_bf|HcA_bf, then in-place poincare ----
    mfma_gemm<false,false,true,true,false,1,false><<<dim3(1,256,2), blk, 0, stream>>>(
        (const short*)Ls_bf,KPAD,9437184, (const short*)Ws_bf,KPAD,36864, HsA_bf,128,4194304,
        Wsb+1, 32768,128,KPAD, NUL, NUL, 0, Wcb+1);
    poinc2_kernel<<<16384, blk, 0, stream>>>(HsA_bf);

    // ---- transpose HsA_bf and HcA_bf in one launch ----
    thsa_kernel<<<dim3(32,4,64), dim3(32,8), 0, stream>>>(HsA_bf, HsAT);

    // ---- Hs path: mx_s = Lmat . Hc_a (split-K=4, atomic) ----
    hipMemsetAsync(mx, 0, 4194304 * sizeof(float), stream);
    mfma_gemm<false,false,false,false,true,4,false><<<dim3(1,8,128), blk, 0, stream>>>(
        (const short*)Lmat_bf,1024,1048576, (const short*)HcAT,1024,131072, mx,128,131072,
        nullptr, 1024,128,1024, NUL, NUL, 0, nullptr);
    rowops_s_kernel<<<32768, 64, 0, stream>>>(HsA_bf, mx, xnrow, whs, lgs);

    // ---- Hc path: mx_cT = Hs_a^T . Lmat (split-K=4) ----
    hipMemsetAsync(mx, 0, 4194304 * sizeof(float), stream);
    mfma_gemm<false,true,false,false,true,4,false><<<dim3(8,1,128), blk, 0, stream>>>(
        (const short*)HsAT,1024,131072, (const short*)Lmat_bf,1024,1048576, mx,1024,131072,
        nullptr, 128,1024,1024, NUL, NUL, 0, nullptr);
    cnscale_kernel<<<dim3(32,4), blk, 0, stream>>>(part_cn, mx);
    rowops_c_kernel<<<4096, blk, 0, stream>>>(HcAT, mx);
    logitsc_kernel<<<dim3(32,4), blk, 0, stream>>>(mx, whc, lgc);

    // ---- softmaxes / centroids / concat ----
    softmax_kernel<<<64, blk, 0, stream>>>(lgs, AsOut);
    centroidA_kernel<<<dim3(32,2,8), 320, 0, stream>>>(Ls_bf, Lc_bf, AsOut, AcOut, part_cent);
    centroidB_kernel<<<dim3(32,2), 320, 0, stream>>>(part_cent, co_s, co_c);
    final_kernel<<<32, blk, 0, stream>>>(co_s, co_c, out);
}

// Round 10
// 565.774 us; speedup vs baseline: 1.4709x; 1.1132x over previous
//
#include <hip/hip_runtime.h>
#include <cstdint>
#include <math.h>

#define NBATCH 32
#define NSQ 1024
#define NCQ 1024
#define DDIM 256
#define DP 257
#define KQ 128
#define KPAD 288   // 257 padded to /32
#define NFOLD 640  // folded m rows per batch (513 padded to /128)
#define KF2 640    // folded stage-2 K (513 used)
#define MXSPLIT 4194304   // float offset between split-K partial buffers

typedef __attribute__((ext_vector_type(8))) short short8;
typedef __attribute__((ext_vector_type(4))) float floatx4;

// ---------------- device helpers ----------------
__device__ __forceinline__ float bf2f(ushort u) { return __uint_as_float(((uint)u) << 16); }
__device__ __forceinline__ ushort f2bf(float f) {
    uint u = __float_as_uint(f);
    return (ushort)((u + 0x7FFFu + ((u >> 16) & 1u)) >> 16);
}
__device__ __forceinline__ void gload16(const void* g, void* l) {
    __builtin_amdgcn_global_load_lds(
        (const __attribute__((address_space(1))) void*)g,
        (__attribute__((address_space(3))) void*)l,
        16, 0, 0);
}
__device__ __forceinline__ float artanh_clip(float x) {
    x = fminf(fmaxf(x, -1.0f + 1e-5f), 1.0f - 1e-5f);
    return 0.5f * (log1pf(x) - log1pf(-x));
}
__device__ __forceinline__ float gelu_f(float x) {
    return 0.5f * x * (1.0f + erff(x * 0.70710678118654752440f));
}
__device__ __forceinline__ float waveRedSum(float v) {
#pragma unroll
    for (int o = 32; o > 0; o >>= 1) v += __shfl_down(v, o, 64);
    return __shfl(v, 0, 64);
}
__device__ __forceinline__ float blockRedSum(float v, float* buf) {
    int lane = threadIdx.x & 63, wid = threadIdx.x >> 6;
#pragma unroll
    for (int o = 32; o > 0; o >>= 1) v += __shfl_down(v, o, 64);
    __syncthreads();
    if (lane == 0) buf[wid] = v;
    __syncthreads();
    int nw = blockDim.x >> 6;
    float s = buf[0];
    for (int i = 1; i < nw; i++) s += buf[i];
    return s;
}
__device__ __forceinline__ float blockRedMax(float v, float* buf) {
    int lane = threadIdx.x & 63, wid = threadIdx.x >> 6;
#pragma unroll
    for (int o = 32; o > 0; o >>= 1) v = fmaxf(v, __shfl_down(v, o, 64));
    __syncthreads();
    if (lane == 0) buf[wid] = v;
    __syncthreads();
    int nw = blockDim.x >> 6;
    float s = buf[0];
    for (int i = 1; i < nw; i++) s = fmaxf(s, buf[i]);
    return s;
}

// ---------------- bf16 MFMA GEMM ----------------
// C[m,n] = sum_k A[m,k]*B'[k,n] (+bias[n]; biasB used when zb!=0)
// NSPLIT>1 && !ATOMIC: partial sums to Cv + ks*cOff1 (separate buffers).
template <bool A_NN, bool B_NN, bool OUT_BF16, bool BIAS, bool ATOMIC, int NSPLIT, bool DUAL>
__global__ __launch_bounds__(256) void mfma_gemm(
    const short* __restrict__ A, int lda, int64_t sA,
    const short* __restrict__ B, int ldb, int64_t sB,
    void* __restrict__ Cv, int ldc, int64_t sC,
    const float* __restrict__ bias, int M, int N, int K,
    const short* __restrict__ A1, const short* __restrict__ B1, int64_t cOff1,
    const float* __restrict__ biasB)
{
    __shared__ short As[128][32];
    __shared__ short Bs[128][32];
    const int zz = blockIdx.z;
    int zb, ks, half;
    if (DUAL) { half = zz & 1; zb = zz >> 1; ks = 0; }
    else      { zb = zz / NSPLIT; ks = zz - zb * NSPLIT; half = 0; }
    const short* Ap = (DUAL && half) ? A1 : A;
    const short* Bp = (DUAL && half) ? B1 : B;
    Ap += (int64_t)zb * sA;
    Bp += (int64_t)zb * sB;
    const int kper = K / NSPLIT;
    const int kbeg = ks * kper, kend = kbeg + kper;
    const int m0 = blockIdx.y * 128, n0 = blockIdx.x * 128;
    const int t = threadIdx.x;
    const int lane = t & 63, w = t >> 6;
    const int wm = (w & 1) * 64, wn = (w >> 1) * 64;
    floatx4 acc[4][4] = {};
    for (int k0 = kbeg; k0 < kend; k0 += 32) {
        if (!A_NN) {
            int r = t >> 2, c8 = (t & 3) * 8;
            const short* ap = Ap + (int64_t)(m0 + r) * lda + k0 + c8;
            gload16(ap, &As[r][c8]);
            gload16(ap + (int64_t)64 * lda, &As[r + 64][c8]);
        } else {
            int r2 = t >> 4, c8 = (t & 15) * 8;
            int kk = 2 * r2;
            const ushort* a0 = (const ushort*)Ap + (int64_t)(k0 + kk) * lda + m0 + c8;
            uint4 v0 = *(const uint4*)a0;
            uint4 v1 = *(const uint4*)(a0 + lda);
            const ushort* p0 = (const ushort*)&v0;
            const ushort* p1 = (const ushort*)&v1;
#pragma unroll
            for (int i = 0; i < 8; i++) {
                uint pk = (uint)p0[i] | ((uint)p1[i] << 16);
                *(uint*)&As[c8 + i][kk] = pk;
            }
        }
        if (!B_NN) {
            int r = t >> 2, c8 = (t & 3) * 8;
            const short* bp = Bp + (int64_t)(n0 + r) * ldb + k0 + c8;
            gload16(bp, &Bs[r][c8]);
            gload16(bp + (int64_t)64 * ldb, &Bs[r + 64][c8]);
        } else {
            int r2 = t >> 4, c8 = (t & 15) * 8;
            int kk = 2 * r2;
            const ushort* b0 = (const ushort*)Bp + (int64_t)(k0 + kk) * ldb + n0 + c8;
            uint4 v0 = *(const uint4*)b0;
            uint4 v1 = *(const uint4*)(b0 + ldb);
            const ushort* p0 = (const ushort*)&v0;
            const ushort* p1 = (const ushort*)&v1;
#pragma unroll
            for (int i = 0; i < 8; i++) {
                uint pk = (uint)p0[i] | ((uint)p1[i] << 16);
                *(uint*)&Bs[c8 + i][kk] = pk;
            }
        }
        __syncthreads();
        short8 af[4], bfv[4];
#pragma unroll
        for (int i = 0; i < 4; i++)
            af[i] = *(const short8*)&As[wm + 16 * i + (lane & 15)][8 * (lane >> 4)];
#pragma unroll
        for (int i = 0; i < 4; i++)
            bfv[i] = *(const short8*)&Bs[wn + 16 * i + (lane & 15)][8 * (lane >> 4)];
#pragma unroll
        for (int i = 0; i < 4; i++)
#pragma unroll
            for (int j = 0; j < 4; j++)
                acc[i][j] = __builtin_amdgcn_mfma_f32_16x16x32_bf16(af[i], bfv[j], acc[i][j], 0, 0, 0);
        __syncthreads();
    }
    const int q = lane >> 4, c = lane & 15;
    int64_t cbase = (int64_t)zb * sC + ((DUAL && half) ? cOff1 : 0);
    if (NSPLIT > 1 && !ATOMIC) cbase += (int64_t)ks * cOff1;
    const float* bsel = (BIAS && biasB && zb) ? biasB : bias;
#pragma unroll
    for (int j = 0; j < 4; j++) {
        int col = n0 + wn + 16 * j + c;
        float bv = BIAS ? bsel[col] : 0.0f;
#pragma unroll
        for (int i = 0; i < 4; i++) {
            int rowb = m0 + wm + 16 * i + 4 * q;
#pragma unroll
            for (int r = 0; r < 4; r++) {
                float v = acc[i][j][r] + bv;
                int64_t idx = cbase + (int64_t)(rowb + r) * ldc + col;
                if (ATOMIC)       atomicAdd((float*)Cv + idx, v);
                else if (OUT_BF16) ((ushort*)Cv)[idx] = f2bf(v);
                else               ((float*)Cv)[idx] = v;
            }
        }
    }
}

// ---------------- fused constants ----------------
__global__ __launch_bounds__(256) void genconst_kernel(
    ushort* CS1c, ushort* CS1s, ushort* C2, ushort* S2,
    const float* __restrict__ WlW, const float* __restrict__ WsW, const float* __restrict__ WcW,
    ushort* Wl, ushort* Ws, ushort* Wc)
{
    int blk = blockIdx.x, t = threadIdx.x;
    if (blk < 3200) {
        int idx = blk * 256 + t;                 // 2 x 640*640
        int hs = idx >= 409600;
        int e = idx - hs * 409600;
        int n = e / KF2, k = e - n * KF2;
        float v = 0.0f;
        if (k <= 512) {
            int p = (n * k) & 1023;
            float ang = (6.28318530717958647692f / 1024.0f) * (float)p;
            v = hs ? ((k == 0) ? 0.0f : -sinf(ang)) : cosf(ang);
        }
        (hs ? CS1s : CS1c)[e] = f2bf(v);
    } else if (blk < 3456) {
        int idx = (blk - 3200) * 256 + t;        // 256x256
        int d = idx >> 8, j = idx & 255;
        int p = (d * j) & 255;
        float ang = (6.28318530717958647692f / 256.0f) * (float)p;
        C2[idx] = f2bf(cosf(ang));
        S2[idx] = f2bf(sinf(ang));
    } else {
        int r = blk - 3456;                      // 512 rows
        const float* src; ushort* dst; int srow;
        if (r < 256)      { src = WlW; dst = Wl + r * KPAD;        srow = r + 1; }
        else if (r < 384) { src = WsW; dst = Ws + (r - 256) * KPAD; srow = r - 256 + 1; }
        else              { src = WcW; dst = Wc + (r - 384) * KPAD; srow = r - 384 + 1; }
        dst[t] = (t < DP) ? f2bf(src[(int64_t)srow * DP + t]) : (ushort)0;
        if (t < KPAD - 256) {
            int t2 = t + 256;
            dst[t2] = (t2 < DP) ? f2bf(src[(int64_t)srow * DP + t2]) : (ushort)0;
        }
    }
}

// input prep + m-fold, wave-per-(bp,z)
__global__ __launch_bounds__(256) void prep_fold_kernel(const float* __restrict__ sent,
                                                        const float* __restrict__ comm,
                                                        ushort* __restrict__ XC, ushort* __restrict__ XS) {
    int bp = blockIdx.x;                       // 0..512
    int z = blockIdx.y * 4 + (threadIdx.x >> 6);
    int lane = threadIdx.x & 63;
    int m2 = (1024 - bp) & 1023;
    const float* base = (z < 32) ? sent + (int64_t)z * 262144 : comm + (int64_t)(z - 32) * 262144;
    float4 a = *(const float4*)(base + bp * 256 + 4 * lane);
    float4 b = *(const float4*)(base + m2 * 256 + 4 * lane);
    if (z >= 32) {
        float s1 = waveRedSum(a.x * a.x + a.y * a.y + a.z * a.z + a.w * a.w);
        float yn1 = sqrtf(fmaxf(s1, 1e-15f));
        float f1 = artanh_clip(yn1) / yn1;
        a.x *= f1; a.y *= f1; a.z *= f1; a.w *= f1;
        float s2 = waveRedSum(b.x * b.x + b.y * b.y + b.z * b.z + b.w * b.w);
        float yn2 = sqrtf(fmaxf(s2, 1e-15f));
        float f2v = artanh_clip(yn2) / yn2;
        b.x *= f2v; b.y *= f2v; b.z *= f2v; b.w *= f2v;
    }
    int64_t o = ((int64_t)z * NFOLD + bp) * 256 + 4 * lane;
    bool single = (bp == 0) || (bp == 512);
    ushort4 oc;
    oc.x = f2bf(single ? a.x : a.x + b.x);
    oc.y = f2bf(single ? a.y : a.y + b.y);
    oc.z = f2bf(single ? a.z : a.z + b.z);
    oc.w = f2bf(single ? a.w : a.w + b.w);
    *(ushort4*)(XC + o) = oc;
    if (!single) {
        ushort4 os;
        os.x = f2bf(a.x - b.x); os.y = f2bf(a.y - b.y);
        os.z = f2bf(a.z - b.z); os.w = f2bf(a.w - b.w);
        *(ushort4*)(XS + o) = os;
    }
}

// euclid_to_lorentz, wave-per-row, n-fold combine, exp-based sinh/cosh
__global__ __launch_bounds__(256) void e2l_kernel(const ushort* __restrict__ YcYs,
                                                  ushort* __restrict__ Lsb, ushort* __restrict__ Lcb) {
    int64_t row = (int64_t)blockIdx.x * 4 + (threadIdx.x >> 6);   // 0..65535
    int lane = threadIdx.x & 63;
    int z = (int)(row >> 10), n = (int)(row & 1023);
    int np = (n <= 512) ? n : 1024 - n;
    float sgn = (n <= 512) ? 1.0f : -1.0f;
    const ushort* base = YcYs + (int64_t)z * 327680 + np * 256 + 4 * lane;
    ushort4 uc = *(const ushort4*)base;
    ushort4 us = *(const ushort4*)(base + 163840);
    float v0 = bf2f(uc.x) + sgn * bf2f(us.x);
    float v1 = bf2f(uc.y) + sgn * bf2f(us.y);
    float v2 = bf2f(uc.z) + sgn * bf2f(us.z);
    float v3 = bf2f(uc.w) + sgn * bf2f(us.w);
    float s = waveRedSum(v0 * v0 + v1 * v1 + v2 * v2 + v3 * v3);
    float xn = sqrtf(fmaxf(s, 1e-15f)) + 1e-5f;
    float sc = fminf(1.0f, 2.0f / xn);
    float s2 = fmaxf(s * sc * sc, 1e-15f);
    float vn = sqrtf(s2);
    float e = expf(vn);
    float ei = 1.0f / e;
    float shv = (vn < 1e-4f) ? 1.0f : (e - ei) * 0.5f / vn;
    float fac = shv * sc;
    ushort* ob = (row < 32768 ? Lsb + row * KPAD : Lcb + (row - 32768) * KPAD);
    ob[1 + 4 * lane + 0] = f2bf(fac * v0);
    ob[1 + 4 * lane + 1] = f2bf(fac * v1);
    ob[1 + 4 * lane + 2] = f2bf(fac * v2);
    ob[1 + 4 * lane + 3] = f2bf(fac * v3);
    if (lane == 0) ob[0] = f2bf((e + ei) * 0.5f);
    if (lane < KPAD - DP) ob[DP + lane] = 0;
}

// lorentz_linear time fill (in place on bf16 rows of 288)
__global__ __launch_bounds__(256) void lnorm_kernel(ushort* __restrict__ Llin_bf) {
    int64_t row = (int64_t)blockIdx.x * 4 + (threadIdx.x >> 6);
    int lane = threadIdx.x & 63;
    ushort* ob = Llin_bf + row * KPAD;
    float s = 0.f;
#pragma unroll
    for (int i = 0; i < 4; i++) { float v = bf2f(ob[1 + 4 * lane + i]); s += v * v; }
    s = waveRedSum(s);
    if (lane == 0) ob[0] = f2bf(sqrtf(s + 1.0f));
    if (lane < KPAD - DP) ob[DP + lane] = 0;
}

// to_poincare in place on bf16 rows of 128
__global__ __launch_bounds__(256) void poinc2_kernel(ushort* __restrict__ Hcat) {
    int64_t row = (int64_t)blockIdx.x * 4 + (threadIdx.x >> 6);
    int lane = threadIdx.x & 63;
    ushort* r = Hcat + row * KQ;
    ushort2 u = *(ushort2*)&r[2 * lane];
    float v0 = bf2f(u.x), v1 = bf2f(u.y);
    float s = waveRedSum(v0 * v0 + v1 * v1);
    float inv = 1.0f / (sqrtf(s + 1.0f) + 1.0f);
    ushort2 o; o.x = f2bf(v0 * inv); o.y = f2bf(v1 * inv);
    *(ushort2*)&r[2 * lane] = o;
}

// lorentz_act on bf16 Lmat rows (1024), in place, + xnrow
__global__ __launch_bounds__(256) void lact_kernel(ushort* __restrict__ Lmat, float* __restrict__ xnrow) {
    __shared__ float red[4];
    int64_t row = blockIdx.x; int t = threadIdx.x;
    ushort* r = Lmat + row * (int64_t)NCQ;
    ushort4 u = *(ushort4*)&r[4 * t];
    float v[4] = {bf2f(u.x), bf2f(u.y), bf2f(u.z), bf2f(u.w)};
    float g[4]; float s = 0.f;
#pragma unroll
    for (int i = 0; i < 4; i++) {
        int idx = 4 * t + i;
        if (idx > 0) { g[i] = gelu_f(v[i]); s += g[i] * g[i]; } else g[i] = 0.f;
    }
    s = blockRedSum(s, red);
    if (t == 0) g[0] = sqrtf(1.0f + s);
    ushort4 o; o.x = f2bf(g[0]); o.y = f2bf(g[1]); o.z = f2bf(g[2]); o.w = f2bf(g[3]);
    *(ushort4*)&r[4 * t] = o;
    if (t == 0) xnrow[row] = sqrtf(fmaxf(1.0f + 2.0f * s, 1e-15f));
}

// per-batch 1024x1024 bf16 transpose (LmatT[m][n] = Lmat[n][m])
__global__ void tmat_kernel(const ushort* __restrict__ in, ushort* __restrict__ outp) {
    __shared__ ushort tile[32][33];
    int z = blockIdx.z;
    int r0 = blockIdx.x * 32, c0 = blockIdx.y * 32;
    const ushort* ib = in + (int64_t)z * 1048576;
    ushort* ob = outp + (int64_t)z * 1048576;
    int tx = threadIdx.x, ty = threadIdx.y;
    for (int i = 0; i < 32; i += 8) tile[ty + i][tx] = ib[(r0 + ty + i) * 1024 + c0 + tx];
    __syncthreads();
    for (int i = 0; i < 32; i += 8) ob[(c0 + ty + i) * 1024 + r0 + tx] = tile[tx][ty + i];
}

// column-norm stage A (partials)
__global__ __launch_bounds__(256) void colnormA_kernel(const ushort* __restrict__ Lmat, float* __restrict__ part) {
    int b = blockIdx.x, chunk = blockIdx.y, t = threadIdx.x;
    const ushort* base = Lmat + (int64_t)b * NSQ * NCQ + (int64_t)chunk * 128 * NCQ + 4 * t;
    float s0 = 0.f, s1 = 0.f, s2 = 0.f, s3 = 0.f;
    for (int n = 0; n < 128; n++) {
        ushort4 u = *(const ushort4*)(base + (int64_t)n * NCQ);
        float a = bf2f(u.x), bb = bf2f(u.y), c = bf2f(u.z), d = bf2f(u.w);
        s0 += a * a; s1 += bb * bb; s2 += c * c; s3 += d * d;
    }
    float4 o = {s0, s1, s2, s3};
    *(float4*)(part + ((int64_t)(b * 8 + chunk)) * 4096 + 4 * t) = o;
}
// fused colnormB + split-sum + mobius column scale on mx_cT (combined result -> buffer A)
__global__ __launch_bounds__(256) void cnscale_kernel(const float* __restrict__ part,
                                                      float* __restrict__ mxcT) {
    int b = blockIdx.x; int m = blockIdx.y * 256 + threadIdx.x;
    const float* p = part + (int64_t)b * 8 * 4096 + m;
    float s = 0.f;
#pragma unroll
    for (int c = 0; c < 8; c++) s += p[c * 4096];
    float xn = sqrtf(fmaxf(s, 1e-15f));
    float* base = mxcT + (int64_t)b * KQ * NCQ + m;
    const float* base2 = base + MXSPLIT;
    float sm = 0.f;
    for (int j = 0; j < KQ; j++) {
        float v = base[j * NCQ] + base2[j * NCQ];
        base[j * NCQ] = v;                  // combined, unscaled
        sm += v * v;
    }
    float mxn = sqrtf(fmaxf(sm, 1e-15f));
    float fac = tanhf(mxn / xn * artanh_clip(xn)) / mxn;
    for (int j = 0; j < KQ; j++) base[j * NCQ] *= fac;
}

// Hs path rowwise chain -> logits (q = sum of 2 split buffers)
__global__ __launch_bounds__(64) void rowops_s_kernel(
    const ushort* __restrict__ Hsa, const float* __restrict__ mxs,
    const float* __restrict__ xnrow, const float* __restrict__ whs,
    float* __restrict__ logits)
{
    int64_t row = blockIdx.x; int t = threadIdx.x;
    const ushort* p = Hsa + row * KQ;
    const float* q = mxs + row * KQ;
    float p0 = bf2f(p[t]), p1 = bf2f(p[t + 64]);
    float q0 = q[t] + q[t + MXSPLIT], q1 = q[t + 64] + q[t + 64 + MXSPLIT];
    float mxn = sqrtf(fmaxf(waveRedSum(q0 * q0 + q1 * q1), 1e-15f));
    float xn = xnrow[row];
    float fac = tanhf(mxn / xn * artanh_clip(xn)) / mxn;
    float y0 = fac * q0, y1 = fac * q1;
    float xy = waveRedSum(p0 * y0 + p1 * y1);
    float x2 = waveRedSum(p0 * p0 + p1 * p1);
    float y2 = waveRedSum(y0 * y0 + y1 * y1);
    float ca = 1.f + 2.f * xy + y2, cb = 1.f - x2;
    float den = fmaxf(1.f + 2.f * xy + x2 * y2, 1e-15f);
    float h0 = (ca * p0 + cb * y0) / den, h1 = (ca * p1 + cb * y1) / den;
    float hn = sqrtf(fmaxf(waveRedSum(h0 * h0 + h1 * h1), 1e-15f));
    float uf = artanh_clip(hn) / hn;
    float g0 = gelu_f(uf * h0), g1 = gelu_f(uf * h1);
    float gn = sqrtf(fmaxf(waveRedSum(g0 * g0 + g1 * g1), 1e-15f));
    float ef = tanhf(gn) / gn;
    float H0 = ef * g0, H1 = ef * g1;
    float dot = waveRedSum(H0 * whs[t] + H1 * whs[t + 64]);
    float Hn = sqrtf(fmaxf(waveRedSum(H0 * H0 + H1 * H1), 1e-15f));
    float mxn2 = sqrtf(fmaxf(dot * dot, 1e-15f));
    float lg = tanhf(mxn2 / Hn * artanh_clip(Hn)) * dot / mxn2;
    if (t == 0) logits[row] = lg;
}

// transpose (z batches of 1024x128) -> (z batches of 128x1024)
__global__ void thsa_kernel(const ushort* __restrict__ in, ushort* __restrict__ outp) {
    __shared__ ushort tile[32][33];
    int z = blockIdx.z;
    int n0 = blockIdx.x * 32, j0 = blockIdx.y * 32;
    const ushort* ib = in + (int64_t)z * 131072;
    ushort* ob = outp + (int64_t)z * 131072;
    int tx = threadIdx.x, ty = threadIdx.y;
    for (int i = 0; i < 32; i += 8) tile[ty + i][tx] = ib[(n0 + ty + i) * 128 + j0 + tx];
    __syncthreads();
    for (int i = 0; i < 32; i += 8) ob[(j0 + ty + i) * 1024 + n0 + tx] = tile[tx][ty + i];
}

// Hc path rowwise chain (per (b,k) over NC), x from bf16 HcAT, y in place
__global__ __launch_bounds__(256) void rowops_c_kernel(const ushort* __restrict__ HcAT, float* __restrict__ y) {
    __shared__ float red[4];
    int64_t row = blockIdx.x;
    const ushort* xbase = HcAT + row * (int64_t)NCQ;
    float* yr = y + row * (int64_t)NCQ;
    int t = threadIdx.x;
    float xv[4], yv[4];
    float xy = 0.f, x2 = 0.f, y2 = 0.f;
#pragma unroll
    for (int i = 0; i < 4; i++) {
        int m = t + 256 * i;
        xv[i] = bf2f(xbase[m]); yv[i] = yr[m];
        xy += xv[i] * yv[i]; x2 += xv[i] * xv[i]; y2 += yv[i] * yv[i];
    }
    xy = blockRedSum(xy, red);
    x2 = blockRedSum(x2, red);
    y2 = blockRedSum(y2, red);
    float ca = 1.f + 2.f * xy + y2, cb = 1.f - x2;
    float den = fmaxf(1.f + 2.f * xy + x2 * y2, 1e-15f);
    float h[4]; float hn2 = 0.f;
#pragma unroll
    for (int i = 0; i < 4; i++) { h[i] = (ca * xv[i] + cb * yv[i]) / den; hn2 += h[i] * h[i]; }
    hn2 = blockRedSum(hn2, red);
    float hn = sqrtf(fmaxf(hn2, 1e-15f));
    float uf = artanh_clip(hn) / hn;
    float g[4]; float gn2 = 0.f;
#pragma unroll
    for (int i = 0; i < 4; i++) { g[i] = gelu_f(uf * h[i]); gn2 += g[i] * g[i]; }
    gn2 = blockRedSum(gn2, red);
    float gn = sqrtf(fmaxf(gn2, 1e-15f));
    float ef = tanhf(gn) / gn;
#pragma unroll
    for (int i = 0; i < 4; i++) yr[t + 256 * i] = ef * g[i];
}

// Ac logits
__global__ __launch_bounds__(256) void logitsc_kernel(const float* __restrict__ Hc, const float* __restrict__ whc, float* __restrict__ lgc) {
    int b = blockIdx.x; int m = blockIdx.y * 256 + threadIdx.x;
    const float* base = Hc + (int64_t)b * KQ * NCQ + m;
    float s1 = 0.f, s2 = 0.f;
    for (int j = 0; j < KQ; j++) { float v = base[j * NCQ]; s1 += v * whc[j]; s2 += v * v; }
    float xn = sqrtf(fmaxf(s2, 1e-15f));
    float mxn = sqrtf(fmaxf(s1 * s1, 1e-15f));
    lgc[b * NCQ + m] = tanhf(mxn / xn * artanh_clip(xn)) * s1 / mxn;
}

// fused softmax for lgs|lgc -> AsOut|AcOut, grid 64
__global__ __launch_bounds__(256) void softmax_kernel(const float* __restrict__ lg, float* __restrict__ outp) {
    __shared__ float red[4];
    int b = blockIdx.x; int t = threadIdx.x;
    const float* x = lg + b * 1024;
    float v[4]; float m = -1e30f;
#pragma unroll
    for (int i = 0; i < 4; i++) { v[i] = x[t + 256 * i]; m = fmaxf(m, v[i]); }
    m = blockRedMax(m, red);
    float s = 0.f;
#pragma unroll
    for (int i = 0; i < 4; i++) { v[i] = expf(v[i] - m); s += v[i]; }
    s = blockRedSum(s, red);
    float inv = 1.0f / s;
#pragma unroll
    for (int i = 0; i < 4; i++) outp[b * 1024 + t + 256 * i] = v[i] * inv;
}

// centroid stage A on bf16 L (stride 288, time at col 0)
__global__ __launch_bounds__(320) void centroidA_kernel(
    const ushort* __restrict__ Lsb, const ushort* __restrict__ Lcb,
    const float* __restrict__ As, const float* __restrict__ Ac,
    float* __restrict__ part)
{
    int b = blockIdx.x;
    int which = blockIdx.y;
    int chunk = blockIdx.z;
    const ushort* L = which ? Lcb : Lsb;
    const float* w = which ? Ac : As;
    int t = threadIdx.x;
    if (t >= DP) return;
    const ushort* Lb = L + (int64_t)b * NSQ * KPAD + (int64_t)chunk * 128 * KPAD + t;
    const float* wb = w + b * NSQ + chunk * 128;
    float s = 0.f;
    for (int n = 0; n < 128; n++) s += wb[n] * bf2f(Lb[(int64_t)n * KPAD]);
    part[((int64_t)((b * 2 + which) * 8 + chunk)) * 264 + t] = s;
}
__global__ __launch_bounds__(320) void centroidB_kernel(
    const float* __restrict__ part, float* __restrict__ co_s, float* __restrict__ co_c)
{
    int b = blockIdx.x;
    int which = blockIdx.y;
    int t = threadIdx.x;
    if (t >= DP) return;
    const float* p = part + (int64_t)(b * 2 + which) * 8 * 264 + t;
    float s = 0.f;
#pragma unroll
    for (int c = 0; c < 8; c++) s += p[c * 264];
    (which ? co_c : co_s)[b * DP + t] = s;
}

__global__ __launch_bounds__(256) void final_kernel(const float* __restrict__ co_s, const float* __restrict__ co_c, float* __restrict__ outp) {
    __shared__ float red[4];
    int b = blockIdx.x, t = threadIdx.x;
    float zmine[2];
    for (int w = 0; w < 2; w++) {
        const float* co = (w ? co_c : co_s) + b * DP;
        float at = co[0];
        float asp = co[1 + t];
        float ssp = blockRedSum(asp * asp, red);
        float li = ssp - at * at;
        float den = sqrtf(fmaxf(fabsf(li), 1e-8f));
        float xt = at / den, xsp = asp / den;
        float s2 = blockRedSum(xsp * xsp, red);
        float nrm = sqrtf(fmaxf(s2, 1e-15f));
        float ac = acoshf(fmaxf(xt, 1.0f + 1e-7f));
        zmine[w] = ac * xsp / nrm;
    }
    float vn2 = blockRedSum(zmine[0] * zmine[0] + zmine[1] * zmine[1], red);
    float vn = sqrtf(fmaxf(vn2, 1e-15f));
    float sc = sinhf(vn) / vn;
    if (t == 0) outp[b * 513] = coshf(vn);
    outp[b * 513 + 1 + t] = sc * zmine[0];
    outp[b * 513 + 1 + 256 + t] = sc * zmine[1];
}

// ---------------- host launcher ----------------
extern "C" void kernel_launch(void* const* d_in, const int* in_sizes, int n_in,
                              void* d_out, int out_size, void* d_ws, size_t ws_size,
                              hipStream_t stream)
{
    const float* sent = (const float*)d_in[0];
    const float* comm = (const float*)d_in[1];
    const float* WlW  = (const float*)d_in[2];
    const float* Wlb  = (const float*)d_in[3];
    const float* WcW  = (const float*)d_in[4];
    const float* Wcb  = (const float*)d_in[5];
    const float* WsW  = (const float*)d_in[6];
    const float* Wsb  = (const float*)d_in[7];
    const float* whs  = (const float*)d_in[8];
    const float* whc  = (const float*)d_in[9];
    float* out = (float*)d_out;
    (void)in_sizes; (void)n_in; (void)out_size; (void)ws_size;

    float* ws = (float*)d_ws;
    size_t off = 0;
    auto take = [&](size_t n) { float* p = ws + off; off += n; return p; };
    float*  xnrow = take(32768);
    float*  lgs   = take(32768);   // contiguous with lgc
    float*  lgc   = take(32768);
    float*  co_s  = take(8224);
    float*  co_c  = take(8224);
    ushort* Ls_bf = (ushort*)take(4718592);   // contiguous with Lc_bf
    ushort* Lc_bf = (ushort*)take(4718592);
    ushort* Wl_bf = (ushort*)take(36864);
    ushort* Ws_bf = (ushort*)take(18432);
    ushort* Wc_bf = (ushort*)take(18432);
    ushort* HsA_bf = (ushort*)take(2097152);  // contiguous with HcA_bf
    ushort* HcA_bf = (ushort*)take(2097152);
    float*  part_cn   = take(1048576);
    float*  part_cent = take(135168);
    ushort* LmatT_bf  = (ushort*)take(16777216);  // 32x1024x1024 bf16
    float*  F     = take(33554432);               // total ~249 MiB

    // Phase overlays in F (float offsets)
    ushort* XC_bf   = (ushort*)F;                 // [P1] 5.24M fl
    ushort* XS_bf   = (ushort*)(F + 5242880);     // [P1] 5.24M fl
    ushort* Ff_bf   = (ushort*)(F + 10485760);    // [P1] 10.49M fl
    ushort* CS1c    = (ushort*)(F + 20971520);    // [P1] 204800 fl
    ushort* CS1s    = (ushort*)(F + 21176320);    // [P1] 204800 fl
    ushort* C2_bf   = (ushort*)(F + 21381120);    // [P1] 32k fl
    ushort* S2_bf   = (ushort*)(F + 21413888);    // [P1] 32k fl
    ushort* YcYs    = (ushort*)F;                 // [P1] aliases XC/XS; 10.49M fl
    ushort* Lmat_bf = (ushort*)F;                 // [P3-P5] 16.78M fl
    ushort* Llin_bf = (ushort*)(F + 29360128);    // [P2-P3] 4.72M fl (dead before HsAT/HcAT? no - see below)
    float*  mx      = F + 16777216;               // [P5] 2 x 4.19M fl split buffers
    ushort* HsAT    = (ushort*)(F + 25165824);    // [P5] 2.1M fl
    ushort* HcAT    = (ushort*)(F + 27262976);    // [P5] 2.1M fl

    float* AsOut = out + 16416;
    float* AcOut = out + 16416 + 32768;

    dim3 blk(256);
    const short* NUL = nullptr;

    genconst_kernel<<<3968, 256, 0, stream>>>(CS1c, CS1s, C2_bf, S2_bf, WlW, WsW, WcW, Wl_bf, Ws_bf, Wc_bf);

    // ---- input prep + m-fold ----
    prep_fold_kernel<<<dim3(513, 16), blk, 0, stream>>>(sent, comm, XC_bf, XS_bf);
    // stage-1 DUAL: Ff[:, :640] = C2 . XC^T ; Ff[:, 640:] = S2 . XS^T
    mfma_gemm<false,false,true,false,false,1,true><<<dim3(5,2,128), blk, 0, stream>>>(
        (const short*)C2_bf,256,0, (const short*)XC_bf,256,(int64_t)NFOLD*256, Ff_bf,1280,(int64_t)256*1280,
        nullptr, 256,NFOLD,256, (const short*)S2_bf, (const short*)XS_bf, 640, nullptr);
    // stage-2 DUAL (n-folded): Yc = CS1c . Fc^T ; Ys = CS1s . Fs^T
    mfma_gemm<false,false,true,false,false,1,true><<<dim3(2,5,128), blk, 0, stream>>>(
        (const short*)CS1c,KF2,0, (const short*)Ff_bf,1280,(int64_t)256*1280, YcYs,256,327680,
        nullptr, NFOLD,256,KF2, (const short*)CS1s, (const short*)(Ff_bf+640), 163840, nullptr);
    e2l_kernel<<<16384, blk, 0, stream>>>(YcYs, Ls_bf, Lc_bf);

    // ---- L = lorentz_linear(Lc, Wl): space cols bf16 straight into Llin_bf[.,1:] ----
    mfma_gemm<false,false,true,true,false,1,false><<<dim3(2,256,1), blk, 0, stream>>>(
        (const short*)Lc_bf,KPAD,0, (const short*)Wl_bf,KPAD,0, (void*)(Llin_bf+1),KPAD,0,
        Wlb+1, 32768,256,KPAD, NUL, NUL, 0, nullptr);
    lnorm_kernel<<<8192, blk, 0, stream>>>(Llin_bf);

    // ---- Lmat = lorentz_act(einsum(Ls, Llin)) in bf16 ----
    mfma_gemm<false,false,true,false,false,1,false><<<dim3(8,8,32), blk, 0, stream>>>(
        (const short*)Ls_bf,KPAD,294912, (const short*)Llin_bf,KPAD,294912, Lmat_bf,1024,1048576,
        nullptr, 1024,1024,KPAD, NUL, NUL, 0, nullptr);
    lact_kernel<<<32768, blk, 0, stream>>>(Lmat_bf, xnrow);
    tmat_kernel<<<dim3(32,32,32), dim3(32,8), 0, stream>>>(Lmat_bf, LmatT_bf);
    colnormA_kernel<<<dim3(32,8), blk, 0, stream>>>(Lmat_bf, part_cn);

    // ---- Hs_a / Hc_a: bf16 + per-z bias straight into HsA_bf|HcA_bf, in-place poincare ----
    mfma_gemm<false,false,true,true,false,1,false><<<dim3(1,256,2), blk, 0, stream>>>(
        (const short*)Ls_bf,KPAD,9437184, (const short*)Ws_bf,KPAD,36864, HsA_bf,128,4194304,
        Wsb+1, 32768,128,KPAD, NUL, NUL, 0, Wcb+1);
    poinc2_kernel<<<16384, blk, 0, stream>>>(HsA_bf);

    // ---- transpose HsA_bf and HcA_bf in one launch ----
    thsa_kernel<<<dim3(32,4,64), dim3(32,8), 0, stream>>>(HsA_bf, HsAT);

    // ---- Hs path: mx_s = Lmat . Hc_a (split-K=2, dual partial buffers) ----
    mfma_gemm<false,false,false,false,false,2,false><<<dim3(1,8,64), blk, 0, stream>>>(
        (const short*)Lmat_bf,1024,1048576, (const short*)HcAT,1024,131072, mx,128,131072,
        nullptr, 1024,128,1024, NUL, NUL, MXSPLIT, nullptr);
    rowops_s_kernel<<<32768, 64, 0, stream>>>(HsA_bf, mx, xnrow, whs, lgs);

    // ---- Hc path: mx_cT = Hs_a^T . Lmat (all-fast via HsAT + LmatT; split-K=2) ----
    mfma_gemm<false,false,false,false,false,2,false><<<dim3(8,1,64), blk, 0, stream>>>(
        (const short*)HsAT,1024,131072, (const short*)LmatT_bf,1024,1048576, mx,1024,131072,
        nullptr, 128,1024,1024, NUL, NUL, MXSPLIT, nullptr);
    cnscale_kernel<<<dim3(32,4), blk, 0, stream>>>(part_cn, mx);
    rowops_c_kernel<<<4096, blk, 0, stream>>>(HcAT, mx);
    logitsc_kernel<<<dim3(32,4), blk, 0, stream>>>(mx, whc, lgc);

    // ---- softmaxes / centroids / concat ----
    softmax_kernel<<<64, blk, 0, stream>>>(lgs, AsOut);
    centroidA_kernel<<<dim3(32,2,8), 320, 0, stream>>>(Ls_bf, Lc_bf, AsOut, AcOut, part_cent);
    centroidB_kernel<<<dim3(32,2), 320, 0, stream>>>(part_cent, co_s, co_c);
    final_kernel<<<32, blk, 0, stream>>>(co_s, co_c, out);
}

// Round 11
// 549.951 us; speedup vs baseline: 1.5132x; 1.0288x over previous
//
#include <hip/hip_runtime.h>
#include <cstdint>
#include <math.h>

#define NBATCH 32
#define NSQ 1024
#define NCQ 1024
#define DDIM 256
#define DP 257
#define KQ 128
#define KPAD 288   // 257 padded to /32
#define NFOLD 640  // folded m rows per batch (513 padded to /128)
#define KF2 640    // folded stage-2 K (513 used)
#define MXSPLIT 4194304   // float offset between split-K partial buffers

typedef __attribute__((ext_vector_type(8))) short short8;
typedef __attribute__((ext_vector_type(4))) float floatx4;

// ---------------- device helpers ----------------
__device__ __forceinline__ float bf2f(ushort u) { return __uint_as_float(((uint)u) << 16); }
__device__ __forceinline__ ushort f2bf(float f) {
    uint u = __float_as_uint(f);
    return (ushort)((u + 0x7FFFu + ((u >> 16) & 1u)) >> 16);
}
__device__ __forceinline__ void gload16(const void* g, void* l) {
    __builtin_amdgcn_global_load_lds(
        (const __attribute__((address_space(1))) void*)g,
        (__attribute__((address_space(3))) void*)l,
        16, 0, 0);
}
__device__ __forceinline__ float artanh_clip(float x) {
    x = fminf(fmaxf(x, -1.0f + 1e-5f), 1.0f - 1e-5f);
    return 0.5f * (log1pf(x) - log1pf(-x));
}
__device__ __forceinline__ float gelu_f(float x) {
    return 0.5f * x * (1.0f + erff(x * 0.70710678118654752440f));
}
__device__ __forceinline__ float waveRedSum(float v) {
#pragma unroll
    for (int o = 32; o > 0; o >>= 1) v += __shfl_down(v, o, 64);
    return __shfl(v, 0, 64);
}
// three/two interleaved wave reductions (one 6-step dependent chain)
__device__ __forceinline__ void waveRedSum3(float& a, float& b, float& c) {
#pragma unroll
    for (int o = 32; o > 0; o >>= 1) {
        a += __shfl_down(a, o, 64);
        b += __shfl_down(b, o, 64);
        c += __shfl_down(c, o, 64);
    }
    a = __shfl(a, 0, 64); b = __shfl(b, 0, 64); c = __shfl(c, 0, 64);
}
__device__ __forceinline__ void waveRedSum2(float& a, float& b) {
#pragma unroll
    for (int o = 32; o > 0; o >>= 1) {
        a += __shfl_down(a, o, 64);
        b += __shfl_down(b, o, 64);
    }
    a = __shfl(a, 0, 64); b = __shfl(b, 0, 64);
}
__device__ __forceinline__ float blockRedSum(float v, float* buf) {
    int lane = threadIdx.x & 63, wid = threadIdx.x >> 6;
#pragma unroll
    for (int o = 32; o > 0; o >>= 1) v += __shfl_down(v, o, 64);
    __syncthreads();
    if (lane == 0) buf[wid] = v;
    __syncthreads();
    int nw = blockDim.x >> 6;
    float s = buf[0];
    for (int i = 1; i < nw; i++) s += buf[i];
    return s;
}
__device__ __forceinline__ float blockRedMax(float v, float* buf) {
    int lane = threadIdx.x & 63, wid = threadIdx.x >> 6;
#pragma unroll
    for (int o = 32; o > 0; o >>= 1) v = fmaxf(v, __shfl_down(v, o, 64));
    __syncthreads();
    if (lane == 0) buf[wid] = v;
    __syncthreads();
    int nw = blockDim.x >> 6;
    float s = buf[0];
    for (int i = 1; i < nw; i++) s = fmaxf(s, buf[i]);
    return s;
}

// ---------------- bf16 MFMA GEMM ----------------
// C[m,n] = sum_k A[m,k]*B'[k,n] (+bias[n]; biasB used when zb!=0)
// NSPLIT>1 && !ATOMIC: partial sums to Cv + ks*cOff1 (separate buffers).
template <bool A_NN, bool B_NN, bool OUT_BF16, bool BIAS, bool ATOMIC, int NSPLIT, bool DUAL>
__global__ __launch_bounds__(256) void mfma_gemm(
    const short* __restrict__ A, int lda, int64_t sA,
    const short* __restrict__ B, int ldb, int64_t sB,
    void* __restrict__ Cv, int ldc, int64_t sC,
    const float* __restrict__ bias, int M, int N, int K,
    const short* __restrict__ A1, const short* __restrict__ B1, int64_t cOff1,
    const float* __restrict__ biasB)
{
    __shared__ short As[128][32];
    __shared__ short Bs[128][32];
    const int zz = blockIdx.z;
    int zb, ks, half;
    if (DUAL) { half = zz & 1; zb = zz >> 1; ks = 0; }
    else      { zb = zz / NSPLIT; ks = zz - zb * NSPLIT; half = 0; }
    const short* Ap = (DUAL && half) ? A1 : A;
    const short* Bp = (DUAL && half) ? B1 : B;
    Ap += (int64_t)zb * sA;
    Bp += (int64_t)zb * sB;
    const int kper = K / NSPLIT;
    const int kbeg = ks * kper, kend = kbeg + kper;
    const int m0 = blockIdx.y * 128, n0 = blockIdx.x * 128;
    const int t = threadIdx.x;
    const int lane = t & 63, w = t >> 6;
    const int wm = (w & 1) * 64, wn = (w >> 1) * 64;
    floatx4 acc[4][4] = {};
    for (int k0 = kbeg; k0 < kend; k0 += 32) {
        if (!A_NN) {
            int r = t >> 2, c8 = (t & 3) * 8;
            const short* ap = Ap + (int64_t)(m0 + r) * lda + k0 + c8;
            gload16(ap, &As[r][c8]);
            gload16(ap + (int64_t)64 * lda, &As[r + 64][c8]);
        } else {
            int r2 = t >> 4, c8 = (t & 15) * 8;
            int kk = 2 * r2;
            const ushort* a0 = (const ushort*)Ap + (int64_t)(k0 + kk) * lda + m0 + c8;
            uint4 v0 = *(const uint4*)a0;
            uint4 v1 = *(const uint4*)(a0 + lda);
            const ushort* p0 = (const ushort*)&v0;
            const ushort* p1 = (const ushort*)&v1;
#pragma unroll
            for (int i = 0; i < 8; i++) {
                uint pk = (uint)p0[i] | ((uint)p1[i] << 16);
                *(uint*)&As[c8 + i][kk] = pk;
            }
        }
        if (!B_NN) {
            int r = t >> 2, c8 = (t & 3) * 8;
            const short* bp = Bp + (int64_t)(n0 + r) * ldb + k0 + c8;
            gload16(bp, &Bs[r][c8]);
            gload16(bp + (int64_t)64 * ldb, &Bs[r + 64][c8]);
        } else {
            int r2 = t >> 4, c8 = (t & 15) * 8;
            int kk = 2 * r2;
            const ushort* b0 = (const ushort*)Bp + (int64_t)(k0 + kk) * ldb + n0 + c8;
            uint4 v0 = *(const uint4*)b0;
            uint4 v1 = *(const uint4*)(b0 + ldb);
            const ushort* p0 = (const ushort*)&v0;
            const ushort* p1 = (const ushort*)&v1;
#pragma unroll
            for (int i = 0; i < 8; i++) {
                uint pk = (uint)p0[i] | ((uint)p1[i] << 16);
                *(uint*)&Bs[c8 + i][kk] = pk;
            }
        }
        __syncthreads();
        short8 af[4], bfv[4];
#pragma unroll
        for (int i = 0; i < 4; i++)
            af[i] = *(const short8*)&As[wm + 16 * i + (lane & 15)][8 * (lane >> 4)];
#pragma unroll
        for (int i = 0; i < 4; i++)
            bfv[i] = *(const short8*)&Bs[wn + 16 * i + (lane & 15)][8 * (lane >> 4)];
#pragma unroll
        for (int i = 0; i < 4; i++)
#pragma unroll
            for (int j = 0; j < 4; j++)
                acc[i][j] = __builtin_amdgcn_mfma_f32_16x16x32_bf16(af[i], bfv[j], acc[i][j], 0, 0, 0);
        __syncthreads();
    }
    const int q = lane >> 4, c = lane & 15;
    int64_t cbase = (int64_t)zb * sC + ((DUAL && half) ? cOff1 : 0);
    if (NSPLIT > 1 && !ATOMIC) cbase += (int64_t)ks * cOff1;
    const float* bsel = (BIAS && biasB && zb) ? biasB : bias;
#pragma unroll
    for (int j = 0; j < 4; j++) {
        int col = n0 + wn + 16 * j + c;
        float bv = BIAS ? bsel[col] : 0.0f;
#pragma unroll
        for (int i = 0; i < 4; i++) {
            int rowb = m0 + wm + 16 * i + 4 * q;
#pragma unroll
            for (int r = 0; r < 4; r++) {
                float v = acc[i][j][r] + bv;
                int64_t idx = cbase + (int64_t)(rowb + r) * ldc + col;
                if (ATOMIC)       atomicAdd((float*)Cv + idx, v);
                else if (OUT_BF16) ((ushort*)Cv)[idx] = f2bf(v);
                else               ((float*)Cv)[idx] = v;
            }
        }
    }
}

// ---------------- fused constants ----------------
__global__ __launch_bounds__(256) void genconst_kernel(
    ushort* CS1c, ushort* CS1s, ushort* C2, ushort* S2,
    const float* __restrict__ WlW, const float* __restrict__ WsW, const float* __restrict__ WcW,
    ushort* Wl, ushort* Ws, ushort* Wc)
{
    int blk = blockIdx.x, t = threadIdx.x;
    if (blk < 3200) {
        int idx = blk * 256 + t;                 // 2 x 640*640
        int hs = idx >= 409600;
        int e = idx - hs * 409600;
        int n = e / KF2, k = e - n * KF2;
        float v = 0.0f;
        if (k <= 512) {
            int p = (n * k) & 1023;
            float ang = (6.28318530717958647692f / 1024.0f) * (float)p;
            v = hs ? ((k == 0) ? 0.0f : -sinf(ang)) : cosf(ang);
        }
        (hs ? CS1s : CS1c)[e] = f2bf(v);
    } else if (blk < 3456) {
        int idx = (blk - 3200) * 256 + t;        // 256x256
        int d = idx >> 8, j = idx & 255;
        int p = (d * j) & 255;
        float ang = (6.28318530717958647692f / 256.0f) * (float)p;
        C2[idx] = f2bf(cosf(ang));
        S2[idx] = f2bf(sinf(ang));
    } else {
        int r = blk - 3456;                      // 512 rows
        const float* src; ushort* dst; int srow;
        if (r < 256)      { src = WlW; dst = Wl + r * KPAD;        srow = r + 1; }
        else if (r < 384) { src = WsW; dst = Ws + (r - 256) * KPAD; srow = r - 256 + 1; }
        else              { src = WcW; dst = Wc + (r - 384) * KPAD; srow = r - 384 + 1; }
        dst[t] = (t < DP) ? f2bf(src[(int64_t)srow * DP + t]) : (ushort)0;
        if (t < KPAD - 256) {
            int t2 = t + 256;
            dst[t2] = (t2 < DP) ? f2bf(src[(int64_t)srow * DP + t2]) : (ushort)0;
        }
    }
}

// input prep + m-fold, wave-per-(bp,z)
__global__ __launch_bounds__(256) void prep_fold_kernel(const float* __restrict__ sent,
                                                        const float* __restrict__ comm,
                                                        ushort* __restrict__ XC, ushort* __restrict__ XS) {
    int bp = blockIdx.x;                       // 0..512
    int z = blockIdx.y * 4 + (threadIdx.x >> 6);
    int lane = threadIdx.x & 63;
    int m2 = (1024 - bp) & 1023;
    const float* base = (z < 32) ? sent + (int64_t)z * 262144 : comm + (int64_t)(z - 32) * 262144;
    float4 a = *(const float4*)(base + bp * 256 + 4 * lane);
    float4 b = *(const float4*)(base + m2 * 256 + 4 * lane);
    if (z >= 32) {
        float s1 = a.x * a.x + a.y * a.y + a.z * a.z + a.w * a.w;
        float s2 = b.x * b.x + b.y * b.y + b.z * b.z + b.w * b.w;
        waveRedSum2(s1, s2);
        float yn1 = sqrtf(fmaxf(s1, 1e-15f));
        float f1 = artanh_clip(yn1) / yn1;
        a.x *= f1; a.y *= f1; a.z *= f1; a.w *= f1;
        float yn2 = sqrtf(fmaxf(s2, 1e-15f));
        float f2v = artanh_clip(yn2) / yn2;
        b.x *= f2v; b.y *= f2v; b.z *= f2v; b.w *= f2v;
    }
    int64_t o = ((int64_t)z * NFOLD + bp) * 256 + 4 * lane;
    bool single = (bp == 0) || (bp == 512);
    ushort4 oc;
    oc.x = f2bf(single ? a.x : a.x + b.x);
    oc.y = f2bf(single ? a.y : a.y + b.y);
    oc.z = f2bf(single ? a.z : a.z + b.z);
    oc.w = f2bf(single ? a.w : a.w + b.w);
    *(ushort4*)(XC + o) = oc;
    if (!single) {
        ushort4 os;
        os.x = f2bf(a.x - b.x); os.y = f2bf(a.y - b.y);
        os.z = f2bf(a.z - b.z); os.w = f2bf(a.w - b.w);
        *(ushort4*)(XS + o) = os;
    }
}

// euclid_to_lorentz, wave-per-row, n-fold combine, exp-based sinh/cosh
__global__ __launch_bounds__(256) void e2l_kernel(const ushort* __restrict__ YcYs,
                                                  ushort* __restrict__ Lsb, ushort* __restrict__ Lcb) {
    int64_t row = (int64_t)blockIdx.x * 4 + (threadIdx.x >> 6);   // 0..65535
    int lane = threadIdx.x & 63;
    int z = (int)(row >> 10), n = (int)(row & 1023);
    int np = (n <= 512) ? n : 1024 - n;
    float sgn = (n <= 512) ? 1.0f : -1.0f;
    const ushort* base = YcYs + (int64_t)z * 327680 + np * 256 + 4 * lane;
    ushort4 uc = *(const ushort4*)base;
    ushort4 us = *(const ushort4*)(base + 163840);
    float v0 = bf2f(uc.x) + sgn * bf2f(us.x);
    float v1 = bf2f(uc.y) + sgn * bf2f(us.y);
    float v2 = bf2f(uc.z) + sgn * bf2f(us.z);
    float v3 = bf2f(uc.w) + sgn * bf2f(us.w);
    float s = waveRedSum(v0 * v0 + v1 * v1 + v2 * v2 + v3 * v3);
    float xn = sqrtf(fmaxf(s, 1e-15f)) + 1e-5f;
    float sc = fminf(1.0f, 2.0f / xn);
    float s2 = fmaxf(s * sc * sc, 1e-15f);
    float vn = sqrtf(s2);
    float e = expf(vn);
    float ei = 1.0f / e;
    float shv = (vn < 1e-4f) ? 1.0f : (e - ei) * 0.5f / vn;
    float fac = shv * sc;
    ushort* ob = (row < 32768 ? Lsb + row * KPAD : Lcb + (row - 32768) * KPAD);
    ob[1 + 4 * lane + 0] = f2bf(fac * v0);
    ob[1 + 4 * lane + 1] = f2bf(fac * v1);
    ob[1 + 4 * lane + 2] = f2bf(fac * v2);
    ob[1 + 4 * lane + 3] = f2bf(fac * v3);
    if (lane == 0) ob[0] = f2bf((e + ei) * 0.5f);
    if (lane < KPAD - DP) ob[DP + lane] = 0;
}

// lorentz_linear time fill (in place on bf16 rows of 288)
__global__ __launch_bounds__(256) void lnorm_kernel(ushort* __restrict__ Llin_bf) {
    int64_t row = (int64_t)blockIdx.x * 4 + (threadIdx.x >> 6);
    int lane = threadIdx.x & 63;
    ushort* ob = Llin_bf + row * KPAD;
    float s = 0.f;
#pragma unroll
    for (int i = 0; i < 4; i++) { float v = bf2f(ob[1 + 4 * lane + i]); s += v * v; }
    s = waveRedSum(s);
    if (lane == 0) ob[0] = f2bf(sqrtf(s + 1.0f));
    if (lane < KPAD - DP) ob[DP + lane] = 0;
}

// to_poincare in place on bf16 rows of 128
__global__ __launch_bounds__(256) void poinc2_kernel(ushort* __restrict__ Hcat) {
    int64_t row = (int64_t)blockIdx.x * 4 + (threadIdx.x >> 6);
    int lane = threadIdx.x & 63;
    ushort* r = Hcat + row * KQ;
    ushort2 u = *(ushort2*)&r[2 * lane];
    float v0 = bf2f(u.x), v1 = bf2f(u.y);
    float s = waveRedSum(v0 * v0 + v1 * v1);
    float inv = 1.0f / (sqrtf(s + 1.0f) + 1.0f);
    ushort2 o; o.x = f2bf(v0 * inv); o.y = f2bf(v1 * inv);
    *(ushort2*)&r[2 * lane] = o;
}

// lorentz_act on bf16 Lmat rows (1024), in place, + xnrow
__global__ __launch_bounds__(256) void lact_kernel(ushort* __restrict__ Lmat, float* __restrict__ xnrow) {
    __shared__ float red[4];
    int64_t row = blockIdx.x; int t = threadIdx.x;
    ushort* r = Lmat + row * (int64_t)NCQ;
    ushort4 u = *(ushort4*)&r[4 * t];
    float v[4] = {bf2f(u.x), bf2f(u.y), bf2f(u.z), bf2f(u.w)};
    float g[4]; float s = 0.f;
#pragma unroll
    for (int i = 0; i < 4; i++) {
        int idx = 4 * t + i;
        if (idx > 0) { g[i] = gelu_f(v[i]); s += g[i] * g[i]; } else g[i] = 0.f;
    }
    s = blockRedSum(s, red);
    if (t == 0) g[0] = sqrtf(1.0f + s);
    ushort4 o; o.x = f2bf(g[0]); o.y = f2bf(g[1]); o.z = f2bf(g[2]); o.w = f2bf(g[3]);
    *(ushort4*)&r[4 * t] = o;
    if (t == 0) xnrow[row] = sqrtf(fmaxf(1.0f + 2.0f * s, 1e-15f));
}

// per-batch 1024x1024 bf16 transpose
__global__ void tmat_kernel(const ushort* __restrict__ in, ushort* __restrict__ outp) {
    __shared__ ushort tile[32][33];
    int z = blockIdx.z;
    int r0 = blockIdx.x * 32, c0 = blockIdx.y * 32;
    const ushort* ib = in + (int64_t)z * 1048576;
    ushort* ob = outp + (int64_t)z * 1048576;
    int tx = threadIdx.x, ty = threadIdx.y;
    for (int i = 0; i < 32; i += 8) tile[ty + i][tx] = ib[(r0 + ty + i) * 1024 + c0 + tx];
    __syncthreads();
    for (int i = 0; i < 32; i += 8) ob[(c0 + ty + i) * 1024 + r0 + tx] = tile[tx][ty + i];
}

// column-norm stage A (partials)
__global__ __launch_bounds__(256) void colnormA_kernel(const ushort* __restrict__ Lmat, float* __restrict__ part) {
    int b = blockIdx.x, chunk = blockIdx.y, t = threadIdx.x;
    const ushort* base = Lmat + (int64_t)b * NSQ * NCQ + (int64_t)chunk * 128 * NCQ + 4 * t;
    float s0 = 0.f, s1 = 0.f, s2 = 0.f, s3 = 0.f;
    for (int n = 0; n < 128; n++) {
        ushort4 u = *(const ushort4*)(base + (int64_t)n * NCQ);
        float a = bf2f(u.x), bb = bf2f(u.y), c = bf2f(u.z), d = bf2f(u.w);
        s0 += a * a; s1 += bb * bb; s2 += c * c; s3 += d * d;
    }
    float4 o = {s0, s1, s2, s3};
    *(float4*)(part + ((int64_t)(b * 8 + chunk)) * 4096 + 4 * t) = o;
}
// colnormB + column factor for mobius scale: fac_c[b,m] (no mx modification)
__global__ __launch_bounds__(256) void colfac_kernel(const float* __restrict__ part,
                                                     const float* __restrict__ mxcT,
                                                     float* __restrict__ fac_c) {
    int b = blockIdx.x; int m = blockIdx.y * 256 + threadIdx.x;
    const float* p = part + (int64_t)b * 8 * 4096 + m;
    float s = 0.f;
#pragma unroll
    for (int c = 0; c < 8; c++) s += p[c * 4096];
    float xn = sqrtf(fmaxf(s, 1e-15f));
    const float* base = mxcT + (int64_t)b * KQ * NCQ + m;
    const float* base2 = base + MXSPLIT;
    float sm = 0.f;
    for (int j = 0; j < KQ; j++) {
        float v = base[j * NCQ] + base2[j * NCQ];
        sm += v * v;
    }
    float mxn = sqrtf(fmaxf(sm, 1e-15f));
    fac_c[b * NCQ + m] = tanhf(mxn / xn * artanh_clip(xn)) / mxn;
}

// Hs path rowwise chain -> logits; 2 reduction rounds, 4 rows/block
__global__ __launch_bounds__(256) void rowops_s_kernel(
    const ushort* __restrict__ Hsa, const float* __restrict__ mxs,
    const float* __restrict__ xnrow, const float* __restrict__ whs,
    float* __restrict__ logits)
{
    int64_t row = (int64_t)blockIdx.x * 4 + (threadIdx.x >> 6);
    int lane = threadIdx.x & 63;
    const ushort* p = Hsa + row * KQ;
    const float* q = mxs + row * KQ;
    float p0 = bf2f(p[lane]), p1 = bf2f(p[lane + 64]);
    float q0 = q[lane] + q[lane + MXSPLIT];
    float q1 = q[lane + 64] + q[lane + 64 + MXSPLIT];
    // Round A: R1=sum q^2, R2=sum p*q, R3=sum p^2 (interleaved)
    float r1 = q0 * q0 + q1 * q1;
    float r2 = p0 * q0 + p1 * q1;
    float r3 = p0 * p0 + p1 * p1;
    waveRedSum3(r1, r2, r3);
    float mxn = sqrtf(fmaxf(r1, 1e-15f));
    float xn = xnrow[row];
    float fac = tanhf(mxn / xn * artanh_clip(xn)) / mxn;
    float xy = fac * r2;
    float x2 = r3;
    float y2 = fac * fac * r1;
    float ca = 1.f + 2.f * xy + y2, cb = 1.f - x2;
    float den = fmaxf(1.f + 2.f * xy + x2 * y2, 1e-15f);
    float h0 = (ca * p0 + cb * fac * q0) / den, h1 = (ca * p1 + cb * fac * q1) / den;
    float hn2 = (ca * ca * x2 + 2.f * ca * cb * xy + cb * cb * y2) / (den * den);
    float hn = sqrtf(fmaxf(hn2, 1e-15f));
    float uf = artanh_clip(hn) / hn;
    float g0 = gelu_f(uf * h0), g1 = gelu_f(uf * h1);
    // Round B: R4=sum g^2, R5=sum g*whs (interleaved)
    float r4 = g0 * g0 + g1 * g1;
    float r5 = g0 * whs[lane] + g1 * whs[lane + 64];
    waveRedSum2(r4, r5);
    float gn = sqrtf(fmaxf(r4, 1e-15f));
    float ef = tanhf(gn) / gn;
    float dot = ef * r5;
    float Hn = sqrtf(fmaxf(ef * ef * r4, 1e-15f));
    float mxn2 = sqrtf(fmaxf(dot * dot, 1e-15f));
    float lg = tanhf(mxn2 / Hn * artanh_clip(Hn)) * dot / mxn2;
    if (lane == 0) logits[row] = lg;
}

// transpose (z batches of 1024x128) -> (z batches of 128x1024)
__global__ void thsa_kernel(const ushort* __restrict__ in, ushort* __restrict__ outp) {
    __shared__ ushort tile[32][33];
    int z = blockIdx.z;
    int n0 = blockIdx.x * 32, j0 = blockIdx.y * 32;
    const ushort* ib = in + (int64_t)z * 131072;
    ushort* ob = outp + (int64_t)z * 131072;
    int tx = threadIdx.x, ty = threadIdx.y;
    for (int i = 0; i < 32; i += 8) tile[ty + i][tx] = ib[(n0 + ty + i) * 128 + j0 + tx];
    __syncthreads();
    for (int i = 0; i < 32; i += 8) ob[(j0 + ty + i) * 1024 + n0 + tx] = tile[tx][ty + i];
}

// Hc path rowwise chain: wave-per-row (16 elems/lane), applies fac on the fly,
// reads two mx splits, writes combined Hc into split A. 2 reduction rounds.
__global__ __launch_bounds__(256) void rowops_c_kernel(const ushort* __restrict__ HcAT,
                                                       float* __restrict__ mx,
                                                       const float* __restrict__ fac_c) {
    int64_t row = (int64_t)blockIdx.x * 4 + (threadIdx.x >> 6);   // 0..4095
    int lane = threadIdx.x & 63;
    int b = (int)(row >> 7);
    const ushort* xb = HcAT + row * (int64_t)NCQ + 16 * lane;
    float* yb = mx + row * (int64_t)NCQ + 16 * lane;
    const float* fb = fac_c + b * NCQ + 16 * lane;
    float xv[16], yv[16];
    {
        uint4 u0 = *(const uint4*)xb;
        uint4 u1 = *(const uint4*)(xb + 8);
        const ushort* pu0 = (const ushort*)&u0;
        const ushort* pu1 = (const ushort*)&u1;
#pragma unroll
        for (int i = 0; i < 8; i++) { xv[i] = bf2f(pu0[i]); xv[8 + i] = bf2f(pu1[i]); }
    }
#pragma unroll
    for (int i = 0; i < 16; i += 4) {
        float4 v1 = *(const float4*)(yb + i);
        float4 v2 = *(const float4*)(yb + i + MXSPLIT);
        float4 fv = *(const float4*)(fb + i);
        yv[i + 0] = fv.x * (v1.x + v2.x);
        yv[i + 1] = fv.y * (v1.y + v2.y);
        yv[i + 2] = fv.z * (v1.z + v2.z);
        yv[i + 3] = fv.w * (v1.w + v2.w);
    }
    // Round A: xy, x2, y2 (interleaved)
    float xy = 0.f, x2 = 0.f, y2 = 0.f;
#pragma unroll
    for (int i = 0; i < 16; i++) { xy += xv[i] * yv[i]; x2 += xv[i] * xv[i]; y2 += yv[i] * yv[i]; }
    waveRedSum3(xy, x2, y2);
    float ca = 1.f + 2.f * xy + y2, cb = 1.f - x2;
    float den = fmaxf(1.f + 2.f * xy + x2 * y2, 1e-15f);
    float hn2 = (ca * ca * x2 + 2.f * ca * cb * xy + cb * cb * y2) / (den * den);
    float hn = sqrtf(fmaxf(hn2, 1e-15f));
    float uf = artanh_clip(hn) / hn;
    float g[16]; float gn2 = 0.f;
#pragma unroll
    for (int i = 0; i < 16; i++) {
        float h = (ca * xv[i] + cb * yv[i]) / den;
        g[i] = gelu_f(uf * h);
        gn2 += g[i] * g[i];
    }
    gn2 = waveRedSum(gn2);
    float gn = sqrtf(fmaxf(gn2, 1e-15f));
    float ef = tanhf(gn) / gn;
#pragma unroll
    for (int i = 0; i < 16; i += 4) {
        float4 o = {ef * g[i], ef * g[i + 1], ef * g[i + 2], ef * g[i + 3]};
        *(float4*)(yb + i) = o;
    }
}

// Ac logits
__global__ __launch_bounds__(256) void logitsc_kernel(const float* __restrict__ Hc, const float* __restrict__ whc, float* __restrict__ lgc) {
    int b = blockIdx.x; int m = blockIdx.y * 256 + threadIdx.x;
    const float* base = Hc + (int64_t)b * KQ * NCQ + m;
    float s1 = 0.f, s2 = 0.f;
    for (int j = 0; j < KQ; j++) { float v = base[j * NCQ]; s1 += v * whc[j]; s2 += v * v; }
    float xn = sqrtf(fmaxf(s2, 1e-15f));
    float mxn = sqrtf(fmaxf(s1 * s1, 1e-15f));
    lgc[b * NCQ + m] = tanhf(mxn / xn * artanh_clip(xn)) * s1 / mxn;
}

// fused softmax for lgs|lgc -> AsOut|AcOut, grid 64
__global__ __launch_bounds__(256) void softmax_kernel(const float* __restrict__ lg, float* __restrict__ outp) {
    __shared__ float red[4];
    int b = blockIdx.x; int t = threadIdx.x;
    const float* x = lg + b * 1024;
    float v[4]; float m = -1e30f;
#pragma unroll
    for (int i = 0; i < 4; i++) { v[i] = x[t + 256 * i]; m = fmaxf(m, v[i]); }
    m = blockRedMax(m, red);
    float s = 0.f;
#pragma unroll
    for (int i = 0; i < 4; i++) { v[i] = expf(v[i] - m); s += v[i]; }
    s = blockRedSum(s, red);
    float inv = 1.0f / s;
#pragma unroll
    for (int i = 0; i < 4; i++) outp[b * 1024 + t + 256 * i] = v[i] * inv;
}

// centroid stage A on bf16 L (stride 288, time at col 0)
__global__ __launch_bounds__(320) void centroidA_kernel(
    const ushort* __restrict__ Lsb, const ushort* __restrict__ Lcb,
    const float* __restrict__ As, const float* __restrict__ Ac,
    float* __restrict__ part)
{
    int b = blockIdx.x;
    int which = blockIdx.y;
    int chunk = blockIdx.z;
    const ushort* L = which ? Lcb : Lsb;
    const float* w = which ? Ac : As;
    int t = threadIdx.x;
    if (t >= DP) return;
    const ushort* Lb = L + (int64_t)b * NSQ * KPAD + (int64_t)chunk * 128 * KPAD + t;
    const float* wb = w + b * NSQ + chunk * 128;
    float s = 0.f;
    for (int n = 0; n < 128; n++) s += wb[n] * bf2f(Lb[(int64_t)n * KPAD]);
    part[((int64_t)((b * 2 + which) * 8 + chunk)) * 264 + t] = s;
}
__global__ __launch_bounds__(320) void centroidB_kernel(
    const float* __restrict__ part, float* __restrict__ co_s, float* __restrict__ co_c)
{
    int b = blockIdx.x;
    int which = blockIdx.y;
    int t = threadIdx.x;
    if (t >= DP) return;
    const float* p = part + (int64_t)(b * 2 + which) * 8 * 264 + t;
    float s = 0.f;
#pragma unroll
    for (int c = 0; c < 8; c++) s += p[c * 264];
    (which ? co_c : co_s)[b * DP + t] = s;
}

__global__ __launch_bounds__(256) void final_kernel(const float* __restrict__ co_s, const float* __restrict__ co_c, float* __restrict__ outp) {
    __shared__ float red[4];
    int b = blockIdx.x, t = threadIdx.x;
    float zmine[2];
    for (int w = 0; w < 2; w++) {
        const float* co = (w ? co_c : co_s) + b * DP;
        float at = co[0];
        float asp = co[1 + t];
        float ssp = blockRedSum(asp * asp, red);
        float li = ssp - at * at;
        float den = sqrtf(fmaxf(fabsf(li), 1e-8f));
        float xt = at / den, xsp = asp / den;
        float s2 = blockRedSum(xsp * xsp, red);
        float nrm = sqrtf(fmaxf(s2, 1e-15f));
        float ac = acoshf(fmaxf(xt, 1.0f + 1e-7f));
        zmine[w] = ac * xsp / nrm;
    }
    float vn2 = blockRedSum(zmine[0] * zmine[0] + zmine[1] * zmine[1], red);
    float vn = sqrtf(fmaxf(vn2, 1e-15f));
    float sc = sinhf(vn) / vn;
    if (t == 0) outp[b * 513] = coshf(vn);
    outp[b * 513 + 1 + t] = sc * zmine[0];
    outp[b * 513 + 1 + 256 + t] = sc * zmine[1];
}

// ---------------- host launcher ----------------
extern "C" void kernel_launch(void* const* d_in, const int* in_sizes, int n_in,
                              void* d_out, int out_size, void* d_ws, size_t ws_size,
                              hipStream_t stream)
{
    const float* sent = (const float*)d_in[0];
    const float* comm = (const float*)d_in[1];
    const float* WlW  = (const float*)d_in[2];
    const float* Wlb  = (const float*)d_in[3];
    const float* WcW  = (const float*)d_in[4];
    const float* Wcb  = (const float*)d_in[5];
    const float* WsW  = (const float*)d_in[6];
    const float* Wsb  = (const float*)d_in[7];
    const float* whs  = (const float*)d_in[8];
    const float* whc  = (const float*)d_in[9];
    float* out = (float*)d_out;
    (void)in_sizes; (void)n_in; (void)out_size; (void)ws_size;

    float* ws = (float*)d_ws;
    size_t off = 0;
    auto take = [&](size_t n) { float* p = ws + off; off += n; return p; };
    float*  xnrow = take(32768);
    float*  fac_c = take(32768);
    float*  lgs   = take(32768);   // contiguous with lgc
    float*  lgc   = take(32768);
    float*  co_s  = take(8224);
    float*  co_c  = take(8224);
    ushort* Ls_bf = (ushort*)take(4718592);   // contiguous with Lc_bf
    ushort* Lc_bf = (ushort*)take(4718592);
    ushort* Wl_bf = (ushort*)take(36864);
    ushort* Ws_bf = (ushort*)take(18432);
    ushort* Wc_bf = (ushort*)take(18432);
    ushort* HsA_bf = (ushort*)take(2097152);  // contiguous with HcA_bf
    ushort* HcA_bf = (ushort*)take(2097152);
    float*  part_cn   = take(1048576);
    float*  part_cent = take(135168);
    ushort* LmatT_bf  = (ushort*)take(16777216);  // 32x1024x1024 bf16
    float*  F     = take(33554432);               // total ~249 MiB

    // Phase overlays in F (float offsets)
    ushort* XC_bf   = (ushort*)F;                 // [P1] 5.24M fl
    ushort* XS_bf   = (ushort*)(F + 5242880);     // [P1] 5.24M fl
    ushort* Ff_bf   = (ushort*)(F + 10485760);    // [P1] 10.49M fl
    ushort* CS1c    = (ushort*)(F + 20971520);    // [P1] 204800 fl
    ushort* CS1s    = (ushort*)(F + 21176320);    // [P1] 204800 fl
    ushort* C2_bf   = (ushort*)(F + 21381120);    // [P1] 32k fl
    ushort* S2_bf   = (ushort*)(F + 21413888);    // [P1] 32k fl
    ushort* YcYs    = (ushort*)F;                 // [P1] aliases XC/XS; 10.49M fl
    ushort* Lmat_bf = (ushort*)F;                 // [P3-P5] 16.78M fl
    ushort* Llin_bf = (ushort*)(F + 29360128);    // [P2-P3] 4.72M fl
    float*  mx      = F + 16777216;               // [P5] 2 x 4.19M fl split buffers
    ushort* HsAT    = (ushort*)(F + 25165824);    // [P5] 2.1M fl
    ushort* HcAT    = (ushort*)(F + 27262976);    // [P5] 2.1M fl

    float* AsOut = out + 16416;
    float* AcOut = out + 16416 + 32768;

    dim3 blk(256);
    const short* NUL = nullptr;

    genconst_kernel<<<3968, 256, 0, stream>>>(CS1c, CS1s, C2_bf, S2_bf, WlW, WsW, WcW, Wl_bf, Ws_bf, Wc_bf);

    // ---- input prep + m-fold ----
    prep_fold_kernel<<<dim3(513, 16), blk, 0, stream>>>(sent, comm, XC_bf, XS_bf);
    // stage-1 DUAL: Ff[:, :640] = C2 . XC^T ; Ff[:, 640:] = S2 . XS^T
    mfma_gemm<false,false,true,false,false,1,true><<<dim3(5,2,128), blk, 0, stream>>>(
        (const short*)C2_bf,256,0, (const short*)XC_bf,256,(int64_t)NFOLD*256, Ff_bf,1280,(int64_t)256*1280,
        nullptr, 256,NFOLD,256, (const short*)S2_bf, (const short*)XS_bf, 640, nullptr);
    // stage-2 DUAL (n-folded): Yc = CS1c . Fc^T ; Ys = CS1s . Fs^T
    mfma_gemm<false,false,true,false,false,1,true><<<dim3(2,5,128), blk, 0, stream>>>(
        (const short*)CS1c,KF2,0, (const short*)Ff_bf,1280,(int64_t)256*1280, YcYs,256,327680,
        nullptr, NFOLD,256,KF2, (const short*)CS1s, (const short*)(Ff_bf+640), 163840, nullptr);
    e2l_kernel<<<16384, blk, 0, stream>>>(YcYs, Ls_bf, Lc_bf);

    // ---- L = lorentz_linear(Lc, Wl): space cols bf16 straight into Llin_bf[.,1:] ----
    mfma_gemm<false,false,true,true,false,1,false><<<dim3(2,256,1), blk, 0, stream>>>(
        (const short*)Lc_bf,KPAD,0, (const short*)Wl_bf,KPAD,0, (void*)(Llin_bf+1),KPAD,0,
        Wlb+1, 32768,256,KPAD, NUL, NUL, 0, nullptr);
    lnorm_kernel<<<8192, blk, 0, stream>>>(Llin_bf);

    // ---- Lmat = lorentz_act(einsum(Ls, Llin)) in bf16 ----
    mfma_gemm<false,false,true,false,false,1,false><<<dim3(8,8,32), blk, 0, stream>>>(
        (const short*)Ls_bf,KPAD,294912, (const short*)Llin_bf,KPAD,294912, Lmat_bf,1024,1048576,
        nullptr, 1024,1024,KPAD, NUL, NUL, 0, nullptr);
    lact_kernel<<<32768, blk, 0, stream>>>(Lmat_bf, xnrow);
    tmat_kernel<<<dim3(32,32,32), dim3(32,8), 0, stream>>>(Lmat_bf, LmatT_bf);
    colnormA_kernel<<<dim3(32,8), blk, 0, stream>>>(Lmat_bf, part_cn);

    // ---- Hs_a / Hc_a: bf16 + per-z bias straight into HsA_bf|HcA_bf, in-place poincare ----
    mfma_gemm<false,false,true,true,false,1,false><<<dim3(1,256,2), blk, 0, stream>>>(
        (const short*)Ls_bf,KPAD,9437184, (const short*)Ws_bf,KPAD,36864, HsA_bf,128,4194304,
        Wsb+1, 32768,128,KPAD, NUL, NUL, 0, Wcb+1);
    poinc2_kernel<<<16384, blk, 0, stream>>>(HsA_bf);

    // ---- transpose HsA_bf and HcA_bf in one launch ----
    thsa_kernel<<<dim3(32,4,64), dim3(32,8), 0, stream>>>(HsA_bf, HsAT);

    // ---- Hs path: mx_s = Lmat . Hc_a (split-K=2, dual partial buffers) ----
    mfma_gemm<false,false,false,false,false,2,false><<<dim3(1,8,64), blk, 0, stream>>>(
        (const short*)Lmat_bf,1024,1048576, (const short*)HcAT,1024,131072, mx,128,131072,
        nullptr, 1024,128,1024, NUL, NUL, MXSPLIT, nullptr);
    rowops_s_kernel<<<8192, blk, 0, stream>>>(HsA_bf, mx, xnrow, whs, lgs);

    // ---- Hc path: mx_cT = Hs_a^T . Lmat (all-fast via HsAT + LmatT; split-K=2) ----
    mfma_gemm<false,false,false,false,false,2,false><<<dim3(8,1,64), blk, 0, stream>>>(
        (const short*)HsAT,1024,131072, (const short*)LmatT_bf,1024,1048576, mx,1024,131072,
        nullptr, 128,1024,1024, NUL, NUL, MXSPLIT, nullptr);
    colfac_kernel<<<dim3(32,4), blk, 0, stream>>>(part_cn, mx, fac_c);
    rowops_c_kernel<<<1024, blk, 0, stream>>>(HcAT, mx, fac_c);
    logitsc_kernel<<<dim3(32,4), blk, 0, stream>>>(mx, whc, lgc);

    // ---- softmaxes / centroids / concat ----
    softmax_kernel<<<64, blk, 0, stream>>>(lgs, AsOut);
    centroidA_kernel<<<dim3(32,2,8), 320, 0, stream>>>(Ls_bf, Lc_bf, AsOut, AcOut, part_cent);
    centroidB_kernel<<<dim3(32,2), 320, 0, stream>>>(part_cent, co_s, co_c);
    final_kernel<<<32, blk, 0, stream>>>(co_s, co_c, out);
}